// Round 16
// baseline (281.975 us; speedup 1.0000x reference)
//
#include <hip/hip_runtime.h>
#include <hip/hip_bf16.h>
#include <math.h>

#define GENES 1000

typedef __attribute__((ext_vector_type(8))) _Float16 half8;
typedef __attribute__((ext_vector_type(4))) float f32x4;
typedef __attribute__((ext_vector_type(4))) unsigned int uint4v;
typedef __attribute__((ext_vector_type(2))) unsigned int uint2v;

__device__ inline float f16lo(unsigned int v) {
  return (float)__builtin_bit_cast(_Float16, (unsigned short)(v & 0xffffu));
}
__device__ inline float f16hi(unsigned int v) {
  return (float)__builtin_bit_cast(_Float16, (unsigned short)(v >> 16));
}
__device__ inline unsigned int pk(float a, float b) {
  return __builtin_bit_cast(unsigned int, __builtin_amdgcn_cvt_pkrtz(a, b));
}

// lgkm-only barrier: LDS-write visibility without draining vmcnt (prefetches
// survive). sched_barrier fences (rule #18).
__device__ inline void lds_barrier() {
  __builtin_amdgcn_sched_barrier(0);
  asm volatile("s_waitcnt lgkmcnt(0)" ::: "memory");
  __builtin_amdgcn_sched_barrier(0);
  __builtin_amdgcn_s_barrier();
  __builtin_amdgcn_sched_barrier(0);
}

// ---------------- CSR build ----------------

__global__ void k_deg(const int* __restrict__ ei, int* __restrict__ deg, int E) {
  int e = blockIdx.x * blockDim.x + threadIdx.x;
  if (e < E) atomicAdd(&deg[ei[E + e]], 1);
}

__global__ void k_scan1(int* __restrict__ deg, int* __restrict__ ptr,
                        int* __restrict__ bsum, int n) {
  __shared__ int ws[4];
  int t = threadIdx.x, b = blockIdx.x;
  int i = b * 256 + t;
  int lane = t & 63, w = t >> 6;
  int x = 0;
  if (i < n) { x = deg[i]; deg[i] = 0; }
  #pragma unroll
  for (int d = 1; d < 64; d <<= 1) {
    int y = __shfl_up(x, d);
    if (lane >= d) x += y;
  }
  if (lane == 63) ws[w] = x;
  __syncthreads();
  if (t == 0) {
    int s = 0;
    #pragma unroll
    for (int k = 0; k < 4; ++k) { s += ws[k]; ws[k] = s; }
  }
  __syncthreads();
  int incl = x + (w ? ws[w - 1] : 0);
  if (i < n) ptr[i + 1] = incl;
  if (t == 255) bsum[b] = incl;
  if (i == 0) ptr[0] = 0;
}

__global__ void k_scan2(int* __restrict__ bsum, int nb) {
  __shared__ int ws[4];
  int t = threadIdx.x;
  int lane = t & 63, w = t >> 6;
  int v = (t < nb) ? bsum[t] : 0;
  int x = v;
  #pragma unroll
  for (int d = 1; d < 64; d <<= 1) {
    int y = __shfl_up(x, d);
    if (lane >= d) x += y;
  }
  if (lane == 63) ws[w] = x;
  __syncthreads();
  if (t == 0) {
    int s = 0;
    #pragma unroll
    for (int k = 0; k < 4; ++k) { s += ws[k]; ws[k] = s; }
  }
  __syncthreads();
  int incl = x + (w ? ws[w - 1] : 0);
  if (t < nb) bsum[t] = incl - v;
}

__global__ void k_scan3(int* __restrict__ ptr, const int* __restrict__ bsum, int n) {
  int i = blockIdx.x * 256 + threadIdx.x;
  if (i < n) ptr[i + 1] += bsum[blockIdx.x];
}

__global__ void k_scatter(const int* __restrict__ ei, const int* __restrict__ ptr,
                          int* __restrict__ cur, int* __restrict__ srcs, int E) {
  int e = blockIdx.x * blockDim.x + threadIdx.x;
  if (e >= E) return;
  int d = ei[E + e];
  int pos = ptr[d] + atomicAdd(&cur[d], 1);
  srcs[pos] = ei[e];
}

// ---------------- W pack (all 3 layers), q-major per 32-k step ------------------
// element idx = s*4096 + q*1024 + col*8 + j  (k = s*32 + q*8 + j), fp16.
// W0 -> 32 ksteps (K padded 1024, zero-pad), W1 -> 4, W2 -> 4 (cols pad 128).

__global__ void k_wpackall(const float* __restrict__ W0, const float* __restrict__ W1,
                           const float* __restrict__ W2, unsigned short* __restrict__ P,
                           int K0) {
  int t = blockIdx.x * blockDim.x + threadIdx.x;  // 163840 total
  if (t >= 163840) return;
  const float* W; int K, N, e;
  if (t < 131072)      { W = W0; K = K0;  N = 128; e = t; }
  else if (t < 147456) { W = W1; K = 128; N = 128; e = t - 131072; }
  else                 { W = W2; K = 128; N = 16;  e = t - 147456; }
  int s = e >> 12, rem = e & 4095;
  int q = rem >> 10, col = (rem >> 3) & 127, j = rem & 7;
  int k = s * 32 + q * 8 + j;
  float v = (k < K && col < N) ? W[(long)k * N + col] : 0.f;
  _Float16 h = (_Float16)v;
  P[t] = __builtin_bit_cast(unsigned short, h);
}

// ---------------- MFMA fp16 GEMM: A direct-to-reg, lgkm-only barriers ----------
// 512 threads = 8 waves (4 row-groups x 2 col-groups); BM=64, BN=128, BK=32.
// A: per-wave fragment loads straight from global into depth-2 named slots --
// never staged in LDS, so prefetches survive barriers (no vmcnt(0) drain:
// barrier is s_waitcnt lgkmcnt(0) + raw s_barrier). B: reg-staged into 2x8KB
// LDS dbuf. All vm waits compiler-counted. VGPR ~50 (64-budget, rounds 5-11
// lesson). W zero-padded to K=1024 -> no k-guards on A (garbage x zero = 0);
// row clamped. Fused epilogue: out (fp16/fp32) + als/ald.

template<int HH, int NST, bool AF16, bool OF16>
__global__ __launch_bounds__(512) void k_mgemm10(
    const void* __restrict__ Ap, const unsigned short* __restrict__ Pb,
    void* __restrict__ outp, float* __restrict__ als, float* __restrict__ ald,
    const float* __restrict__ avs, const float* __restrict__ avd,
    int M, int K, int ldc) {
  __shared__ __align__(16) char lds[16384];   // B dbuf: 2 x 8KB

  int t = threadIdx.x, lane = t & 63;
  int r15 = lane & 15, q = lane >> 4;
  int wv = t >> 6;
  int wr = wv >> 1, wc = wv & 1;
  long row0 = (long)blockIdx.x * 64;

  long arow = row0 + wr * 16 + r15; if (arow >= M) arow = M - 1;
  const float* pa32 = (const float*)Ap + arow * (long)K + q * 8;
  const unsigned short* pa16 = (const unsigned short*)Ap + arow * (long)K + q * 8;
  const char* pB = (const char*)Pb + t * 16;

  f32x4 acc[4];
  #pragma unroll
  for (int nt = 0; nt < 4; ++nt) acc[nt] = (f32x4){0.f, 0.f, 0.f, 0.f};

  // named register slots (all indices compile-time under full unroll)
  uint4v a0lo, a0hi, a1lo, a1hi;   // A depth-2 (fp32: lo+hi; fp16: lo only)
  uint4v bs0, bs1;                 // B stage depth-2

  auto issueA = [&](int s, int slot) {
    if constexpr (AF16) {
      if (slot == 0) a0lo = *(const uint4v*)(pa16 + s * 32);
      else           a1lo = *(const uint4v*)(pa16 + s * 32);
    } else {
      if (slot == 0) {
        a0lo = *(const uint4v*)(pa32 + s * 32);
        a0hi = *(const uint4v*)(pa32 + s * 32 + 4);
      } else {
        a1lo = *(const uint4v*)(pa32 + s * 32);
        a1hi = *(const uint4v*)(pa32 + s * 32 + 4);
      }
    }
  };
  auto issueB = [&](int s, int slot) {
    if (slot == 0) bs0 = *(const uint4v*)(pB + (size_t)s * 8192);
    else           bs1 = *(const uint4v*)(pB + (size_t)s * 8192);
  };
  auto writeB = [&](int buf, int slot) {
    *(uint4v*)(lds + buf * 8192 + t * 16) = (slot == 0) ? bs0 : bs1;
  };
  auto mkfrag = [&](int slot) -> half8 {
    if constexpr (AF16) {
      return __builtin_bit_cast(half8, slot == 0 ? a0lo : a1lo);
    } else {
      float4 lo = __builtin_bit_cast(float4, slot == 0 ? a0lo : a1lo);
      float4 hi = __builtin_bit_cast(float4, slot == 0 ? a0hi : a1hi);
      uint4v au;
      au[0] = pk(lo.x, lo.y); au[1] = pk(lo.z, lo.w);
      au[2] = pk(hi.x, hi.y); au[3] = pk(hi.z, hi.w);
      return __builtin_bit_cast(half8, au);
    }
  };

  // prologue
  issueB(0, 0);
  if (NST > 1) issueB(1, 1);
  issueA(0, 0);
  writeB(0, 0);                       // counted vmcnt (waits bs0 only)
  lds_barrier();

  #pragma unroll
  for (int s = 0; s < NST; ++s) {
    const int sl = s & 1;
    if (s + 2 < NST) issueB(s + 2, sl);
    if (s + 1 < NST) issueA(s + 1, (s + 1) & 1);
    half8 af = mkfrag(sl);            // counted vmcnt for A(s)
    #pragma unroll
    for (int nt = 0; nt < 4; ++nt) {
      half8 bf = *(const half8*)(lds + sl * 8192 + q * 2048 +
                                 (wc * 64 + nt * 16 + r15) * 16);
      acc[nt] = __builtin_amdgcn_mfma_f32_16x16x32_f16(af, bf, acc[nt], 0, 0, 0);
    }
    if (s + 1 < NST) {
      writeB((s + 1) & 1, (s + 1) & 1); // counted vmcnt for B(s+1)
      lds_barrier();
    }
  }

  // ---- epilogue: C/D layout col=lane&15, row=(lane>>4)*4+i ----
  long rbase = row0 + wr * 16 + q * 4;
  if constexpr (OF16) {
    unsigned short* o16 = (unsigned short*)outp;
    #pragma unroll
    for (int i = 0; i < 4; ++i) {
      long r = rbase + i;
      if (r < M) {
        #pragma unroll
        for (int nt = 0; nt < 4; ++nt) {
          int col = wc * 64 + nt * 16 + r15;
          _Float16 hv = (_Float16)acc[nt][i];
          o16[r * ldc + col] = __builtin_bit_cast(unsigned short, hv);
        }
      }
    }
  } else {
    float* o32 = (float*)outp;
    #pragma unroll
    for (int i = 0; i < 4; ++i) {
      long r = rbase + i;
      if (r < M) {
        #pragma unroll
        for (int nt = 0; nt < 4; ++nt) {
          int col = wc * 64 + nt * 16 + r15;
          if (col < ldc) o32[r * ldc + col] = acc[nt][i];
        }
      }
    }
  }
  #pragma unroll
  for (int nt = 0; nt < 4; ++nt) {
    int head = wc * 4 + nt;
    if (head < HH) {
      float cs = avs[head * 16 + r15];
      float cd = avd[head * 16 + r15];
      #pragma unroll
      for (int i = 0; i < 4; ++i) {
        float s1 = acc[nt][i] * cs;
        float s2 = acc[nt][i] * cd;
        #pragma unroll
        for (int d = 1; d < 16; d <<= 1) {
          s1 += __shfl_xor(s1, d);
          s2 += __shfl_xor(s2, d);
        }
        if (r15 == 0) {
          long r = rbase + i;
          if (r < M) { als[r * HH + head] = s1; ald[r * HH + head] = s2; }
        }
      }
    }
  }
}

// ---------------- per-dst aggregation, H=8, C=16, fp16 h, ELU ------------------

__global__ void k_agg128h(const unsigned short* __restrict__ h,
                          const float* __restrict__ als, const float* __restrict__ ald,
                          const int* __restrict__ ptr, const int* __restrict__ srcs,
                          const float* __restrict__ bias,
                          unsigned short* __restrict__ out, int n) {
  int wid = (int)(((long)blockIdx.x * blockDim.x + threadIdx.x) >> 6);
  if (wid >= n) return;
  int lane = threadIdx.x & 63;
  int half = lane >> 5, l5 = lane & 31;
  int c0 = 4 * l5;
  int hB = l5 >> 2;
  int p0 = ptr[wid], deg = ptr[wid + 1] - p0;
  float aldB = ald[wid * 8 + hB];
  float a0 = 0.f, a1 = 0.f, a2 = 0.f, a3 = 0.f, dsum = 0.f;
  int j = half;
  for (; j + 6 < deg; j += 8) {
    int s0 = srcs[p0 + j],     s1 = srcs[p0 + j + 2];
    int s2 = srcs[p0 + j + 4], s3 = srcs[p0 + j + 6];
    float l0 = als[s0 * 8 + hB] + aldB;
    float l1 = als[s1 * 8 + hB] + aldB;
    float l2 = als[s2 * 8 + hB] + aldB;
    float l3 = als[s3 * 8 + hB] + aldB;
    uint2v h0 = *(const uint2v*)(h + (long)s0 * 128 + c0);
    uint2v h1 = *(const uint2v*)(h + (long)s1 * 128 + c0);
    uint2v h2 = *(const uint2v*)(h + (long)s2 * 128 + c0);
    uint2v h3 = *(const uint2v*)(h + (long)s3 * 128 + c0);
    l0 = l0 > 0.f ? l0 : 0.2f * l0;
    l1 = l1 > 0.f ? l1 : 0.2f * l1;
    l2 = l2 > 0.f ? l2 : 0.2f * l2;
    l3 = l3 > 0.f ? l3 : 0.2f * l3;
    float e0 = __expf(l0), e1 = __expf(l1), e2 = __expf(l2), e3 = __expf(l3);
    dsum += e0 + e1 + e2 + e3;
    a0 += e0 * f16lo(h0[0]) + e1 * f16lo(h1[0]) + e2 * f16lo(h2[0]) + e3 * f16lo(h3[0]);
    a1 += e0 * f16hi(h0[0]) + e1 * f16hi(h1[0]) + e2 * f16hi(h2[0]) + e3 * f16hi(h3[0]);
    a2 += e0 * f16lo(h0[1]) + e1 * f16lo(h1[1]) + e2 * f16lo(h2[1]) + e3 * f16lo(h3[1]);
    a3 += e0 * f16hi(h0[1]) + e1 * f16hi(h1[1]) + e2 * f16hi(h2[1]) + e3 * f16hi(h3[1]);
  }
  for (; j < deg; j += 2) {
    int s = srcs[p0 + j];
    float l = als[s * 8 + hB] + aldB;
    l = l > 0.f ? l : 0.2f * l;
    float e = __expf(l);
    uint2v hv = *(const uint2v*)(h + (long)s * 128 + c0);
    dsum += e;
    a0 += e * f16lo(hv[0]);
    a1 += e * f16hi(hv[0]);
    a2 += e * f16lo(hv[1]);
    a3 += e * f16hi(hv[1]);
  }
  a0 += __shfl_xor(a0, 32);
  a1 += __shfl_xor(a1, 32);
  a2 += __shfl_xor(a2, 32);
  a3 += __shfl_xor(a3, 32);
  dsum += __shfl_xor(dsum, 32);
  if (half == 0) {
    float inv = 1.f / (dsum + 1e-16f);
    float o0 = a0 * inv + bias[c0];
    float o1 = a1 * inv + bias[c0 + 1];
    float o2 = a2 * inv + bias[c0 + 2];
    float o3 = a3 * inv + bias[c0 + 3];
    o0 = o0 > 0.f ? o0 : (__expf(o0) - 1.f);
    o1 = o1 > 0.f ? o1 : (__expf(o1) - 1.f);
    o2 = o2 > 0.f ? o2 : (__expf(o2) - 1.f);
    o3 = o3 > 0.f ? o3 : (__expf(o3) - 1.f);
    uint2v po;
    po[0] = __builtin_bit_cast(unsigned int, __builtin_amdgcn_cvt_pkrtz(o0, o1));
    po[1] = __builtin_bit_cast(unsigned int, __builtin_amdgcn_cvt_pkrtz(o2, o3));
    *(uint2v*)(out + (long)wid * 128 + c0) = po;
  }
}

// ---------------- per-dst aggregation, H=1, C=16, fp32, no max, 4-batch --------

__global__ void k_agg16(const float* __restrict__ h, const float* __restrict__ als,
                        const float* __restrict__ ald, const int* __restrict__ ptr,
                        const int* __restrict__ srcs, const float* __restrict__ bias,
                        float* __restrict__ out, int n, int lda) {
  int wid = (int)(((long)blockIdx.x * blockDim.x + threadIdx.x) >> 6);
  if (wid >= n) return;
  int lane = threadIdx.x & 63;
  int p0 = ptr[wid], deg = ptr[wid + 1] - p0;
  float aldv = ald[wid];
  int g = lane >> 4, c = lane & 15;
  float acc = 0.f, dsum = 0.f;
  int j = g;
  for (; j + 12 < deg; j += 16) {
    int s0 = srcs[p0 + j],     s1 = srcs[p0 + j + 4];
    int s2 = srcs[p0 + j + 8], s3 = srcs[p0 + j + 12];
    float l0 = als[s0] + aldv, l1 = als[s1] + aldv;
    float l2 = als[s2] + aldv, l3 = als[s3] + aldv;
    float h0 = h[(long)s0 * lda + c], h1 = h[(long)s1 * lda + c];
    float h2 = h[(long)s2 * lda + c], h3 = h[(long)s3 * lda + c];
    l0 = l0 > 0.f ? l0 : 0.2f * l0;
    l1 = l1 > 0.f ? l1 : 0.2f * l1;
    l2 = l2 > 0.f ? l2 : 0.2f * l2;
    l3 = l3 > 0.f ? l3 : 0.2f * l3;
    float e0 = __expf(l0), e1 = __expf(l1), e2 = __expf(l2), e3 = __expf(l3);
    dsum += e0 + e1 + e2 + e3;
    acc += e0 * h0 + e1 * h1 + e2 * h2 + e3 * h3;
  }
  for (; j < deg; j += 4) {
    int s = srcs[p0 + j];
    float l = als[s] + aldv;
    l = l > 0.f ? l : 0.2f * l;
    float e = __expf(l);
    dsum += e;
    acc += e * h[(long)s * lda + c];
  }
  #pragma unroll
  for (int d = 16; d < 64; d <<= 1) {
    acc += __shfl_xor(acc, d);
    dsum += __shfl_xor(dsum, d);
  }
  if (lane < 16)
    out[(long)wid * 16 + lane] = acc / (dsum + 1e-16f) + bias[lane];
}

// ---------------- launch ----------------

extern "C" void kernel_launch(void* const* d_in, const int* in_sizes, int n_in,
                              void* d_out, int out_size, void* d_ws, size_t ws_size,
                              hipStream_t stream) {
  const float* x  = (const float*)d_in[0];
  const int*   ei = (const int*)d_in[1];
  const float* W0 = (const float*)d_in[2];
  const float* as0= (const float*)d_in[3];
  const float* ad0= (const float*)d_in[4];
  const float* b0 = (const float*)d_in[5];
  const float* W1 = (const float*)d_in[6];
  const float* as1= (const float*)d_in[7];
  const float* ad1= (const float*)d_in[8];
  const float* b1 = (const float*)d_in[9];
  const float* W2 = (const float*)d_in[10];
  const float* as2= (const float*)d_in[11];
  const float* ad2= (const float*)d_in[12];
  const float* b2 = (const float*)d_in[13];
  float* out = (float*)d_out;

  int E = in_sizes[1] / 2;
  int n = in_sizes[0] / GENES;

  char* ws = (char*)d_ws;
  size_t off = 0;
  auto alloc = [&](size_t bytes) {
    void* p = ws + off;
    off = (off + bytes + 255) & ~(size_t)255;
    return p;
  };
  int* ptr   = (int*)alloc((size_t)(n + 1) * sizeof(int));
  int* cur   = (int*)alloc((size_t)n * sizeof(int));
  int* bsum  = (int*)alloc(512 * sizeof(int));
  int* srcs  = (int*)alloc((size_t)E * sizeof(int));
  unsigned short* Ah = (unsigned short*)alloc((size_t)n * 128 * sizeof(unsigned short));
  unsigned short* Bh = (unsigned short*)alloc((size_t)n * 128 * sizeof(unsigned short));
  float* A2  = (float*)alloc((size_t)n * 16 * sizeof(float));
  float* als = (float*)alloc((size_t)n * 8 * sizeof(float));
  float* ald = (float*)alloc((size_t)n * 8 * sizeof(float));
  unsigned short* P = (unsigned short*)alloc((size_t)163840 * sizeof(unsigned short));
  unsigned short* P0 = P;
  unsigned short* P1 = P + 131072;
  unsigned short* P2 = P + 147456;

  int eb = (E + 255) / 256;
  int nb = (n + 255) / 256;
  hipMemsetAsync(cur, 0, (size_t)n * sizeof(int), stream);
  k_deg<<<eb, 256, 0, stream>>>(ei, cur, E);
  k_scan1<<<nb, 256, 0, stream>>>(cur, ptr, bsum, n);   // zeroes cur in place
  k_scan2<<<1, 256, 0, stream>>>(bsum, nb);
  k_scan3<<<nb, 256, 0, stream>>>(ptr, bsum, n);
  k_scatter<<<eb, 256, 0, stream>>>(ei, ptr, cur, srcs, E);
  k_wpackall<<<640, 256, 0, stream>>>(W0, W1, W2, P, GENES);

  int mgb  = (n + 63) / 64;
  int aggb = (int)(((long)n * 64 + 255) / 256);

  // layer 0: x @ W0 -> Ah fp16 (+als/ald), aggregate -> Bh fp16 (ELU)
  k_mgemm10<8, 32, false, true><<<mgb, 512, 0, stream>>>(
      x, P0, Ah, als, ald, as0, ad0, n, GENES, 128);
  k_agg128h<<<aggb, 256, 0, stream>>>(Ah, als, ald, ptr, srcs, b0, Bh, n);

  // layer 1: Bh @ W1 -> Ah fp16 (+als/ald), aggregate -> Bh fp16 (ELU)
  k_mgemm10<8, 4, true, true><<<mgb, 512, 0, stream>>>(
      Bh, P1, Ah, als, ald, as1, ad1, n, 128, 128);
  k_agg128h<<<aggb, 256, 0, stream>>>(Ah, als, ald, ptr, srcs, b1, Bh, n);

  // layer 2: Bh @ W2 (padded) -> A2 fp32 [n][16] (+als/ald H=1), aggregate -> out
  k_mgemm10<1, 4, true, false><<<mgb, 512, 0, stream>>>(
      Bh, P2, A2, als, ald, as2, ad2, n, 128, 16);
  k_agg16<<<aggb, 256, 0, stream>>>(A2, als, ald, ptr, srcs, b2, out, n, 16);
}

// Round 17
// 273.423 us; speedup vs baseline: 1.0313x; 1.0313x over previous
//
#include <hip/hip_runtime.h>
#include <hip/hip_bf16.h>
#include <math.h>

#define GENES 1000

typedef __attribute__((ext_vector_type(8))) _Float16 half8;
typedef __attribute__((ext_vector_type(4))) float f32x4;
typedef __attribute__((ext_vector_type(4))) unsigned int uint4v;
typedef __attribute__((ext_vector_type(2))) unsigned int uint2v;

__device__ inline float f16lo(unsigned int v) {
  return (float)__builtin_bit_cast(_Float16, (unsigned short)(v & 0xffffu));
}
__device__ inline float f16hi(unsigned int v) {
  return (float)__builtin_bit_cast(_Float16, (unsigned short)(v >> 16));
}
__device__ inline unsigned int pk(float a, float b) {
  return __builtin_bit_cast(unsigned int, __builtin_amdgcn_cvt_pkrtz(a, b));
}

// async global->LDS, 16B per lane. Dest must be wave-uniform base + lane*16
// (m104); source address is per-lane (enables pre-swizzled sources, m173).
__device__ inline void gload16(const void* g, void* l) {
  __builtin_amdgcn_global_load_lds(
      (const __attribute__((address_space(1))) unsigned int*)g,
      (__attribute__((address_space(3))) unsigned int*)l, 16, 0, 0);
}

// ---------------- CSR build ----------------

__global__ void k_deg(const int* __restrict__ ei, int* __restrict__ deg, int E) {
  int e = blockIdx.x * blockDim.x + threadIdx.x;
  if (e < E) atomicAdd(&deg[ei[E + e]], 1);
}

// reads deg, zeroes it in place (saves a memset dispatch)
__global__ void k_scan1(int* __restrict__ deg, int* __restrict__ ptr,
                        int* __restrict__ bsum, int n) {
  __shared__ int ws[4];
  int t = threadIdx.x, b = blockIdx.x;
  int i = b * 256 + t;
  int lane = t & 63, w = t >> 6;
  int x = 0;
  if (i < n) { x = deg[i]; deg[i] = 0; }
  #pragma unroll
  for (int d = 1; d < 64; d <<= 1) {
    int y = __shfl_up(x, d);
    if (lane >= d) x += y;
  }
  if (lane == 63) ws[w] = x;
  __syncthreads();
  if (t == 0) {
    int s = 0;
    #pragma unroll
    for (int k = 0; k < 4; ++k) { s += ws[k]; ws[k] = s; }
  }
  __syncthreads();
  int incl = x + (w ? ws[w - 1] : 0);
  if (i < n) ptr[i + 1] = incl;
  if (t == 255) bsum[b] = incl;
  if (i == 0) ptr[0] = 0;
}

__global__ void k_scan2(int* __restrict__ bsum, int nb) {
  __shared__ int ws[4];
  int t = threadIdx.x;
  int lane = t & 63, w = t >> 6;
  int v = (t < nb) ? bsum[t] : 0;
  int x = v;
  #pragma unroll
  for (int d = 1; d < 64; d <<= 1) {
    int y = __shfl_up(x, d);
    if (lane >= d) x += y;
  }
  if (lane == 63) ws[w] = x;
  __syncthreads();
  if (t == 0) {
    int s = 0;
    #pragma unroll
    for (int k = 0; k < 4; ++k) { s += ws[k]; ws[k] = s; }
  }
  __syncthreads();
  int incl = x + (w ? ws[w - 1] : 0);
  if (t < nb) bsum[t] = incl - v;
}

__global__ void k_scan3(int* __restrict__ ptr, const int* __restrict__ bsum, int n) {
  int i = blockIdx.x * 256 + threadIdx.x;
  if (i < n) ptr[i + 1] += bsum[blockIdx.x];
}

__global__ void k_scatter(const int* __restrict__ ei, const int* __restrict__ ptr,
                          int* __restrict__ cur, int* __restrict__ srcs, int E) {
  int e = blockIdx.x * blockDim.x + threadIdx.x;
  if (e >= E) return;
  int d = ei[E + e];
  int pos = ptr[d] + atomicAdd(&cur[d], 1);
  srcs[pos] = ei[e];
}

// ---------------- W pack (all 3 layers, one launch), q-major per 32-k step -----
// element idx = s*4096 + q*1024 + col*8 + j  (k = s*32 + q*8 + j), fp16.
// W0 -> 32 ksteps (K padded 1024, zero-pad), W1 -> 4, W2 -> 4 (cols pad 128).

__global__ void k_wpackall(const float* __restrict__ W0, const float* __restrict__ W1,
                           const float* __restrict__ W2, unsigned short* __restrict__ P,
                           int K0) {
  int t = blockIdx.x * blockDim.x + threadIdx.x;  // 163840 total
  if (t >= 163840) return;
  const float* W; int K, N, e;
  if (t < 131072)      { W = W0; K = K0;  N = 128; e = t; }
  else if (t < 147456) { W = W1; K = 128; N = 128; e = t - 131072; }
  else                 { W = W2; K = 128; N = 16;  e = t - 147456; }
  int s = e >> 12, rem = e & 4095;
  int q = rem >> 10, col = (rem >> 3) & 127, j = rem & 7;
  int k = s * 32 + q * 8 + j;
  float v = (k < K && col < N) ? W[(long)k * N + col] : 0.f;
  _Float16 h = (_Float16)v;
  P[t] = __builtin_bit_cast(unsigned short, h);
}

// ---------------- layer-0 MFMA GEMM: global_load_lds staging (m97 shape) -------
// 512 threads = 8 waves (4 row-groups x 2 col-groups); BM=64, BN=128, BK=32,
// NST=32 (K zero-padded to 1024 via W pad; A over-reads <=96B past row, page-safe).
// Staging: one width-16 global_load_lds per thread per k-step for A (fp32 tile,
// 8KB: [64 row][128B], source seg pre-swizzled seg^=(row&7)) and for B (fp16
// packed, 8KB linear). No staging VGPRs at all -> nothing for the compiler to
// collapse (rounds 5-16 lesson). Fragment reads: 2-way bank-aliased (free).
// LDS 32KB dbuf -> 4 blocks/CU = 32 waves/CU. One barrier per k-step.
// Fused epilogue: fp16 out + als/ald.

__global__ __launch_bounds__(512) void k_mgemm11(
    const float* __restrict__ A, const unsigned short* __restrict__ Pb,
    unsigned short* __restrict__ outp, float* __restrict__ als,
    float* __restrict__ ald, const float* __restrict__ avs,
    const float* __restrict__ avd, int M, int K) {
  __shared__ __align__(16) char lds[32768];  // A dbuf 2x8KB | B dbuf 2x8KB

  int t = threadIdx.x, lane = t & 63, wv = t >> 6;
  int r15 = lane & 15, q = lane >> 4;
  int wr = wv >> 1, wc = wv & 1;
  long row0 = (long)blockIdx.x * 64;

  // staging: thread -> (row = wv*8 + lane>>3, LDS seg = lane&7).
  // LDS dest t*16 == row*128 + seg*16 (wave-uniform slab + lane*16: OK).
  int srow = wv * 8 + (lane >> 3);
  int sseg = lane & 7;
  int gseg = sseg ^ (srow & 7);          // pre-swizzled global source segment
  long arow = row0 + srow; if (arow >= M) arow = M - 1;
  const char* gA = (const char*)(A + arow * (long)K) + gseg * 16;
  const char* gB = (const char*)Pb + t * 16;

  f32x4 acc[4];
  #pragma unroll
  for (int nt = 0; nt < 4; ++nt) acc[nt] = (f32x4){0.f, 0.f, 0.f, 0.f};

  auto issue = [&](int s) {
    char* Ab = lds + (s & 1) * 8192;
    char* Bb = lds + 16384 + (s & 1) * 8192;
    gload16(gA + (size_t)s * 128, Ab + t * 16);
    gload16(gB + (size_t)s * 8192, Bb + t * 16);
  };
  auto compute = [&](int s) {
    const char* Ab = lds + (s & 1) * 8192;
    const char* Bb = lds + 16384 + (s & 1) * 8192;
    int row = wr * 16 + r15;
    int sw = row & 7;
    uint4v alo = *(const uint4v*)(Ab + row * 128 + ((2 * q) ^ sw) * 16);
    uint4v ahi = *(const uint4v*)(Ab + row * 128 + ((2 * q + 1) ^ sw) * 16);
    float4 lo = __builtin_bit_cast(float4, alo);
    float4 hi = __builtin_bit_cast(float4, ahi);
    uint4v au;
    au[0] = pk(lo.x, lo.y); au[1] = pk(lo.z, lo.w);
    au[2] = pk(hi.x, hi.y); au[3] = pk(hi.z, hi.w);
    half8 af = __builtin_bit_cast(half8, au);
    #pragma unroll
    for (int nt = 0; nt < 4; ++nt) {
      half8 bf = *(const half8*)(Bb + q * 2048 + (wc * 64 + nt * 16 + r15) * 16);
      acc[nt] = __builtin_amdgcn_mfma_f32_16x16x32_f16(af, bf, acc[nt], 0, 0, 0);
    }
  };

  issue(0);
  __syncthreads();
  for (int s = 0; s < 32; ++s) {
    if (s + 1 < 32) issue(s + 1);   // into buf freed at barrier end of s-1
    compute(s);
    __syncthreads();                // drains s+1 loads; buf[s&1] free for s+2
  }

  // ---- epilogue: C/D layout col=lane&15, row=(lane>>4)*4+i ----
  long rbase = row0 + wr * 16 + q * 4;
  #pragma unroll
  for (int i = 0; i < 4; ++i) {
    long r = rbase + i;
    if (r < M) {
      #pragma unroll
      for (int nt = 0; nt < 4; ++nt) {
        int col = wc * 64 + nt * 16 + r15;
        _Float16 hv = (_Float16)acc[nt][i];
        outp[r * 128 + col] = __builtin_bit_cast(unsigned short, hv);
      }
    }
  }
  #pragma unroll
  for (int nt = 0; nt < 4; ++nt) {
    int head = wc * 4 + nt;
    float cs = avs[head * 16 + r15];
    float cd = avd[head * 16 + r15];
    #pragma unroll
    for (int i = 0; i < 4; ++i) {
      float s1 = acc[nt][i] * cs;
      float s2 = acc[nt][i] * cd;
      #pragma unroll
      for (int d = 1; d < 16; d <<= 1) {
        s1 += __shfl_xor(s1, d);
        s2 += __shfl_xor(s2, d);
      }
      if (r15 == 0) {
        long r = rbase + i;
        if (r < M) { als[r * 8 + head] = s1; ald[r * 8 + head] = s2; }
      }
    }
  }
}

// ---------------- MFMA fp16 GEMM (layers 1,2): 64-VGPR dbuf (round-13) --------

template<int HH, bool AF16, bool OF16>
__global__ __launch_bounds__(512) void k_mgemm7(
    const void* __restrict__ Ap, const unsigned short* __restrict__ Pb,
    void* __restrict__ outp, float* __restrict__ als, float* __restrict__ ald,
    const float* __restrict__ avs, const float* __restrict__ avd,
    int M, int K, int nst, int ldc) {
  __shared__ __align__(16) char lds[24576];
  char* bA0 = lds;
  char* bA1 = lds + 4096;
  char* bB0 = lds + 8192;
  char* bB1 = lds + 16384;

  int t = threadIdx.x, lane = t & 63;
  int r15 = lane & 15, q = lane >> 4;
  int wv = t >> 6;
  int wr = wv >> 1, wc = wv & 1;
  long row0 = (long)blockIdx.x * 64;

  int srow = t >> 3, sseg = t & 7;
  long arow = row0 + srow; if (arow >= M) arow = M - 1;
  const float* pa32 = (const float*)Ap + arow * (long)K;
  const unsigned short* pa16 = (const unsigned short*)Ap + arow * (long)K;

  f32x4 acc[4];
  #pragma unroll
  for (int nt = 0; nt < 4; ++nt) acc[nt] = (f32x4){0.f, 0.f, 0.f, 0.f};

  uint4v rA0, rA1, rB0, rB1;
  uint2v sA0, sA1;

  auto loadA = [&](int s, uint4v& r32, uint2v& r16) {
    int k0 = s * 32 + sseg * 4;
    if constexpr (AF16) {
      r16 = (k0 < K) ? *(const uint2v*)(pa16 + k0) : (uint2v){0u, 0u};
    } else {
      r32 = (k0 < K) ? *(const uint4v*)(pa32 + k0) : (uint4v){0u, 0u, 0u, 0u};
    }
  };
  auto writeA = [&](char* buf, uint4v r32, uint2v r16) {
    char* p = buf + ((sseg >> 1) * 1024 + srow * 16 + (sseg & 1) * 8);
    if constexpr (AF16) {
      *(uint2v*)p = r16;
    } else {
      float4 f = __builtin_bit_cast(float4, r32);
      uint2v h;
      h[0] = pk(f.x, f.y);
      h[1] = pk(f.z, f.w);
      *(uint2v*)p = h;
    }
  };
  auto loadB = [&](int s, uint4v& r) {
    r = *(const uint4v*)(Pb + (size_t)s * 4096 + t * 8);
  };
  auto writeB = [&](char* buf, uint4v r) {
    *(uint4v*)(buf + t * 16) = r;
  };
  auto compute = [&](const char* bA, const char* bB) {
    half8 af = *(const half8*)(bA + q * 1024 + (wr * 16 + r15) * 16);
    #pragma unroll
    for (int nt = 0; nt < 4; ++nt) {
      half8 bf = *(const half8*)(bB + q * 2048 + (wc * 64 + nt * 16 + r15) * 16);
      acc[nt] = __builtin_amdgcn_mfma_f32_16x16x32_f16(af, bf, acc[nt], 0, 0, 0);
    }
  };

  loadA(0, rA0, sA0); loadB(0, rB0);
  if (nst > 1) { loadA(1, rA1, sA1); loadB(1, rB1); }
  writeA(bA0, rA0, sA0); writeB(bB0, rB0);
  __syncthreads();

  for (int s = 0; s < nst; s += 2) {
    if (s + 2 < nst) { loadA(s + 2, rA0, sA0); loadB(s + 2, rB0); }
    compute(bA0, bB0);
    if (s + 1 < nst) { writeA(bA1, rA1, sA1); writeB(bB1, rB1); }
    __syncthreads();
    if (s + 1 < nst) {
      if (s + 3 < nst) { loadA(s + 3, rA1, sA1); loadB(s + 3, rB1); }
      compute(bA1, bB1);
      if (s + 2 < nst) { writeA(bA0, rA0, sA0); writeB(bB0, rB0); }
      __syncthreads();
    }
  }

  long rbase = row0 + wr * 16 + q * 4;
  if constexpr (OF16) {
    unsigned short* o16 = (unsigned short*)outp;
    #pragma unroll
    for (int i = 0; i < 4; ++i) {
      long r = rbase + i;
      if (r < M) {
        #pragma unroll
        for (int nt = 0; nt < 4; ++nt) {
          int col = wc * 64 + nt * 16 + r15;
          _Float16 hv = (_Float16)acc[nt][i];
          o16[r * ldc + col] = __builtin_bit_cast(unsigned short, hv);
        }
      }
    }
  } else {
    float* o32 = (float*)outp;
    #pragma unroll
    for (int i = 0; i < 4; ++i) {
      long r = rbase + i;
      if (r < M) {
        #pragma unroll
        for (int nt = 0; nt < 4; ++nt) {
          int col = wc * 64 + nt * 16 + r15;
          if (col < ldc) o32[r * ldc + col] = acc[nt][i];
        }
      }
    }
  }
  #pragma unroll
  for (int nt = 0; nt < 4; ++nt) {
    int head = wc * 4 + nt;
    if (head < HH) {
      float cs = avs[head * 16 + r15];
      float cd = avd[head * 16 + r15];
      #pragma unroll
      for (int i = 0; i < 4; ++i) {
        float s1 = acc[nt][i] * cs;
        float s2 = acc[nt][i] * cd;
        #pragma unroll
        for (int d = 1; d < 16; d <<= 1) {
          s1 += __shfl_xor(s1, d);
          s2 += __shfl_xor(s2, d);
        }
        if (r15 == 0) {
          long r = rbase + i;
          if (r < M) { als[r * HH + head] = s1; ald[r * HH + head] = s2; }
        }
      }
    }
  }
}

// ---------------- per-dst aggregation, H=8, C=16, fp16 h, ELU ------------------
// Split-wave halves, alternate edges, 4-edge batches; no max pass.

__global__ void k_agg128h(const unsigned short* __restrict__ h,
                          const float* __restrict__ als, const float* __restrict__ ald,
                          const int* __restrict__ ptr, const int* __restrict__ srcs,
                          const float* __restrict__ bias,
                          unsigned short* __restrict__ out, int n) {
  int wid = (int)(((long)blockIdx.x * blockDim.x + threadIdx.x) >> 6);
  if (wid >= n) return;
  int lane = threadIdx.x & 63;
  int half = lane >> 5, l5 = lane & 31;
  int c0 = 4 * l5;
  int hB = l5 >> 2;
  int p0 = ptr[wid], deg = ptr[wid + 1] - p0;
  float aldB = ald[wid * 8 + hB];
  float a0 = 0.f, a1 = 0.f, a2 = 0.f, a3 = 0.f, dsum = 0.f;
  int j = half;
  for (; j + 6 < deg; j += 8) {
    int s0 = srcs[p0 + j],     s1 = srcs[p0 + j + 2];
    int s2 = srcs[p0 + j + 4], s3 = srcs[p0 + j + 6];
    float l0 = als[s0 * 8 + hB] + aldB;
    float l1 = als[s1 * 8 + hB] + aldB;
    float l2 = als[s2 * 8 + hB] + aldB;
    float l3 = als[s3 * 8 + hB] + aldB;
    uint2v h0 = *(const uint2v*)(h + (long)s0 * 128 + c0);
    uint2v h1 = *(const uint2v*)(h + (long)s1 * 128 + c0);
    uint2v h2 = *(const uint2v*)(h + (long)s2 * 128 + c0);
    uint2v h3 = *(const uint2v*)(h + (long)s3 * 128 + c0);
    l0 = l0 > 0.f ? l0 : 0.2f * l0;
    l1 = l1 > 0.f ? l1 : 0.2f * l1;
    l2 = l2 > 0.f ? l2 : 0.2f * l2;
    l3 = l3 > 0.f ? l3 : 0.2f * l3;
    float e0 = __expf(l0), e1 = __expf(l1), e2 = __expf(l2), e3 = __expf(l3);
    dsum += e0 + e1 + e2 + e3;
    a0 += e0 * f16lo(h0[0]) + e1 * f16lo(h1[0]) + e2 * f16lo(h2[0]) + e3 * f16lo(h3[0]);
    a1 += e0 * f16hi(h0[0]) + e1 * f16hi(h1[0]) + e2 * f16hi(h2[0]) + e3 * f16hi(h3[0]);
    a2 += e0 * f16lo(h0[1]) + e1 * f16lo(h1[1]) + e2 * f16lo(h2[1]) + e3 * f16lo(h3[1]);
    a3 += e0 * f16hi(h0[1]) + e1 * f16hi(h1[1]) + e2 * f16hi(h2[1]) + e3 * f16hi(h3[1]);
  }
  for (; j < deg; j += 2) {
    int s = srcs[p0 + j];
    float l = als[s * 8 + hB] + aldB;
    l = l > 0.f ? l : 0.2f * l;
    float e = __expf(l);
    uint2v hv = *(const uint2v*)(h + (long)s * 128 + c0);
    dsum += e;
    a0 += e * f16lo(hv[0]);
    a1 += e * f16hi(hv[0]);
    a2 += e * f16lo(hv[1]);
    a3 += e * f16hi(hv[1]);
  }
  a0 += __shfl_xor(a0, 32);
  a1 += __shfl_xor(a1, 32);
  a2 += __shfl_xor(a2, 32);
  a3 += __shfl_xor(a3, 32);
  dsum += __shfl_xor(dsum, 32);
  if (half == 0) {
    float inv = 1.f / (dsum + 1e-16f);
    float o0 = a0 * inv + bias[c0];
    float o1 = a1 * inv + bias[c0 + 1];
    float o2 = a2 * inv + bias[c0 + 2];
    float o3 = a3 * inv + bias[c0 + 3];
    o0 = o0 > 0.f ? o0 : (__expf(o0) - 1.f);
    o1 = o1 > 0.f ? o1 : (__expf(o1) - 1.f);
    o2 = o2 > 0.f ? o2 : (__expf(o2) - 1.f);
    o3 = o3 > 0.f ? o3 : (__expf(o3) - 1.f);
    uint2v po;
    po[0] = __builtin_bit_cast(unsigned int, __builtin_amdgcn_cvt_pkrtz(o0, o1));
    po[1] = __builtin_bit_cast(unsigned int, __builtin_amdgcn_cvt_pkrtz(o2, o3));
    *(uint2v*)(out + (long)wid * 128 + c0) = po;
  }
}

// ---------------- per-dst aggregation, H=1, C=16, fp32, no max, 4-batch --------

__global__ void k_agg16(const float* __restrict__ h, const float* __restrict__ als,
                        const float* __restrict__ ald, const int* __restrict__ ptr,
                        const int* __restrict__ srcs, const float* __restrict__ bias,
                        float* __restrict__ out, int n, int lda) {
  int wid = (int)(((long)blockIdx.x * blockDim.x + threadIdx.x) >> 6);
  if (wid >= n) return;
  int lane = threadIdx.x & 63;
  int p0 = ptr[wid], deg = ptr[wid + 1] - p0;
  float aldv = ald[wid];
  int g = lane >> 4, c = lane & 15;
  float acc = 0.f, dsum = 0.f;
  int j = g;
  for (; j + 12 < deg; j += 16) {
    int s0 = srcs[p0 + j],     s1 = srcs[p0 + j + 4];
    int s2 = srcs[p0 + j + 8], s3 = srcs[p0 + j + 12];
    float l0 = als[s0] + aldv, l1 = als[s1] + aldv;
    float l2 = als[s2] + aldv, l3 = als[s3] + aldv;
    float h0 = h[(long)s0 * lda + c], h1 = h[(long)s1 * lda + c];
    float h2 = h[(long)s2 * lda + c], h3 = h[(long)s3 * lda + c];
    l0 = l0 > 0.f ? l0 : 0.2f * l0;
    l1 = l1 > 0.f ? l1 : 0.2f * l1;
    l2 = l2 > 0.f ? l2 : 0.2f * l2;
    l3 = l3 > 0.f ? l3 : 0.2f * l3;
    float e0 = __expf(l0), e1 = __expf(l1), e2 = __expf(l2), e3 = __expf(l3);
    dsum += e0 + e1 + e2 + e3;
    acc += e0 * h0 + e1 * h1 + e2 * h2 + e3 * h3;
  }
  for (; j < deg; j += 4) {
    int s = srcs[p0 + j];
    float l = als[s] + aldv;
    l = l > 0.f ? l : 0.2f * l;
    float e = __expf(l);
    dsum += e;
    acc += e * h[(long)s * lda + c];
  }
  #pragma unroll
  for (int d = 16; d < 64; d <<= 1) {
    acc += __shfl_xor(acc, d);
    dsum += __shfl_xor(dsum, d);
  }
  if (lane < 16)
    out[(long)wid * 16 + lane] = acc / (dsum + 1e-16f) + bias[lane];
}

// ---------------- launch ----------------

extern "C" void kernel_launch(void* const* d_in, const int* in_sizes, int n_in,
                              void* d_out, int out_size, void* d_ws, size_t ws_size,
                              hipStream_t stream) {
  const float* x  = (const float*)d_in[0];
  const int*   ei = (const int*)d_in[1];
  const float* W0 = (const float*)d_in[2];
  const float* as0= (const float*)d_in[3];
  const float* ad0= (const float*)d_in[4];
  const float* b0 = (const float*)d_in[5];
  const float* W1 = (const float*)d_in[6];
  const float* as1= (const float*)d_in[7];
  const float* ad1= (const float*)d_in[8];
  const float* b1 = (const float*)d_in[9];
  const float* W2 = (const float*)d_in[10];
  const float* as2= (const float*)d_in[11];
  const float* ad2= (const float*)d_in[12];
  const float* b2 = (const float*)d_in[13];
  float* out = (float*)d_out;

  int E = in_sizes[1] / 2;
  int n = in_sizes[0] / GENES;

  char* ws = (char*)d_ws;
  size_t off = 0;
  auto alloc = [&](size_t bytes) {
    void* p = ws + off;
    off = (off + bytes + 255) & ~(size_t)255;
    return p;
  };
  int* ptr   = (int*)alloc((size_t)(n + 1) * sizeof(int));
  int* cur   = (int*)alloc((size_t)n * sizeof(int));
  int* bsum  = (int*)alloc(512 * sizeof(int));
  int* srcs  = (int*)alloc((size_t)E * sizeof(int));
  unsigned short* Ah = (unsigned short*)alloc((size_t)n * 128 * sizeof(unsigned short));
  unsigned short* Bh = (unsigned short*)alloc((size_t)n * 128 * sizeof(unsigned short));
  float* A2  = (float*)alloc((size_t)n * 16 * sizeof(float));
  float* als = (float*)alloc((size_t)n * 8 * sizeof(float));
  float* ald = (float*)alloc((size_t)n * 8 * sizeof(float));
  unsigned short* P = (unsigned short*)alloc((size_t)163840 * sizeof(unsigned short));
  unsigned short* P0 = P;
  unsigned short* P1 = P + 131072;
  unsigned short* P2 = P + 147456;

  int eb = (E + 255) / 256;
  int nb = (n + 255) / 256;
  hipMemsetAsync(cur, 0, (size_t)n * sizeof(int), stream);
  k_deg<<<eb, 256, 0, stream>>>(ei, cur, E);
  k_scan1<<<nb, 256, 0, stream>>>(cur, ptr, bsum, n);   // zeroes cur in place
  k_scan2<<<1, 256, 0, stream>>>(bsum, nb);
  k_scan3<<<nb, 256, 0, stream>>>(ptr, bsum, n);
  k_scatter<<<eb, 256, 0, stream>>>(ei, ptr, cur, srcs, E);
  k_wpackall<<<640, 256, 0, stream>>>(W0, W1, W2, P, GENES);

  int mgb  = (n + 63) / 64;
  int aggb = (int)(((long)n * 64 + 255) / 256);

  // layer 0: x @ W0 -> Ah fp16 (+als/ald) via global_load_lds GEMM, agg -> Bh
  k_mgemm11<<<mgb, 512, 0, stream>>>(x, P0, Ah, als, ald, as0, ad0, n, GENES);
  k_agg128h<<<aggb, 256, 0, stream>>>(Ah, als, ald, ptr, srcs, b0, Bh, n);

  // layer 1: Bh @ W1 -> Ah fp16 (+als/ald), aggregate -> Bh fp16 (ELU)
  k_mgemm7<8, true, true><<<mgb, 512, 0, stream>>>(
      Bh, P1, Ah, als, ald, as1, ad1, n, 128, 4, 128);
  k_agg128h<<<aggb, 256, 0, stream>>>(Ah, als, ald, ptr, srcs, b1, Bh, n);

  // layer 2: Bh @ W2 (padded) -> A2 fp32 [n][16] (+als/ald H=1), aggregate -> out
  k_mgemm7<1, true, false><<<mgb, 512, 0, stream>>>(
      Bh, P2, A2, als, ald, as2, ad2, n, 128, 4, 16);
  k_agg16<<<aggb, 256, 0, stream>>>(A2, als, ald, ptr, srcs, b2, out, n, 16);
}

// Round 18
// 272.943 us; speedup vs baseline: 1.0331x; 1.0018x over previous
//
#include <hip/hip_runtime.h>
#include <hip/hip_bf16.h>
#include <math.h>

#define GENES 1000

typedef __attribute__((ext_vector_type(8))) _Float16 half8;
typedef __attribute__((ext_vector_type(4))) float f32x4;
typedef __attribute__((ext_vector_type(4))) unsigned int uint4v;
typedef __attribute__((ext_vector_type(2))) unsigned int uint2v;

__device__ inline float f16lo(unsigned int v) {
  return (float)__builtin_bit_cast(_Float16, (unsigned short)(v & 0xffffu));
}
__device__ inline float f16hi(unsigned int v) {
  return (float)__builtin_bit_cast(_Float16, (unsigned short)(v >> 16));
}
__device__ inline unsigned int pk(float a, float b) {
  return __builtin_bit_cast(unsigned int, __builtin_amdgcn_cvt_pkrtz(a, b));
}

// ---------------- CSR build ----------------

// reads deg, zeroes it in place (saves a memset dispatch)
__global__ void k_scan1(int* __restrict__ deg, int* __restrict__ ptr,
                        int* __restrict__ bsum, int n) {
  __shared__ int ws[4];
  int t = threadIdx.x, b = blockIdx.x;
  int i = b * 256 + t;
  int lane = t & 63, w = t >> 6;
  int x = 0;
  if (i < n) { x = deg[i]; deg[i] = 0; }
  #pragma unroll
  for (int d = 1; d < 64; d <<= 1) {
    int y = __shfl_up(x, d);
    if (lane >= d) x += y;
  }
  if (lane == 63) ws[w] = x;
  __syncthreads();
  if (t == 0) {
    int s = 0;
    #pragma unroll
    for (int k = 0; k < 4; ++k) { s += ws[k]; ws[k] = s; }
  }
  __syncthreads();
  int incl = x + (w ? ws[w - 1] : 0);
  if (i < n) ptr[i + 1] = incl;
  if (t == 255) bsum[b] = incl;
  if (i == 0) ptr[0] = 0;
}

__global__ void k_scan2(int* __restrict__ bsum, int nb) {
  __shared__ int ws[4];
  int t = threadIdx.x;
  int lane = t & 63, w = t >> 6;
  int v = (t < nb) ? bsum[t] : 0;
  int x = v;
  #pragma unroll
  for (int d = 1; d < 64; d <<= 1) {
    int y = __shfl_up(x, d);
    if (lane >= d) x += y;
  }
  if (lane == 63) ws[w] = x;
  __syncthreads();
  if (t == 0) {
    int s = 0;
    #pragma unroll
    for (int k = 0; k < 4; ++k) { s += ws[k]; ws[k] = s; }
  }
  __syncthreads();
  int incl = x + (w ? ws[w - 1] : 0);
  if (t < nb) bsum[t] = incl - v;
}

__global__ void k_scan3(int* __restrict__ ptr, const int* __restrict__ bsum, int n) {
  int i = blockIdx.x * 256 + threadIdx.x;
  if (i < n) ptr[i + 1] += bsum[blockIdx.x];
}

// ---------------- W pack + degree count (fused, one launch) --------------------
// pack: element idx = s*4096 + q*1024 + col*8 + j (k = s*32+q*8+j), fp16.
// W0 -> 32 ksteps (K zero-padded to 1024), W1 -> 4, W2 -> 4 (cols pad 128).
// deg: one atomicAdd per edge (independent work, same launch).

__global__ void k_wpackdeg(const float* __restrict__ W0, const float* __restrict__ W1,
                           const float* __restrict__ W2, unsigned short* __restrict__ P,
                           int K0, const int* __restrict__ ei, int* __restrict__ deg,
                           int E) {
  int t = blockIdx.x * blockDim.x + threadIdx.x;
  if (t < 163840) {
    const float* W; int K, N, e;
    if (t < 131072)      { W = W0; K = K0;  N = 128; e = t; }
    else if (t < 147456) { W = W1; K = 128; N = 128; e = t - 131072; }
    else                 { W = W2; K = 128; N = 16;  e = t - 147456; }
    int s = e >> 12, rem = e & 4095;
    int q = rem >> 10, col = (rem >> 3) & 127, j = rem & 7;
    int k = s * 32 + q * 8 + j;
    float v = (k < K && col < N) ? W[(long)k * N + col] : 0.f;
    _Float16 h = (_Float16)v;
    P[t] = __builtin_bit_cast(unsigned short, h);
  }
  if (t < E) atomicAdd(&deg[ei[E + t]], 1);
}

// ---------------- layer-0 MFMA GEMM: DRAM-linear A staging ---------------------
// BM=32, 512 threads = 8 waves (2 row-groups x 4 col-groups).
// Theory (r18): previous 8 structures all read A as 64x128B @4000B stride per
// k-step -> chip-wide scattered 128B DRAM requests (~1 TB/s). Here each block's
// A is a CONTIGUOUS 128KB region, loaded once by whole-row linear sweeps
// (wave-consecutive 1KB loads -> DRAM row hits), cvt to fp16 into LDS (66KB,
// [q][ks(528B)][row(16B)]), ONE barrier, then 32 barrier-free MFMA k-steps
// with B straight from L2 into depth-2 named regs. 2 blocks/CU.
// Fused: CSR scatter (independent) in prologue; epilogue fp16 out + als/ald.

__global__ __launch_bounds__(512) void k_mgemm12(
    const float* __restrict__ A, const unsigned short* __restrict__ Pb,
    unsigned short* __restrict__ outp, float* __restrict__ als,
    float* __restrict__ ald, const float* __restrict__ avs,
    const float* __restrict__ avd, int M, int K,
    const int* __restrict__ ei, const int* __restrict__ ptr,
    int* __restrict__ cur, int* __restrict__ srcs, int E) {
  __shared__ __align__(16) char As[4 * 16896];   // [q][ks stride 528][row 16B]

  int t = threadIdx.x, lane = t & 63, wv = t >> 6;
  int r15 = lane & 15, q = lane >> 4;
  int rg = wv >> 2, cg = wv & 3;
  long row0 = (long)blockIdx.x * 32;

  // fused CSR scatter: 512 edges per block, hidden under the staging burst
  {
    int e = blockIdx.x * 512 + t;
    if (e < E) {
      int d = ei[E + e];
      int pos = ptr[d] + atomicAdd(&cur[d], 1);
      srcs[pos] = ei[e];
    }
  }

  // zero the k>=1000 pad region ([q=1..3][ks=31][row]) -- NaN safety
  if (t < 96) {
    int zq = 1 + (t >> 5), zr = t & 31;
    *(uint4v*)(As + zq * 16896 + 31 * 528 + zr * 16) = (uint4v){0u, 0u, 0u, 0u};
  }

  // stage A: wave wv sweeps rows wv*4..wv*4+3 linearly (1KB wave-loads)
  #pragma unroll
  for (int i = 0; i < 4; ++i) {
    int R = wv * 4 + i;
    long arow = row0 + R; if (arow >= M) arow = M - 1;
    const float* base = A + arow * (long)K;
    #pragma unroll
    for (int inst = 0; inst < 4; ++inst) {
      int off = inst * 256 + lane * 4;          // float index within row
      if (off + 4 <= K) {
        float4 v = *(const float4*)(base + off);
        uint2v h;
        h[0] = pk(v.x, v.y);
        h[1] = pk(v.z, v.w);
        int ks = off >> 5, qq = (off >> 3) & 3, j0 = off & 7;
        *(uint2v*)(As + qq * 16896 + ks * 528 + R * 16 + j0 * 2) = h;
      }
    }
  }
  __syncthreads();   // the only barrier

  f32x4 acc0 = (f32x4){0.f, 0.f, 0.f, 0.f};
  f32x4 acc1 = (f32x4){0.f, 0.f, 0.f, 0.f};

  // B: direct from L2 (packed, hot) into depth-2 named slots
  const char* pBl = (const char*)Pb + q * 2048 + (cg * 32 + r15) * 16;
  const char* pAf = As + q * 16896 + (rg * 16 + r15) * 16;
  uint4v b00, b01, b10, b11;

  auto issueB = [&](int s, int slot) {
    const char* p = pBl + (size_t)s * 8192;
    if (slot == 0) { b00 = *(const uint4v*)p; b01 = *(const uint4v*)(p + 256); }
    else           { b10 = *(const uint4v*)p; b11 = *(const uint4v*)(p + 256); }
  };

  issueB(0, 0);
  issueB(1, 1);
  #pragma unroll
  for (int s = 0; s < 32; ++s) {
    half8 af = *(const half8*)(pAf + s * 528);
    uint4v bn0 = (s & 1) ? b10 : b00;
    uint4v bn1 = (s & 1) ? b11 : b01;
    if (s + 2 < 32) issueB(s + 2, s & 1);
    acc0 = __builtin_amdgcn_mfma_f32_16x16x32_f16(af, __builtin_bit_cast(half8, bn0), acc0, 0, 0, 0);
    acc1 = __builtin_amdgcn_mfma_f32_16x16x32_f16(af, __builtin_bit_cast(half8, bn1), acc1, 0, 0, 0);
  }

  // ---- epilogue: C/D layout col=lane&15, row=(lane>>4)*4+i ----
  long rbase = row0 + rg * 16 + q * 4;
  #pragma unroll
  for (int i = 0; i < 4; ++i) {
    long r = rbase + i;
    if (r < M) {
      int col0 = cg * 32 + r15;
      _Float16 h0 = (_Float16)acc0[i];
      _Float16 h1 = (_Float16)acc1[i];
      outp[r * 128 + col0]      = __builtin_bit_cast(unsigned short, h0);
      outp[r * 128 + col0 + 16] = __builtin_bit_cast(unsigned short, h1);
    }
  }
  #pragma unroll
  for (int nt = 0; nt < 2; ++nt) {
    int head = cg * 2 + nt;
    float cs = avs[head * 16 + r15];
    float cd = avd[head * 16 + r15];
    #pragma unroll
    for (int i = 0; i < 4; ++i) {
      float av = nt ? acc1[i] : acc0[i];
      float s1 = av * cs;
      float s2 = av * cd;
      #pragma unroll
      for (int d = 1; d < 16; d <<= 1) {
        s1 += __shfl_xor(s1, d);
        s2 += __shfl_xor(s2, d);
      }
      if (r15 == 0) {
        long r = rbase + i;
        if (r < M) { als[r * 8 + head] = s1; ald[r * 8 + head] = s2; }
      }
    }
  }
}

// ---------------- MFMA fp16 GEMM (layers 1,2): 64-VGPR dbuf (round-13) --------

template<int HH, bool AF16, bool OF16>
__global__ __launch_bounds__(512) void k_mgemm7(
    const void* __restrict__ Ap, const unsigned short* __restrict__ Pb,
    void* __restrict__ outp, float* __restrict__ als, float* __restrict__ ald,
    const float* __restrict__ avs, const float* __restrict__ avd,
    int M, int K, int nst, int ldc) {
  __shared__ __align__(16) char lds[24576];
  char* bA0 = lds;
  char* bA1 = lds + 4096;
  char* bB0 = lds + 8192;
  char* bB1 = lds + 16384;

  int t = threadIdx.x, lane = t & 63;
  int r15 = lane & 15, q = lane >> 4;
  int wv = t >> 6;
  int wr = wv >> 1, wc = wv & 1;
  long row0 = (long)blockIdx.x * 64;

  int srow = t >> 3, sseg = t & 7;
  long arow = row0 + srow; if (arow >= M) arow = M - 1;
  const float* pa32 = (const float*)Ap + arow * (long)K;
  const unsigned short* pa16 = (const unsigned short*)Ap + arow * (long)K;

  f32x4 acc[4];
  #pragma unroll
  for (int nt = 0; nt < 4; ++nt) acc[nt] = (f32x4){0.f, 0.f, 0.f, 0.f};

  uint4v rA0, rA1, rB0, rB1;
  uint2v sA0, sA1;

  auto loadA = [&](int s, uint4v& r32, uint2v& r16) {
    int k0 = s * 32 + sseg * 4;
    if constexpr (AF16) {
      r16 = (k0 < K) ? *(const uint2v*)(pa16 + k0) : (uint2v){0u, 0u};
    } else {
      r32 = (k0 < K) ? *(const uint4v*)(pa32 + k0) : (uint4v){0u, 0u, 0u, 0u};
    }
  };
  auto writeA = [&](char* buf, uint4v r32, uint2v r16) {
    char* p = buf + ((sseg >> 1) * 1024 + srow * 16 + (sseg & 1) * 8);
    if constexpr (AF16) {
      *(uint2v*)p = r16;
    } else {
      float4 f = __builtin_bit_cast(float4, r32);
      uint2v h;
      h[0] = pk(f.x, f.y);
      h[1] = pk(f.z, f.w);
      *(uint2v*)p = h;
    }
  };
  auto loadB = [&](int s, uint4v& r) {
    r = *(const uint4v*)(Pb + (size_t)s * 4096 + t * 8);
  };
  auto writeB = [&](char* buf, uint4v r) {
    *(uint4v*)(buf + t * 16) = r;
  };
  auto compute = [&](const char* bA, const char* bB) {
    half8 af = *(const half8*)(bA + q * 1024 + (wr * 16 + r15) * 16);
    #pragma unroll
    for (int nt = 0; nt < 4; ++nt) {
      half8 bf = *(const half8*)(bB + q * 2048 + (wc * 64 + nt * 16 + r15) * 16);
      acc[nt] = __builtin_amdgcn_mfma_f32_16x16x32_f16(af, bf, acc[nt], 0, 0, 0);
    }
  };

  loadA(0, rA0, sA0); loadB(0, rB0);
  if (nst > 1) { loadA(1, rA1, sA1); loadB(1, rB1); }
  writeA(bA0, rA0, sA0); writeB(bB0, rB0);
  __syncthreads();

  for (int s = 0; s < nst; s += 2) {
    if (s + 2 < nst) { loadA(s + 2, rA0, sA0); loadB(s + 2, rB0); }
    compute(bA0, bB0);
    if (s + 1 < nst) { writeA(bA1, rA1, sA1); writeB(bB1, rB1); }
    __syncthreads();
    if (s + 1 < nst) {
      if (s + 3 < nst) { loadA(s + 3, rA1, sA1); loadB(s + 3, rB1); }
      compute(bA1, bB1);
      if (s + 2 < nst) { writeA(bA0, rA0, sA0); writeB(bB0, rB0); }
      __syncthreads();
    }
  }

  long rbase = row0 + wr * 16 + q * 4;
  if constexpr (OF16) {
    unsigned short* o16 = (unsigned short*)outp;
    #pragma unroll
    for (int i = 0; i < 4; ++i) {
      long r = rbase + i;
      if (r < M) {
        #pragma unroll
        for (int nt = 0; nt < 4; ++nt) {
          int col = wc * 64 + nt * 16 + r15;
          _Float16 hv = (_Float16)acc[nt][i];
          o16[r * ldc + col] = __builtin_bit_cast(unsigned short, hv);
        }
      }
    }
  } else {
    float* o32 = (float*)outp;
    #pragma unroll
    for (int i = 0; i < 4; ++i) {
      long r = rbase + i;
      if (r < M) {
        #pragma unroll
        for (int nt = 0; nt < 4; ++nt) {
          int col = wc * 64 + nt * 16 + r15;
          if (col < ldc) o32[r * ldc + col] = acc[nt][i];
        }
      }
    }
  }
  #pragma unroll
  for (int nt = 0; nt < 4; ++nt) {
    int head = wc * 4 + nt;
    if (head < HH) {
      float cs = avs[head * 16 + r15];
      float cd = avd[head * 16 + r15];
      #pragma unroll
      for (int i = 0; i < 4; ++i) {
        float s1 = acc[nt][i] * cs;
        float s2 = acc[nt][i] * cd;
        #pragma unroll
        for (int d = 1; d < 16; d <<= 1) {
          s1 += __shfl_xor(s1, d);
          s2 += __shfl_xor(s2, d);
        }
        if (r15 == 0) {
          long r = rbase + i;
          if (r < M) { als[r * HH + head] = s1; ald[r * HH + head] = s2; }
        }
      }
    }
  }
}

// ---------------- per-dst aggregation, H=8, C=16, fp16 h, ELU ------------------
// Split-wave halves, alternate edges, 4-edge batches; no max pass.

__global__ void k_agg128h(const unsigned short* __restrict__ h,
                          const float* __restrict__ als, const float* __restrict__ ald,
                          const int* __restrict__ ptr, const int* __restrict__ srcs,
                          const float* __restrict__ bias,
                          unsigned short* __restrict__ out, int n) {
  int wid = (int)(((long)blockIdx.x * blockDim.x + threadIdx.x) >> 6);
  if (wid >= n) return;
  int lane = threadIdx.x & 63;
  int half = lane >> 5, l5 = lane & 31;
  int c0 = 4 * l5;
  int hB = l5 >> 2;
  int p0 = ptr[wid], deg = ptr[wid + 1] - p0;
  float aldB = ald[wid * 8 + hB];
  float a0 = 0.f, a1 = 0.f, a2 = 0.f, a3 = 0.f, dsum = 0.f;
  int j = half;
  for (; j + 6 < deg; j += 8) {
    int s0 = srcs[p0 + j],     s1 = srcs[p0 + j + 2];
    int s2 = srcs[p0 + j + 4], s3 = srcs[p0 + j + 6];
    float l0 = als[s0 * 8 + hB] + aldB;
    float l1 = als[s1 * 8 + hB] + aldB;
    float l2 = als[s2 * 8 + hB] + aldB;
    float l3 = als[s3 * 8 + hB] + aldB;
    uint2v h0 = *(const uint2v*)(h + (long)s0 * 128 + c0);
    uint2v h1 = *(const uint2v*)(h + (long)s1 * 128 + c0);
    uint2v h2 = *(const uint2v*)(h + (long)s2 * 128 + c0);
    uint2v h3 = *(const uint2v*)(h + (long)s3 * 128 + c0);
    l0 = l0 > 0.f ? l0 : 0.2f * l0;
    l1 = l1 > 0.f ? l1 : 0.2f * l1;
    l2 = l2 > 0.f ? l2 : 0.2f * l2;
    l3 = l3 > 0.f ? l3 : 0.2f * l3;
    float e0 = __expf(l0), e1 = __expf(l1), e2 = __expf(l2), e3 = __expf(l3);
    dsum += e0 + e1 + e2 + e3;
    a0 += e0 * f16lo(h0[0]) + e1 * f16lo(h1[0]) + e2 * f16lo(h2[0]) + e3 * f16lo(h3[0]);
    a1 += e0 * f16hi(h0[0]) + e1 * f16hi(h1[0]) + e2 * f16hi(h2[0]) + e3 * f16hi(h3[0]);
    a2 += e0 * f16lo(h0[1]) + e1 * f16lo(h1[1]) + e2 * f16lo(h2[1]) + e3 * f16lo(h3[1]);
    a3 += e0 * f16hi(h0[1]) + e1 * f16hi(h1[1]) + e2 * f16hi(h2[1]) + e3 * f16hi(h3[1]);
  }
  for (; j < deg; j += 2) {
    int s = srcs[p0 + j];
    float l = als[s * 8 + hB] + aldB;
    l = l > 0.f ? l : 0.2f * l;
    float e = __expf(l);
    uint2v hv = *(const uint2v*)(h + (long)s * 128 + c0);
    dsum += e;
    a0 += e * f16lo(hv[0]);
    a1 += e * f16hi(hv[0]);
    a2 += e * f16lo(hv[1]);
    a3 += e * f16hi(hv[1]);
  }
  a0 += __shfl_xor(a0, 32);
  a1 += __shfl_xor(a1, 32);
  a2 += __shfl_xor(a2, 32);
  a3 += __shfl_xor(a3, 32);
  dsum += __shfl_xor(dsum, 32);
  if (half == 0) {
    float inv = 1.f / (dsum + 1e-16f);
    float o0 = a0 * inv + bias[c0];
    float o1 = a1 * inv + bias[c0 + 1];
    float o2 = a2 * inv + bias[c0 + 2];
    float o3 = a3 * inv + bias[c0 + 3];
    o0 = o0 > 0.f ? o0 : (__expf(o0) - 1.f);
    o1 = o1 > 0.f ? o1 : (__expf(o1) - 1.f);
    o2 = o2 > 0.f ? o2 : (__expf(o2) - 1.f);
    o3 = o3 > 0.f ? o3 : (__expf(o3) - 1.f);
    uint2v po;
    po[0] = __builtin_bit_cast(unsigned int, __builtin_amdgcn_cvt_pkrtz(o0, o1));
    po[1] = __builtin_bit_cast(unsigned int, __builtin_amdgcn_cvt_pkrtz(o2, o3));
    *(uint2v*)(out + (long)wid * 128 + c0) = po;
  }
}

// ---------------- per-dst aggregation, H=1, C=16, fp32, no max, 4-batch --------

__global__ void k_agg16(const float* __restrict__ h, const float* __restrict__ als,
                        const float* __restrict__ ald, const int* __restrict__ ptr,
                        const int* __restrict__ srcs, const float* __restrict__ bias,
                        float* __restrict__ out, int n, int lda) {
  int wid = (int)(((long)blockIdx.x * blockDim.x + threadIdx.x) >> 6);
  if (wid >= n) return;
  int lane = threadIdx.x & 63;
  int p0 = ptr[wid], deg = ptr[wid + 1] - p0;
  float aldv = ald[wid];
  int g = lane >> 4, c = lane & 15;
  float acc = 0.f, dsum = 0.f;
  int j = g;
  for (; j + 12 < deg; j += 16) {
    int s0 = srcs[p0 + j],     s1 = srcs[p0 + j + 4];
    int s2 = srcs[p0 + j + 8], s3 = srcs[p0 + j + 12];
    float l0 = als[s0] + aldv, l1 = als[s1] + aldv;
    float l2 = als[s2] + aldv, l3 = als[s3] + aldv;
    float h0 = h[(long)s0 * lda + c], h1 = h[(long)s1 * lda + c];
    float h2 = h[(long)s2 * lda + c], h3 = h[(long)s3 * lda + c];
    l0 = l0 > 0.f ? l0 : 0.2f * l0;
    l1 = l1 > 0.f ? l1 : 0.2f * l1;
    l2 = l2 > 0.f ? l2 : 0.2f * l2;
    l3 = l3 > 0.f ? l3 : 0.2f * l3;
    float e0 = __expf(l0), e1 = __expf(l1), e2 = __expf(l2), e3 = __expf(l3);
    dsum += e0 + e1 + e2 + e3;
    acc += e0 * h0 + e1 * h1 + e2 * h2 + e3 * h3;
  }
  for (; j < deg; j += 4) {
    int s = srcs[p0 + j];
    float l = als[s] + aldv;
    l = l > 0.f ? l : 0.2f * l;
    float e = __expf(l);
    dsum += e;
    acc += e * h[(long)s * lda + c];
  }
  #pragma unroll
  for (int d = 16; d < 64; d <<= 1) {
    acc += __shfl_xor(acc, d);
    dsum += __shfl_xor(dsum, d);
  }
  if (lane < 16)
    out[(long)wid * 16 + lane] = acc / (dsum + 1e-16f) + bias[lane];
}

// ---------------- launch ----------------

extern "C" void kernel_launch(void* const* d_in, const int* in_sizes, int n_in,
                              void* d_out, int out_size, void* d_ws, size_t ws_size,
                              hipStream_t stream) {
  const float* x  = (const float*)d_in[0];
  const int*   ei = (const int*)d_in[1];
  const float* W0 = (const float*)d_in[2];
  const float* as0= (const float*)d_in[3];
  const float* ad0= (const float*)d_in[4];
  const float* b0 = (const float*)d_in[5];
  const float* W1 = (const float*)d_in[6];
  const float* as1= (const float*)d_in[7];
  const float* ad1= (const float*)d_in[8];
  const float* b1 = (const float*)d_in[9];
  const float* W2 = (const float*)d_in[10];
  const float* as2= (const float*)d_in[11];
  const float* ad2= (const float*)d_in[12];
  const float* b2 = (const float*)d_in[13];
  float* out = (float*)d_out;

  int E = in_sizes[1] / 2;
  int n = in_sizes[0] / GENES;

  char* ws = (char*)d_ws;
  size_t off = 0;
  auto alloc = [&](size_t bytes) {
    void* p = ws + off;
    off = (off + bytes + 255) & ~(size_t)255;
    return p;
  };
  int* ptr   = (int*)alloc((size_t)(n + 1) * sizeof(int));
  int* cur   = (int*)alloc((size_t)n * sizeof(int));
  int* bsum  = (int*)alloc(512 * sizeof(int));
  int* srcs  = (int*)alloc((size_t)E * sizeof(int));
  unsigned short* Ah = (unsigned short*)alloc((size_t)n * 128 * sizeof(unsigned short));
  unsigned short* Bh = (unsigned short*)alloc((size_t)n * 128 * sizeof(unsigned short));
  float* A2  = (float*)alloc((size_t)n * 16 * sizeof(float));
  float* als = (float*)alloc((size_t)n * 8 * sizeof(float));
  float* ald = (float*)alloc((size_t)n * 8 * sizeof(float));
  unsigned short* P = (unsigned short*)alloc((size_t)163840 * sizeof(unsigned short));
  unsigned short* P0 = P;
  unsigned short* P1 = P + 131072;
  unsigned short* P2 = P + 147456;

  int eb = (E + 255) / 256;
  int nb = (n + 255) / 256;
  hipMemsetAsync(cur, 0, (size_t)n * sizeof(int), stream);
  k_wpackdeg<<<eb, 256, 0, stream>>>(W0, W1, W2, P, GENES, ei, cur, E);
  k_scan1<<<nb, 256, 0, stream>>>(cur, ptr, bsum, n);   // zeroes cur in place
  k_scan2<<<1, 256, 0, stream>>>(bsum, nb);
  k_scan3<<<nb, 256, 0, stream>>>(ptr, bsum, n);

  int mgb0 = (n + 31) / 32;      // 1563 blocks; also covers E edges for scatter
  int mgb  = (n + 63) / 64;
  int aggb = (int)(((long)n * 64 + 255) / 256);

  // layer 0: x @ W0 -> Ah fp16 (+als/ald, +fused scatter), aggregate -> Bh
  k_mgemm12<<<mgb0, 512, 0, stream>>>(x, P0, Ah, als, ald, as0, ad0, n, GENES,
                                      ei, ptr, cur, srcs, E);
  k_agg128h<<<aggb, 256, 0, stream>>>(Ah, als, ald, ptr, srcs, b0, Bh, n);

  // layer 1: Bh @ W1 -> Ah fp16 (+als/ald), aggregate -> Bh fp16 (ELU)
  k_mgemm7<8, true, true><<<mgb, 512, 0, stream>>>(
      Bh, P1, Ah, als, ald, as1, ad1, n, 128, 4, 128);
  k_agg128h<<<aggb, 256, 0, stream>>>(Ah, als, ald, ptr, srcs, b1, Bh, n);

  // layer 2: Bh @ W2 (padded) -> A2 fp32 [n][16] (+als/ald H=1), aggregate -> out
  k_mgemm7<1, true, false><<<mgb, 512, 0, stream>>>(
      Bh, P2, A2, als, ald, as2, ad2, n, 128, 4, 16);
  k_agg16<<<aggb, 256, 0, stream>>>(A2, als, ald, ptr, srcs, b2, out, n, 16);
}

// Round 19
// 271.822 us; speedup vs baseline: 1.0374x; 1.0041x over previous
//
#include <hip/hip_runtime.h>
#include <hip/hip_bf16.h>
#include <math.h>

#define GENES 1000

typedef __attribute__((ext_vector_type(8))) _Float16 half8;
typedef __attribute__((ext_vector_type(4))) float f32x4;
typedef __attribute__((ext_vector_type(4))) unsigned int uint4v;
typedef __attribute__((ext_vector_type(2))) unsigned int uint2v;

__device__ inline float f16lo(unsigned int v) {
  return (float)__builtin_bit_cast(_Float16, (unsigned short)(v & 0xffffu));
}
__device__ inline float f16hi(unsigned int v) {
  return (float)__builtin_bit_cast(_Float16, (unsigned short)(v >> 16));
}
__device__ inline unsigned int pk(float a, float b) {
  return __builtin_bit_cast(unsigned int, __builtin_amdgcn_cvt_pkrtz(a, b));
}

// async global->LDS, 16B per lane; dest = wave-uniform base + lane*16 (m104),
// per-lane source (m173). Tracked ONLY by vmcnt -> counted waits possible.
__device__ inline void gload16(const void* g, void* l) {
  __builtin_amdgcn_global_load_lds(
      (const __attribute__((address_space(1))) unsigned int*)g,
      (__attribute__((address_space(3))) unsigned int*)l, 16, 0, 0);
}

// counted vm wait (literal) + scheduling fence
__device__ __forceinline__ void waitvm(int n) {
  __builtin_amdgcn_sched_barrier(0);
  if (n <= 0)      asm volatile("s_waitcnt vmcnt(0)" ::: "memory");
  else if (n <= 2) asm volatile("s_waitcnt vmcnt(2)" ::: "memory");
  else             asm volatile("s_waitcnt vmcnt(4)" ::: "memory");
  __builtin_amdgcn_sched_barrier(0);
}

// ---------------- CSR build ----------------

__global__ void k_scan1(int* __restrict__ deg, int* __restrict__ ptr,
                        int* __restrict__ bsum, int n) {
  __shared__ int ws[4];
  int t = threadIdx.x, b = blockIdx.x;
  int i = b * 256 + t;
  int lane = t & 63, w = t >> 6;
  int x = 0;
  if (i < n) { x = deg[i]; deg[i] = 0; }
  #pragma unroll
  for (int d = 1; d < 64; d <<= 1) {
    int y = __shfl_up(x, d);
    if (lane >= d) x += y;
  }
  if (lane == 63) ws[w] = x;
  __syncthreads();
  if (t == 0) {
    int s = 0;
    #pragma unroll
    for (int k = 0; k < 4; ++k) { s += ws[k]; ws[k] = s; }
  }
  __syncthreads();
  int incl = x + (w ? ws[w - 1] : 0);
  if (i < n) ptr[i + 1] = incl;
  if (t == 255) bsum[b] = incl;
  if (i == 0) ptr[0] = 0;
}

__global__ void k_scan2(int* __restrict__ bsum, int nb) {
  __shared__ int ws[4];
  int t = threadIdx.x;
  int lane = t & 63, w = t >> 6;
  int v = (t < nb) ? bsum[t] : 0;
  int x = v;
  #pragma unroll
  for (int d = 1; d < 64; d <<= 1) {
    int y = __shfl_up(x, d);
    if (lane >= d) x += y;
  }
  if (lane == 63) ws[w] = x;
  __syncthreads();
  if (t == 0) {
    int s = 0;
    #pragma unroll
    for (int k = 0; k < 4; ++k) { s += ws[k]; ws[k] = s; }
  }
  __syncthreads();
  int incl = x + (w ? ws[w - 1] : 0);
  if (t < nb) bsum[t] = incl - v;
}

__global__ void k_scan3(int* __restrict__ ptr, const int* __restrict__ bsum, int n) {
  int i = blockIdx.x * 256 + threadIdx.x;
  if (i < n) ptr[i + 1] += bsum[blockIdx.x];
}

__global__ void k_scatter(const int* __restrict__ ei, const int* __restrict__ ptr,
                          int* __restrict__ cur, int* __restrict__ srcs, int E) {
  int e = blockIdx.x * blockDim.x + threadIdx.x;
  if (e >= E) return;
  int d = ei[E + e];
  int pos = ptr[d] + atomicAdd(&cur[d], 1);
  srcs[pos] = ei[e];
}

// ---------------- W pack + degree count (fused) --------------------------------
// pack: idx = s*4096 + q*1024 + col*8 + j (k = s*32+q*8+j), fp16.
// W0 -> 32 ksteps (K zero-padded to 1024), W1 -> 4, W2 -> 4 (cols pad 128).

__global__ void k_wpackdeg(const float* __restrict__ W0, const float* __restrict__ W1,
                           const float* __restrict__ W2, unsigned short* __restrict__ P,
                           int K0, const int* __restrict__ ei, int* __restrict__ deg,
                           int E) {
  int t = blockIdx.x * blockDim.x + threadIdx.x;
  if (t < 163840) {
    const float* W; int K, N, e;
    if (t < 131072)      { W = W0; K = K0;  N = 128; e = t; }
    else if (t < 147456) { W = W1; K = 128; N = 128; e = t - 131072; }
    else                 { W = W2; K = 128; N = 16;  e = t - 147456; }
    int s = e >> 12, rem = e & 4095;
    int q = rem >> 10, col = (rem >> 3) & 127, j = rem & 7;
    int k = s * 32 + q * 8 + j;
    float v = (k < K && col < N) ? W[(long)k * N + col] : 0.f;
    _Float16 h = (_Float16)v;
    P[t] = __builtin_bit_cast(unsigned short, h);
  }
  if (t < E) atomicAdd(&deg[ei[E + t]], 1);
}

// ---------------- layer-0 GEMM: global_load_lds + counted-vmcnt pipeline (T4) --
// 512 threads = 8 waves (4 row-groups x 2 col-groups); BM=64, BN=128, BK=32.
// 4-deep LDS buffers (A 4x8KB swizzled-source, B 4x8KB linear), prologue issues
// tiles 0..2, per step: vmcnt(4) [tile s landed, 4 newer loads IN FLIGHT
// ACROSS THE BARRIER] -> raw s_barrier -> compute -> issue tile s+3.
// No vmcnt(0) drain anywhere in the main loop (the rounds-4..18 killer).
// Race-safe: in-flight writes target bufs (s+1..s+3)&3, never s&3 (tile-s
// readers are separated from tile s-1 by the barrier). Fused epilogue.

__global__ __launch_bounds__(512) void k_mgemm13(
    const float* __restrict__ A, const unsigned short* __restrict__ Pb,
    unsigned short* __restrict__ outp, float* __restrict__ als,
    float* __restrict__ ald, const float* __restrict__ avs,
    const float* __restrict__ avd, int M, int K) {
  __shared__ __align__(16) char lds[65536];  // A: 4x8KB | B: 4x8KB

  int t = threadIdx.x, lane = t & 63, wv = t >> 6;
  int r15 = lane & 15, q = lane >> 4;
  int wr = wv >> 1, wc = wv & 1;
  long row0 = (long)blockIdx.x * 64;

  // staging: thread -> row = t>>3 (0..63), seg = t&7 (16B of 128B row-chunk)
  int srow = t >> 3, sseg = t & 7;
  int gseg = sseg ^ (srow & 7);            // pre-swizzled source (rule 21)
  long arow = row0 + srow; if (arow >= M) arow = M - 1;
  const char* gA = (const char*)(A + arow * (long)K) + gseg * 16;
  const char* gB = (const char*)Pb + t * 16;

  f32x4 acc[4];
  #pragma unroll
  for (int nt = 0; nt < 4; ++nt) acc[nt] = (f32x4){0.f, 0.f, 0.f, 0.f};

  auto issue = [&](int s) {
    char* Ab = lds + (s & 3) * 8192;
    char* Bb = lds + 32768 + (s & 3) * 8192;
    gload16(gA + (size_t)s * 128, Ab + t * 16);
    gload16(gB + (size_t)s * 8192, Bb + t * 16);
  };
  auto compute = [&](int s) {
    const char* Ab = lds + (s & 3) * 8192;
    const char* Bb = lds + 32768 + (s & 3) * 8192;
    int row = wr * 16 + r15;
    int sw = row & 7;
    uint4v alo = *(const uint4v*)(Ab + row * 128 + ((2 * q) ^ sw) * 16);
    uint4v ahi = *(const uint4v*)(Ab + row * 128 + ((2 * q + 1) ^ sw) * 16);
    float4 lo = __builtin_bit_cast(float4, alo);
    float4 hi = __builtin_bit_cast(float4, ahi);
    uint4v au;
    au[0] = pk(lo.x, lo.y); au[1] = pk(lo.z, lo.w);
    au[2] = pk(hi.x, hi.y); au[3] = pk(hi.z, hi.w);
    half8 af = __builtin_bit_cast(half8, au);
    #pragma unroll
    for (int nt = 0; nt < 4; ++nt) {
      half8 bf = *(const half8*)(Bb + q * 2048 + (wc * 64 + nt * 16 + r15) * 16);
      acc[nt] = __builtin_amdgcn_mfma_f32_16x16x32_f16(af, bf, acc[nt], 0, 0, 0);
    }
  };

  issue(0); issue(1); issue(2);            // 6 loads/thread in flight
  #pragma unroll
  for (int s = 0; s < 32; ++s) {
    int nleft = 31 - s;                    // tiles after s not yet consumed
    waitvm(nleft >= 2 ? 4 : 2 * nleft);    // tile s landed; newer stay in flight
    __builtin_amdgcn_s_barrier();          // collective: tile s fully in LDS
    compute(s);
    if (s + 3 < 32) issue(s + 3);          // refill buf (s+3)&3 (not s&3)
  }

  // ---- epilogue: C/D layout col=lane&15, row=(lane>>4)*4+i ----
  long rbase = row0 + wr * 16 + q * 4;
  #pragma unroll
  for (int i = 0; i < 4; ++i) {
    long r = rbase + i;
    if (r < M) {
      #pragma unroll
      for (int nt = 0; nt < 4; ++nt) {
        int col = wc * 64 + nt * 16 + r15;
        _Float16 hv = (_Float16)acc[nt][i];
        outp[r * 128 + col] = __builtin_bit_cast(unsigned short, hv);
      }
    }
  }
  #pragma unroll
  for (int nt = 0; nt < 4; ++nt) {
    int head = wc * 4 + nt;
    float cs = avs[head * 16 + r15];
    float cd = avd[head * 16 + r15];
    #pragma unroll
    for (int i = 0; i < 4; ++i) {
      float s1 = acc[nt][i] * cs;
      float s2 = acc[nt][i] * cd;
      #pragma unroll
      for (int d = 1; d < 16; d <<= 1) {
        s1 += __shfl_xor(s1, d);
        s2 += __shfl_xor(s2, d);
      }
      if (r15 == 0) {
        long r = rbase + i;
        if (r < M) { als[r * 8 + head] = s1; ald[r * 8 + head] = s2; }
      }
    }
  }
}

// ---------------- MFMA fp16 GEMM (layers 1,2): 64-VGPR dbuf (round-13) --------

template<int HH, bool AF16, bool OF16>
__global__ __launch_bounds__(512) void k_mgemm7(
    const void* __restrict__ Ap, const unsigned short* __restrict__ Pb,
    void* __restrict__ outp, float* __restrict__ als, float* __restrict__ ald,
    const float* __restrict__ avs, const float* __restrict__ avd,
    int M, int K, int nst, int ldc) {
  __shared__ __align__(16) char lds[24576];
  char* bA0 = lds;
  char* bA1 = lds + 4096;
  char* bB0 = lds + 8192;
  char* bB1 = lds + 16384;

  int t = threadIdx.x, lane = t & 63;
  int r15 = lane & 15, q = lane >> 4;
  int wv = t >> 6;
  int wr = wv >> 1, wc = wv & 1;
  long row0 = (long)blockIdx.x * 64;

  int srow = t >> 3, sseg = t & 7;
  long arow = row0 + srow; if (arow >= M) arow = M - 1;
  const float* pa32 = (const float*)Ap + arow * (long)K;
  const unsigned short* pa16 = (const unsigned short*)Ap + arow * (long)K;

  f32x4 acc[4];
  #pragma unroll
  for (int nt = 0; nt < 4; ++nt) acc[nt] = (f32x4){0.f, 0.f, 0.f, 0.f};

  uint4v rA0, rA1, rB0, rB1;
  uint2v sA0, sA1;

  auto loadA = [&](int s, uint4v& r32, uint2v& r16) {
    int k0 = s * 32 + sseg * 4;
    if constexpr (AF16) {
      r16 = (k0 < K) ? *(const uint2v*)(pa16 + k0) : (uint2v){0u, 0u};
    } else {
      r32 = (k0 < K) ? *(const uint4v*)(pa32 + k0) : (uint4v){0u, 0u, 0u, 0u};
    }
  };
  auto writeA = [&](char* buf, uint4v r32, uint2v r16) {
    char* p = buf + ((sseg >> 1) * 1024 + srow * 16 + (sseg & 1) * 8);
    if constexpr (AF16) {
      *(uint2v*)p = r16;
    } else {
      float4 f = __builtin_bit_cast(float4, r32);
      uint2v h;
      h[0] = pk(f.x, f.y);
      h[1] = pk(f.z, f.w);
      *(uint2v*)p = h;
    }
  };
  auto loadB = [&](int s, uint4v& r) {
    r = *(const uint4v*)(Pb + (size_t)s * 4096 + t * 8);
  };
  auto writeB = [&](char* buf, uint4v r) {
    *(uint4v*)(buf + t * 16) = r;
  };
  auto compute = [&](const char* bA, const char* bB) {
    half8 af = *(const half8*)(bA + q * 1024 + (wr * 16 + r15) * 16);
    #pragma unroll
    for (int nt = 0; nt < 4; ++nt) {
      half8 bf = *(const half8*)(bB + q * 2048 + (wc * 64 + nt * 16 + r15) * 16);
      acc[nt] = __builtin_amdgcn_mfma_f32_16x16x32_f16(af, bf, acc[nt], 0, 0, 0);
    }
  };

  loadA(0, rA0, sA0); loadB(0, rB0);
  if (nst > 1) { loadA(1, rA1, sA1); loadB(1, rB1); }
  writeA(bA0, rA0, sA0); writeB(bB0, rB0);
  __syncthreads();

  for (int s = 0; s < nst; s += 2) {
    if (s + 2 < nst) { loadA(s + 2, rA0, sA0); loadB(s + 2, rB0); }
    compute(bA0, bB0);
    if (s + 1 < nst) { writeA(bA1, rA1, sA1); writeB(bB1, rB1); }
    __syncthreads();
    if (s + 1 < nst) {
      if (s + 3 < nst) { loadA(s + 3, rA1, sA1); loadB(s + 3, rB1); }
      compute(bA1, bB1);
      if (s + 2 < nst) { writeA(bA0, rA0, sA0); writeB(bB0, rB0); }
      __syncthreads();
    }
  }

  long rbase = row0 + wr * 16 + q * 4;
  if constexpr (OF16) {
    unsigned short* o16 = (unsigned short*)outp;
    #pragma unroll
    for (int i = 0; i < 4; ++i) {
      long r = rbase + i;
      if (r < M) {
        #pragma unroll
        for (int nt = 0; nt < 4; ++nt) {
          int col = wc * 64 + nt * 16 + r15;
          _Float16 hv = (_Float16)acc[nt][i];
          o16[r * ldc + col] = __builtin_bit_cast(unsigned short, hv);
        }
      }
    }
  } else {
    float* o32 = (float*)outp;
    #pragma unroll
    for (int i = 0; i < 4; ++i) {
      long r = rbase + i;
      if (r < M) {
        #pragma unroll
        for (int nt = 0; nt < 4; ++nt) {
          int col = wc * 64 + nt * 16 + r15;
          if (col < ldc) o32[r * ldc + col] = acc[nt][i];
        }
      }
    }
  }
  #pragma unroll
  for (int nt = 0; nt < 4; ++nt) {
    int head = wc * 4 + nt;
    if (head < HH) {
      float cs = avs[head * 16 + r15];
      float cd = avd[head * 16 + r15];
      #pragma unroll
      for (int i = 0; i < 4; ++i) {
        float s1 = acc[nt][i] * cs;
        float s2 = acc[nt][i] * cd;
        #pragma unroll
        for (int d = 1; d < 16; d <<= 1) {
          s1 += __shfl_xor(s1, d);
          s2 += __shfl_xor(s2, d);
        }
        if (r15 == 0) {
          long r = rbase + i;
          if (r < M) { als[r * HH + head] = s1; ald[r * HH + head] = s2; }
        }
      }
    }
  }
}

// ---------------- per-dst aggregation, H=8, C=16, fp16 h, ELU ------------------
// Split-wave halves, alternate edges, 4-edge batches; no max pass.

__global__ void k_agg128h(const unsigned short* __restrict__ h,
                          const float* __restrict__ als, const float* __restrict__ ald,
                          const int* __restrict__ ptr, const int* __restrict__ srcs,
                          const float* __restrict__ bias,
                          unsigned short* __restrict__ out, int n) {
  int wid = (int)(((long)blockIdx.x * blockDim.x + threadIdx.x) >> 6);
  if (wid >= n) return;
  int lane = threadIdx.x & 63;
  int half = lane >> 5, l5 = lane & 31;
  int c0 = 4 * l5;
  int hB = l5 >> 2;
  int p0 = ptr[wid], deg = ptr[wid + 1] - p0;
  float aldB = ald[wid * 8 + hB];
  float a0 = 0.f, a1 = 0.f, a2 = 0.f, a3 = 0.f, dsum = 0.f;
  int j = half;
  for (; j + 6 < deg; j += 8) {
    int s0 = srcs[p0 + j],     s1 = srcs[p0 + j + 2];
    int s2 = srcs[p0 + j + 4], s3 = srcs[p0 + j + 6];
    float l0 = als[s0 * 8 + hB] + aldB;
    float l1 = als[s1 * 8 + hB] + aldB;
    float l2 = als[s2 * 8 + hB] + aldB;
    float l3 = als[s3 * 8 + hB] + aldB;
    uint2v h0 = *(const uint2v*)(h + (long)s0 * 128 + c0);
    uint2v h1 = *(const uint2v*)(h + (long)s1 * 128 + c0);
    uint2v h2 = *(const uint2v*)(h + (long)s2 * 128 + c0);
    uint2v h3 = *(const uint2v*)(h + (long)s3 * 128 + c0);
    l0 = l0 > 0.f ? l0 : 0.2f * l0;
    l1 = l1 > 0.f ? l1 : 0.2f * l1;
    l2 = l2 > 0.f ? l2 : 0.2f * l2;
    l3 = l3 > 0.f ? l3 : 0.2f * l3;
    float e0 = __expf(l0), e1 = __expf(l1), e2 = __expf(l2), e3 = __expf(l3);
    dsum += e0 + e1 + e2 + e3;
    a0 += e0 * f16lo(h0[0]) + e1 * f16lo(h1[0]) + e2 * f16lo(h2[0]) + e3 * f16lo(h3[0]);
    a1 += e0 * f16hi(h0[0]) + e1 * f16hi(h1[0]) + e2 * f16hi(h2[0]) + e3 * f16hi(h3[0]);
    a2 += e0 * f16lo(h0[1]) + e1 * f16lo(h1[1]) + e2 * f16lo(h2[1]) + e3 * f16lo(h3[1]);
    a3 += e0 * f16hi(h0[1]) + e1 * f16hi(h1[1]) + e2 * f16hi(h2[1]) + e3 * f16hi(h3[1]);
  }
  for (; j < deg; j += 2) {
    int s = srcs[p0 + j];
    float l = als[s * 8 + hB] + aldB;
    l = l > 0.f ? l : 0.2f * l;
    float e = __expf(l);
    uint2v hv = *(const uint2v*)(h + (long)s * 128 + c0);
    dsum += e;
    a0 += e * f16lo(hv[0]);
    a1 += e * f16hi(hv[0]);
    a2 += e * f16lo(hv[1]);
    a3 += e * f16hi(hv[1]);
  }
  a0 += __shfl_xor(a0, 32);
  a1 += __shfl_xor(a1, 32);
  a2 += __shfl_xor(a2, 32);
  a3 += __shfl_xor(a3, 32);
  dsum += __shfl_xor(dsum, 32);
  if (half == 0) {
    float inv = 1.f / (dsum + 1e-16f);
    float o0 = a0 * inv + bias[c0];
    float o1 = a1 * inv + bias[c0 + 1];
    float o2 = a2 * inv + bias[c0 + 2];
    float o3 = a3 * inv + bias[c0 + 3];
    o0 = o0 > 0.f ? o0 : (__expf(o0) - 1.f);
    o1 = o1 > 0.f ? o1 : (__expf(o1) - 1.f);
    o2 = o2 > 0.f ? o2 : (__expf(o2) - 1.f);
    o3 = o3 > 0.f ? o3 : (__expf(o3) - 1.f);
    uint2v po;
    po[0] = __builtin_bit_cast(unsigned int, __builtin_amdgcn_cvt_pkrtz(o0, o1));
    po[1] = __builtin_bit_cast(unsigned int, __builtin_amdgcn_cvt_pkrtz(o2, o3));
    *(uint2v*)(out + (long)wid * 128 + c0) = po;
  }
}

// ---------------- per-dst aggregation, H=1, C=16, fp32, no max, 4-batch --------

__global__ void k_agg16(const float* __restrict__ h, const float* __restrict__ als,
                        const float* __restrict__ ald, const int* __restrict__ ptr,
                        const int* __restrict__ srcs, const float* __restrict__ bias,
                        float* __restrict__ out, int n, int lda) {
  int wid = (int)(((long)blockIdx.x * blockDim.x + threadIdx.x) >> 6);
  if (wid >= n) return;
  int lane = threadIdx.x & 63;
  int p0 = ptr[wid], deg = ptr[wid + 1] - p0;
  float aldv = ald[wid];
  int g = lane >> 4, c = lane & 15;
  float acc = 0.f, dsum = 0.f;
  int j = g;
  for (; j + 12 < deg; j += 16) {
    int s0 = srcs[p0 + j],     s1 = srcs[p0 + j + 4];
    int s2 = srcs[p0 + j + 8], s3 = srcs[p0 + j + 12];
    float l0 = als[s0] + aldv, l1 = als[s1] + aldv;
    float l2 = als[s2] + aldv, l3 = als[s3] + aldv;
    float h0 = h[(long)s0 * lda + c], h1 = h[(long)s1 * lda + c];
    float h2 = h[(long)s2 * lda + c], h3 = h[(long)s3 * lda + c];
    l0 = l0 > 0.f ? l0 : 0.2f * l0;
    l1 = l1 > 0.f ? l1 : 0.2f * l1;
    l2 = l2 > 0.f ? l2 : 0.2f * l2;
    l3 = l3 > 0.f ? l3 : 0.2f * l3;
    float e0 = __expf(l0), e1 = __expf(l1), e2 = __expf(l2), e3 = __expf(l3);
    dsum += e0 + e1 + e2 + e3;
    acc += e0 * h0 + e1 * h1 + e2 * h2 + e3 * h3;
  }
  for (; j < deg; j += 4) {
    int s = srcs[p0 + j];
    float l = als[s] + aldv;
    l = l > 0.f ? l : 0.2f * l;
    float e = __expf(l);
    dsum += e;
    acc += e * h[(long)s * lda + c];
  }
  #pragma unroll
  for (int d = 16; d < 64; d <<= 1) {
    acc += __shfl_xor(acc, d);
    dsum += __shfl_xor(dsum, d);
  }
  if (lane < 16)
    out[(long)wid * 16 + lane] = acc / (dsum + 1e-16f) + bias[lane];
}

// ---------------- launch ----------------

extern "C" void kernel_launch(void* const* d_in, const int* in_sizes, int n_in,
                              void* d_out, int out_size, void* d_ws, size_t ws_size,
                              hipStream_t stream) {
  const float* x  = (const float*)d_in[0];
  const int*   ei = (const int*)d_in[1];
  const float* W0 = (const float*)d_in[2];
  const float* as0= (const float*)d_in[3];
  const float* ad0= (const float*)d_in[4];
  const float* b0 = (const float*)d_in[5];
  const float* W1 = (const float*)d_in[6];
  const float* as1= (const float*)d_in[7];
  const float* ad1= (const float*)d_in[8];
  const float* b1 = (const float*)d_in[9];
  const float* W2 = (const float*)d_in[10];
  const float* as2= (const float*)d_in[11];
  const float* ad2= (const float*)d_in[12];
  const float* b2 = (const float*)d_in[13];
  float* out = (float*)d_out;

  int E = in_sizes[1] / 2;
  int n = in_sizes[0] / GENES;

  char* ws = (char*)d_ws;
  size_t off = 0;
  auto alloc = [&](size_t bytes) {
    void* p = ws + off;
    off = (off + bytes + 255) & ~(size_t)255;
    return p;
  };
  int* ptr   = (int*)alloc((size_t)(n + 1) * sizeof(int));
  int* cur   = (int*)alloc((size_t)n * sizeof(int));
  int* bsum  = (int*)alloc(512 * sizeof(int));
  int* srcs  = (int*)alloc((size_t)E * sizeof(int));
  unsigned short* Ah = (unsigned short*)alloc((size_t)n * 128 * sizeof(unsigned short));
  unsigned short* Bh = (unsigned short*)alloc((size_t)n * 128 * sizeof(unsigned short));
  float* A2  = (float*)alloc((size_t)n * 16 * sizeof(float));
  float* als = (float*)alloc((size_t)n * 8 * sizeof(float));
  float* ald = (float*)alloc((size_t)n * 8 * sizeof(float));
  unsigned short* P = (unsigned short*)alloc((size_t)163840 * sizeof(unsigned short));
  unsigned short* P0 = P;
  unsigned short* P1 = P + 131072;
  unsigned short* P2 = P + 147456;

  int eb = (E + 255) / 256;
  int nb = (n + 255) / 256;
  hipMemsetAsync(cur, 0, (size_t)n * sizeof(int), stream);
  k_wpackdeg<<<eb, 256, 0, stream>>>(W0, W1, W2, P, GENES, ei, cur, E);
  k_scan1<<<nb, 256, 0, stream>>>(cur, ptr, bsum, n);   // zeroes cur in place
  k_scan2<<<1, 256, 0, stream>>>(bsum, nb);
  k_scan3<<<nb, 256, 0, stream>>>(ptr, bsum, n);
  k_scatter<<<eb, 256, 0, stream>>>(ei, ptr, cur, srcs, E);

  int mgb  = (n + 63) / 64;
  int aggb = (int)(((long)n * 64 + 255) / 256);

  // layer 0: x @ W0 -> Ah fp16 (+als/ald), counted-vmcnt pipeline; agg -> Bh
  k_mgemm13<<<mgb, 512, 0, stream>>>(x, P0, Ah, als, ald, as0, ad0, n, GENES);
  k_agg128h<<<aggb, 256, 0, stream>>>(Ah, als, ald, ptr, srcs, b0, Bh, n);

  // layer 1: Bh @ W1 -> Ah fp16 (+als/ald), aggregate -> Bh fp16 (ELU)
  k_mgemm7<8, true, true><<<mgb, 512, 0, stream>>>(
      Bh, P1, Ah, als, ald, as1, ad1, n, 128, 4, 128);
  k_agg128h<<<aggb, 256, 0, stream>>>(Ah, als, ald, ptr, srcs, b1, Bh, n);

  // layer 2: Bh @ W2 (padded) -> A2 fp32 [n][16] (+als/ald H=1), aggregate -> out
  k_mgemm7<1, true, false><<<mgb, 512, 0, stream>>>(
      Bh, P2, A2, als, ald, as2, ad2, n, 128, 4, 16);
  k_agg16<<<aggb, 256, 0, stream>>>(A2, als, ald, ptr, srcs, b2, out, n, 16);
}

// Round 20
// 265.216 us; speedup vs baseline: 1.0632x; 1.0249x over previous
//
#include <hip/hip_runtime.h>
#include <hip/hip_bf16.h>
#include <math.h>

#define GENES 1000

typedef __attribute__((ext_vector_type(8))) _Float16 half8;
typedef __attribute__((ext_vector_type(4))) float f32x4;
typedef __attribute__((ext_vector_type(4))) unsigned int uint4v;
typedef __attribute__((ext_vector_type(2))) unsigned int uint2v;

__device__ inline float f16lo(unsigned int v) {
  return (float)__builtin_bit_cast(_Float16, (unsigned short)(v & 0xffffu));
}
__device__ inline float f16hi(unsigned int v) {
  return (float)__builtin_bit_cast(_Float16, (unsigned short)(v >> 16));
}
__device__ inline unsigned int pk(float a, float b) {
  return __builtin_bit_cast(unsigned int, __builtin_amdgcn_cvt_pkrtz(a, b));
}

// async global->LDS, 16B per lane; dest = wave-uniform base + lane*16 (m104),
// per-lane source (m173). Tracked ONLY by vmcnt -> counted waits possible.
__device__ inline void gload16(const void* g, void* l) {
  __builtin_amdgcn_global_load_lds(
      (const __attribute__((address_space(1))) unsigned int*)g,
      (__attribute__((address_space(3))) unsigned int*)l, 16, 0, 0);
}

// counted vm wait (literal) + scheduling fence
__device__ __forceinline__ void waitvm(int n) {
  __builtin_amdgcn_sched_barrier(0);
  if (n <= 0)      asm volatile("s_waitcnt vmcnt(0)" ::: "memory");
  else if (n <= 2) asm volatile("s_waitcnt vmcnt(2)" ::: "memory");
  else             asm volatile("s_waitcnt vmcnt(4)" ::: "memory");
  __builtin_amdgcn_sched_barrier(0);
}

// ---------------- CSR build ----------------

__global__ void k_scan1(int* __restrict__ deg, int* __restrict__ ptr,
                        int* __restrict__ bsum, int n) {
  __shared__ int ws[4];
  int t = threadIdx.x, b = blockIdx.x;
  int i = b * 256 + t;
  int lane = t & 63, w = t >> 6;
  int x = 0;
  if (i < n) { x = deg[i]; deg[i] = 0; }
  #pragma unroll
  for (int d = 1; d < 64; d <<= 1) {
    int y = __shfl_up(x, d);
    if (lane >= d) x += y;
  }
  if (lane == 63) ws[w] = x;
  __syncthreads();
  if (t == 0) {
    int s = 0;
    #pragma unroll
    for (int k = 0; k < 4; ++k) { s += ws[k]; ws[k] = s; }
  }
  __syncthreads();
  int incl = x + (w ? ws[w - 1] : 0);
  if (i < n) ptr[i + 1] = incl;
  if (t == 255) bsum[b] = incl;
  if (i == 0) ptr[0] = 0;
}

__global__ void k_scan2(int* __restrict__ bsum, int nb) {
  __shared__ int ws[4];
  int t = threadIdx.x;
  int lane = t & 63, w = t >> 6;
  int v = (t < nb) ? bsum[t] : 0;
  int x = v;
  #pragma unroll
  for (int d = 1; d < 64; d <<= 1) {
    int y = __shfl_up(x, d);
    if (lane >= d) x += y;
  }
  if (lane == 63) ws[w] = x;
  __syncthreads();
  if (t == 0) {
    int s = 0;
    #pragma unroll
    for (int k = 0; k < 4; ++k) { s += ws[k]; ws[k] = s; }
  }
  __syncthreads();
  int incl = x + (w ? ws[w - 1] : 0);
  if (t < nb) bsum[t] = incl - v;
}

__global__ void k_scan3(int* __restrict__ ptr, const int* __restrict__ bsum, int n) {
  int i = blockIdx.x * 256 + threadIdx.x;
  if (i < n) ptr[i + 1] += bsum[blockIdx.x];
}

// ---------------- W pack + degree count (fused) --------------------------------
// pack: idx = s*4096 + q*1024 + col*8 + j (k = s*32+q*8+j), fp16.
// W0 -> 32 ksteps (K zero-padded to 1024), W1 -> 4, W2 -> 4 (cols pad 128).

__global__ void k_wpackdeg(const float* __restrict__ W0, const float* __restrict__ W1,
                           const float* __restrict__ W2, unsigned short* __restrict__ P,
                           int K0, const int* __restrict__ ei, int* __restrict__ deg,
                           int E) {
  int t = blockIdx.x * blockDim.x + threadIdx.x;
  if (t < 163840) {
    const float* W; int K, N, e;
    if (t < 131072)      { W = W0; K = K0;  N = 128; e = t; }
    else if (t < 147456) { W = W1; K = 128; N = 128; e = t - 131072; }
    else                 { W = W2; K = 128; N = 16;  e = t - 147456; }
    int s = e >> 12, rem = e & 4095;
    int q = rem >> 10, col = (rem >> 3) & 127, j = rem & 7;
    int k = s * 32 + q * 8 + j;
    float v = (k < K && col < N) ? W[(long)k * N + col] : 0.f;
    _Float16 h = (_Float16)v;
    P[t] = __builtin_bit_cast(unsigned short, h);
  }
  if (t < E) atomicAdd(&deg[ei[E + t]], 1);
}

// ---------------- layer-0 GEMM: counted-vmcnt pipeline + fused CSR scatter -----
// 512 threads = 8 waves (4 row-groups x 2 col-groups); BM=64, BN=128, BK=32.
// 4-deep LDS buffers; prologue issues tiles 0..2; per step: vmcnt(4) -> raw
// s_barrier -> compute -> issue tile s+3. No vmcnt(0) drain in the main loop.
// CSR scatter (independent work, 2 edges/thread) fused into the prologue --
// its gather/atomic latency hides under the staging burst (r18 lesson,
// worth ~15-20 us of removed standalone dispatch). Fused epilogue.

__global__ __launch_bounds__(512) void k_mgemm13(
    const float* __restrict__ A, const unsigned short* __restrict__ Pb,
    unsigned short* __restrict__ outp, float* __restrict__ als,
    float* __restrict__ ald, const float* __restrict__ avs,
    const float* __restrict__ avd, int M, int K,
    const int* __restrict__ ei, const int* __restrict__ ptr,
    int* __restrict__ cur, int* __restrict__ srcs, int E) {
  __shared__ __align__(16) char lds[65536];  // A: 4x8KB | B: 4x8KB

  int t = threadIdx.x, lane = t & 63, wv = t >> 6;
  int r15 = lane & 15, q = lane >> 4;
  int wr = wv >> 1, wc = wv & 1;
  long row0 = (long)blockIdx.x * 64;

  // staging: thread -> row = t>>3 (0..63), seg = t&7 (16B of 128B row-chunk)
  int srow = t >> 3, sseg = t & 7;
  int gseg = sseg ^ (srow & 7);            // pre-swizzled source (rule 21)
  long arow = row0 + srow; if (arow >= M) arow = M - 1;
  const char* gA = (const char*)(A + arow * (long)K) + gseg * 16;
  const char* gB = (const char*)Pb + t * 16;

  f32x4 acc[4];
  #pragma unroll
  for (int nt = 0; nt < 4; ++nt) acc[nt] = (f32x4){0.f, 0.f, 0.f, 0.f};

  auto issue = [&](int s) {
    char* Ab = lds + (s & 3) * 8192;
    char* Bb = lds + 32768 + (s & 3) * 8192;
    gload16(gA + (size_t)s * 128, Ab + t * 16);
    gload16(gB + (size_t)s * 8192, Bb + t * 16);
  };
  auto compute = [&](int s) {
    const char* Ab = lds + (s & 3) * 8192;
    const char* Bb = lds + 32768 + (s & 3) * 8192;
    int row = wr * 16 + r15;
    int sw = row & 7;
    uint4v alo = *(const uint4v*)(Ab + row * 128 + ((2 * q) ^ sw) * 16);
    uint4v ahi = *(const uint4v*)(Ab + row * 128 + ((2 * q + 1) ^ sw) * 16);
    float4 lo = __builtin_bit_cast(float4, alo);
    float4 hi = __builtin_bit_cast(float4, ahi);
    uint4v au;
    au[0] = pk(lo.x, lo.y); au[1] = pk(lo.z, lo.w);
    au[2] = pk(hi.x, hi.y); au[3] = pk(hi.z, hi.w);
    half8 af = __builtin_bit_cast(half8, au);
    #pragma unroll
    for (int nt = 0; nt < 4; ++nt) {
      half8 bf = *(const half8*)(Bb + q * 2048 + (wc * 64 + nt * 16 + r15) * 16);
      acc[nt] = __builtin_amdgcn_mfma_f32_16x16x32_f16(af, bf, acc[nt], 0, 0, 0);
    }
  };

  issue(0); issue(1); issue(2);            // 6 loads/thread in flight

  // fused CSR scatter: 1024 edges per block (2 per thread), independent work
  // whose latency hides under the staging pipeline
  {
    int e0 = blockIdx.x * 1024 + t;
    if (e0 < E) {
      int d = ei[E + e0];
      int pos = ptr[d] + atomicAdd(&cur[d], 1);
      srcs[pos] = ei[e0];
    }
    int e1 = e0 + 512;
    if (e1 < E) {
      int d = ei[E + e1];
      int pos = ptr[d] + atomicAdd(&cur[d], 1);
      srcs[pos] = ei[e1];
    }
  }

  #pragma unroll
  for (int s = 0; s < 32; ++s) {
    int nleft = 31 - s;                    // tiles after s not yet consumed
    waitvm(nleft >= 2 ? 4 : 2 * nleft);    // tile s landed; newer stay in flight
    __builtin_amdgcn_s_barrier();          // collective: tile s fully in LDS
    compute(s);
    if (s + 3 < 32) issue(s + 3);          // refill buf (s+3)&3 (not s&3)
  }

  // ---- epilogue: C/D layout col=lane&15, row=(lane>>4)*4+i ----
  long rbase = row0 + wr * 16 + q * 4;
  #pragma unroll
  for (int i = 0; i < 4; ++i) {
    long r = rbase + i;
    if (r < M) {
      #pragma unroll
      for (int nt = 0; nt < 4; ++nt) {
        int col = wc * 64 + nt * 16 + r15;
        _Float16 hv = (_Float16)acc[nt][i];
        outp[r * 128 + col] = __builtin_bit_cast(unsigned short, hv);
      }
    }
  }
  #pragma unroll
  for (int nt = 0; nt < 4; ++nt) {
    int head = wc * 4 + nt;
    float cs = avs[head * 16 + r15];
    float cd = avd[head * 16 + r15];
    #pragma unroll
    for (int i = 0; i < 4; ++i) {
      float s1 = acc[nt][i] * cs;
      float s2 = acc[nt][i] * cd;
      #pragma unroll
      for (int d = 1; d < 16; d <<= 1) {
        s1 += __shfl_xor(s1, d);
        s2 += __shfl_xor(s2, d);
      }
      if (r15 == 0) {
        long r = rbase + i;
        if (r < M) { als[r * 8 + head] = s1; ald[r * 8 + head] = s2; }
      }
    }
  }
}

// ---------------- MFMA fp16 GEMM (layers 1,2): 64-VGPR dbuf (round-13) --------

template<int HH, bool AF16, bool OF16>
__global__ __launch_bounds__(512) void k_mgemm7(
    const void* __restrict__ Ap, const unsigned short* __restrict__ Pb,
    void* __restrict__ outp, float* __restrict__ als, float* __restrict__ ald,
    const float* __restrict__ avs, const float* __restrict__ avd,
    int M, int K, int nst, int ldc) {
  __shared__ __align__(16) char lds[24576];
  char* bA0 = lds;
  char* bA1 = lds + 4096;
  char* bB0 = lds + 8192;
  char* bB1 = lds + 16384;

  int t = threadIdx.x, lane = t & 63;
  int r15 = lane & 15, q = lane >> 4;
  int wv = t >> 6;
  int wr = wv >> 1, wc = wv & 1;
  long row0 = (long)blockIdx.x * 64;

  int srow = t >> 3, sseg = t & 7;
  long arow = row0 + srow; if (arow >= M) arow = M - 1;
  const float* pa32 = (const float*)Ap + arow * (long)K;
  const unsigned short* pa16 = (const unsigned short*)Ap + arow * (long)K;

  f32x4 acc[4];
  #pragma unroll
  for (int nt = 0; nt < 4; ++nt) acc[nt] = (f32x4){0.f, 0.f, 0.f, 0.f};

  uint4v rA0, rA1, rB0, rB1;
  uint2v sA0, sA1;

  auto loadA = [&](int s, uint4v& r32, uint2v& r16) {
    int k0 = s * 32 + sseg * 4;
    if constexpr (AF16) {
      r16 = (k0 < K) ? *(const uint2v*)(pa16 + k0) : (uint2v){0u, 0u};
    } else {
      r32 = (k0 < K) ? *(const uint4v*)(pa32 + k0) : (uint4v){0u, 0u, 0u, 0u};
    }
  };
  auto writeA = [&](char* buf, uint4v r32, uint2v r16) {
    char* p = buf + ((sseg >> 1) * 1024 + srow * 16 + (sseg & 1) * 8);
    if constexpr (AF16) {
      *(uint2v*)p = r16;
    } else {
      float4 f = __builtin_bit_cast(float4, r32);
      uint2v h;
      h[0] = pk(f.x, f.y);
      h[1] = pk(f.z, f.w);
      *(uint2v*)p = h;
    }
  };
  auto loadB = [&](int s, uint4v& r) {
    r = *(const uint4v*)(Pb + (size_t)s * 4096 + t * 8);
  };
  auto writeB = [&](char* buf, uint4v r) {
    *(uint4v*)(buf + t * 16) = r;
  };
  auto compute = [&](const char* bA, const char* bB) {
    half8 af = *(const half8*)(bA + q * 1024 + (wr * 16 + r15) * 16);
    #pragma unroll
    for (int nt = 0; nt < 4; ++nt) {
      half8 bf = *(const half8*)(bB + q * 2048 + (wc * 64 + nt * 16 + r15) * 16);
      acc[nt] = __builtin_amdgcn_mfma_f32_16x16x32_f16(af, bf, acc[nt], 0, 0, 0);
    }
  };

  loadA(0, rA0, sA0); loadB(0, rB0);
  if (nst > 1) { loadA(1, rA1, sA1); loadB(1, rB1); }
  writeA(bA0, rA0, sA0); writeB(bB0, rB0);
  __syncthreads();

  for (int s = 0; s < nst; s += 2) {
    if (s + 2 < nst) { loadA(s + 2, rA0, sA0); loadB(s + 2, rB0); }
    compute(bA0, bB0);
    if (s + 1 < nst) { writeA(bA1, rA1, sA1); writeB(bB1, rB1); }
    __syncthreads();
    if (s + 1 < nst) {
      if (s + 3 < nst) { loadA(s + 3, rA1, sA1); loadB(s + 3, rB1); }
      compute(bA1, bB1);
      if (s + 2 < nst) { writeA(bA0, rA0, sA0); writeB(bB0, rB0); }
      __syncthreads();
    }
  }

  long rbase = row0 + wr * 16 + q * 4;
  if constexpr (OF16) {
    unsigned short* o16 = (unsigned short*)outp;
    #pragma unroll
    for (int i = 0; i < 4; ++i) {
      long r = rbase + i;
      if (r < M) {
        #pragma unroll
        for (int nt = 0; nt < 4; ++nt) {
          int col = wc * 64 + nt * 16 + r15;
          _Float16 hv = (_Float16)acc[nt][i];
          o16[r * ldc + col] = __builtin_bit_cast(unsigned short, hv);
        }
      }
    }
  } else {
    float* o32 = (float*)outp;
    #pragma unroll
    for (int i = 0; i < 4; ++i) {
      long r = rbase + i;
      if (r < M) {
        #pragma unroll
        for (int nt = 0; nt < 4; ++nt) {
          int col = wc * 64 + nt * 16 + r15;
          if (col < ldc) o32[r * ldc + col] = acc[nt][i];
        }
      }
    }
  }
  #pragma unroll
  for (int nt = 0; nt < 4; ++nt) {
    int head = wc * 4 + nt;
    if (head < HH) {
      float cs = avs[head * 16 + r15];
      float cd = avd[head * 16 + r15];
      #pragma unroll
      for (int i = 0; i < 4; ++i) {
        float s1 = acc[nt][i] * cs;
        float s2 = acc[nt][i] * cd;
        #pragma unroll
        for (int d = 1; d < 16; d <<= 1) {
          s1 += __shfl_xor(s1, d);
          s2 += __shfl_xor(s2, d);
        }
        if (r15 == 0) {
          long r = rbase + i;
          if (r < M) { als[r * HH + head] = s1; ald[r * HH + head] = s2; }
        }
      }
    }
  }
}

// ---------------- per-dst aggregation, H=8, C=16, fp16 h, ELU ------------------
// Split-wave halves, alternate edges, 4-edge batches; no max pass.

__global__ void k_agg128h(const unsigned short* __restrict__ h,
                          const float* __restrict__ als, const float* __restrict__ ald,
                          const int* __restrict__ ptr, const int* __restrict__ srcs,
                          const float* __restrict__ bias,
                          unsigned short* __restrict__ out, int n) {
  int wid = (int)(((long)blockIdx.x * blockDim.x + threadIdx.x) >> 6);
  if (wid >= n) return;
  int lane = threadIdx.x & 63;
  int half = lane >> 5, l5 = lane & 31;
  int c0 = 4 * l5;
  int hB = l5 >> 2;
  int p0 = ptr[wid], deg = ptr[wid + 1] - p0;
  float aldB = ald[wid * 8 + hB];
  float a0 = 0.f, a1 = 0.f, a2 = 0.f, a3 = 0.f, dsum = 0.f;
  int j = half;
  for (; j + 6 < deg; j += 8) {
    int s0 = srcs[p0 + j],     s1 = srcs[p0 + j + 2];
    int s2 = srcs[p0 + j + 4], s3 = srcs[p0 + j + 6];
    float l0 = als[s0 * 8 + hB] + aldB;
    float l1 = als[s1 * 8 + hB] + aldB;
    float l2 = als[s2 * 8 + hB] + aldB;
    float l3 = als[s3 * 8 + hB] + aldB;
    uint2v h0 = *(const uint2v*)(h + (long)s0 * 128 + c0);
    uint2v h1 = *(const uint2v*)(h + (long)s1 * 128 + c0);
    uint2v h2 = *(const uint2v*)(h + (long)s2 * 128 + c0);
    uint2v h3 = *(const uint2v*)(h + (long)s3 * 128 + c0);
    l0 = l0 > 0.f ? l0 : 0.2f * l0;
    l1 = l1 > 0.f ? l1 : 0.2f * l1;
    l2 = l2 > 0.f ? l2 : 0.2f * l2;
    l3 = l3 > 0.f ? l3 : 0.2f * l3;
    float e0 = __expf(l0), e1 = __expf(l1), e2 = __expf(l2), e3 = __expf(l3);
    dsum += e0 + e1 + e2 + e3;
    a0 += e0 * f16lo(h0[0]) + e1 * f16lo(h1[0]) + e2 * f16lo(h2[0]) + e3 * f16lo(h3[0]);
    a1 += e0 * f16hi(h0[0]) + e1 * f16hi(h1[0]) + e2 * f16hi(h2[0]) + e3 * f16hi(h3[0]);
    a2 += e0 * f16lo(h0[1]) + e1 * f16lo(h1[1]) + e2 * f16lo(h2[1]) + e3 * f16lo(h3[1]);
    a3 += e0 * f16hi(h0[1]) + e1 * f16hi(h1[1]) + e2 * f16hi(h2[1]) + e3 * f16hi(h3[1]);
  }
  for (; j < deg; j += 2) {
    int s = srcs[p0 + j];
    float l = als[s * 8 + hB] + aldB;
    l = l > 0.f ? l : 0.2f * l;
    float e = __expf(l);
    uint2v hv = *(const uint2v*)(h + (long)s * 128 + c0);
    dsum += e;
    a0 += e * f16lo(hv[0]);
    a1 += e * f16hi(hv[0]);
    a2 += e * f16lo(hv[1]);
    a3 += e * f16hi(hv[1]);
  }
  a0 += __shfl_xor(a0, 32);
  a1 += __shfl_xor(a1, 32);
  a2 += __shfl_xor(a2, 32);
  a3 += __shfl_xor(a3, 32);
  dsum += __shfl_xor(dsum, 32);
  if (half == 0) {
    float inv = 1.f / (dsum + 1e-16f);
    float o0 = a0 * inv + bias[c0];
    float o1 = a1 * inv + bias[c0 + 1];
    float o2 = a2 * inv + bias[c0 + 2];
    float o3 = a3 * inv + bias[c0 + 3];
    o0 = o0 > 0.f ? o0 : (__expf(o0) - 1.f);
    o1 = o1 > 0.f ? o1 : (__expf(o1) - 1.f);
    o2 = o2 > 0.f ? o2 : (__expf(o2) - 1.f);
    o3 = o3 > 0.f ? o3 : (__expf(o3) - 1.f);
    uint2v po;
    po[0] = __builtin_bit_cast(unsigned int, __builtin_amdgcn_cvt_pkrtz(o0, o1));
    po[1] = __builtin_bit_cast(unsigned int, __builtin_amdgcn_cvt_pkrtz(o2, o3));
    *(uint2v*)(out + (long)wid * 128 + c0) = po;
  }
}

// ---------------- per-dst aggregation, H=1, C=16, fp32, no max, 4-batch --------

__global__ void k_agg16(const float* __restrict__ h, const float* __restrict__ als,
                        const float* __restrict__ ald, const int* __restrict__ ptr,
                        const int* __restrict__ srcs, const float* __restrict__ bias,
                        float* __restrict__ out, int n, int lda) {
  int wid = (int)(((long)blockIdx.x * blockDim.x + threadIdx.x) >> 6);
  if (wid >= n) return;
  int lane = threadIdx.x & 63;
  int p0 = ptr[wid], deg = ptr[wid + 1] - p0;
  float aldv = ald[wid];
  int g = lane >> 4, c = lane & 15;
  float acc = 0.f, dsum = 0.f;
  int j = g;
  for (; j + 12 < deg; j += 16) {
    int s0 = srcs[p0 + j],     s1 = srcs[p0 + j + 4];
    int s2 = srcs[p0 + j + 8], s3 = srcs[p0 + j + 12];
    float l0 = als[s0] + aldv, l1 = als[s1] + aldv;
    float l2 = als[s2] + aldv, l3 = als[s3] + aldv;
    float h0 = h[(long)s0 * lda + c], h1 = h[(long)s1 * lda + c];
    float h2 = h[(long)s2 * lda + c], h3 = h[(long)s3 * lda + c];
    l0 = l0 > 0.f ? l0 : 0.2f * l0;
    l1 = l1 > 0.f ? l1 : 0.2f * l1;
    l2 = l2 > 0.f ? l2 : 0.2f * l2;
    l3 = l3 > 0.f ? l3 : 0.2f * l3;
    float e0 = __expf(l0), e1 = __expf(l1), e2 = __expf(l2), e3 = __expf(l3);
    dsum += e0 + e1 + e2 + e3;
    acc += e0 * h0 + e1 * h1 + e2 * h2 + e3 * h3;
  }
  for (; j < deg; j += 4) {
    int s = srcs[p0 + j];
    float l = als[s] + aldv;
    l = l > 0.f ? l : 0.2f * l;
    float e = __expf(l);
    dsum += e;
    acc += e * h[(long)s * lda + c];
  }
  #pragma unroll
  for (int d = 16; d < 64; d <<= 1) {
    acc += __shfl_xor(acc, d);
    dsum += __shfl_xor(dsum, d);
  }
  if (lane < 16)
    out[(long)wid * 16 + lane] = acc / (dsum + 1e-16f) + bias[lane];
}

// ---------------- launch ----------------

extern "C" void kernel_launch(void* const* d_in, const int* in_sizes, int n_in,
                              void* d_out, int out_size, void* d_ws, size_t ws_size,
                              hipStream_t stream) {
  const float* x  = (const float*)d_in[0];
  const int*   ei = (const int*)d_in[1];
  const float* W0 = (const float*)d_in[2];
  const float* as0= (const float*)d_in[3];
  const float* ad0= (const float*)d_in[4];
  const float* b0 = (const float*)d_in[5];
  const float* W1 = (const float*)d_in[6];
  const float* as1= (const float*)d_in[7];
  const float* ad1= (const float*)d_in[8];
  const float* b1 = (const float*)d_in[9];
  const float* W2 = (const float*)d_in[10];
  const float* as2= (const float*)d_in[11];
  const float* ad2= (const float*)d_in[12];
  const float* b2 = (const float*)d_in[13];
  float* out = (float*)d_out;

  int E = in_sizes[1] / 2;
  int n = in_sizes[0] / GENES;

  char* ws = (char*)d_ws;
  size_t off = 0;
  auto alloc = [&](size_t bytes) {
    void* p = ws + off;
    off = (off + bytes + 255) & ~(size_t)255;
    return p;
  };
  int* ptr   = (int*)alloc((size_t)(n + 1) * sizeof(int));
  int* cur   = (int*)alloc((size_t)n * sizeof(int));
  int* bsum  = (int*)alloc(512 * sizeof(int));
  int* srcs  = (int*)alloc((size_t)E * sizeof(int));
  unsigned short* Ah = (unsigned short*)alloc((size_t)n * 128 * sizeof(unsigned short));
  unsigned short* Bh = (unsigned short*)alloc((size_t)n * 128 * sizeof(unsigned short));
  float* A2  = (float*)alloc((size_t)n * 16 * sizeof(float));
  float* als = (float*)alloc((size_t)n * 8 * sizeof(float));
  float* ald = (float*)alloc((size_t)n * 8 * sizeof(float));
  unsigned short* P = (unsigned short*)alloc((size_t)163840 * sizeof(unsigned short));
  unsigned short* P0 = P;
  unsigned short* P1 = P + 131072;
  unsigned short* P2 = P + 147456;

  int eb = (E + 255) / 256;
  int nb = (n + 255) / 256;
  hipMemsetAsync(cur, 0, (size_t)n * sizeof(int), stream);
  k_wpackdeg<<<eb, 256, 0, stream>>>(W0, W1, W2, P, GENES, ei, cur, E);
  k_scan1<<<nb, 256, 0, stream>>>(cur, ptr, bsum, n);   // zeroes cur in place
  k_scan2<<<1, 256, 0, stream>>>(bsum, nb);
  k_scan3<<<nb, 256, 0, stream>>>(ptr, bsum, n);

  int mgb  = (n + 63) / 64;
  int aggb = (int)(((long)n * 64 + 255) / 256);

  // layer 0: x @ W0 -> Ah fp16 (+als/ald, +fused CSR scatter); agg -> Bh
  k_mgemm13<<<mgb, 512, 0, stream>>>(x, P0, Ah, als, ald, as0, ad0, n, GENES,
                                     ei, ptr, cur, srcs, E);
  k_agg128h<<<aggb, 256, 0, stream>>>(Ah, als, ald, ptr, srcs, b0, Bh, n);

  // layer 1: Bh @ W1 -> Ah fp16 (+als/ald), aggregate -> Bh fp16 (ELU)
  k_mgemm7<8, true, true><<<mgb, 512, 0, stream>>>(
      Bh, P1, Ah, als, ald, as1, ad1, n, 128, 4, 128);
  k_agg128h<<<aggb, 256, 0, stream>>>(Ah, als, ald, ptr, srcs, b1, Bh, n);

  // layer 2: Bh @ W2 (padded) -> A2 fp32 [n][16] (+als/ald H=1), aggregate -> out
  k_mgemm7<1, true, false><<<mgb, 512, 0, stream>>>(
      Bh, P2, A2, als, ald, as2, ad2, n, 128, 4, 16);
  k_agg16<<<aggb, 256, 0, stream>>>(A2, als, ald, ptr, srcs, b2, out, n, 16);
}

// Round 21
// 262.851 us; speedup vs baseline: 1.0728x; 1.0090x over previous
//
#include <hip/hip_runtime.h>
#include <hip/hip_bf16.h>
#include <math.h>

#define GENES 1000

typedef __attribute__((ext_vector_type(8))) _Float16 half8;
typedef __attribute__((ext_vector_type(4))) float f32x4;
typedef __attribute__((ext_vector_type(4))) unsigned int uint4v;
typedef __attribute__((ext_vector_type(2))) unsigned int uint2v;

__device__ inline float f16lo(unsigned int v) {
  return (float)__builtin_bit_cast(_Float16, (unsigned short)(v & 0xffffu));
}
__device__ inline float f16hi(unsigned int v) {
  return (float)__builtin_bit_cast(_Float16, (unsigned short)(v >> 16));
}
__device__ inline unsigned int pk(float a, float b) {
  return __builtin_bit_cast(unsigned int, __builtin_amdgcn_cvt_pkrtz(a, b));
}

// async global->LDS, 16B per lane; dest = wave-uniform base + lane*16 (m104),
// per-lane source (m173). Tracked ONLY by vmcnt -> counted waits possible.
__device__ inline void gload16(const void* g, void* l) {
  __builtin_amdgcn_global_load_lds(
      (const __attribute__((address_space(1))) unsigned int*)g,
      (__attribute__((address_space(3))) unsigned int*)l, 16, 0, 0);
}

// counted vm wait (literal) + scheduling fence
__device__ __forceinline__ void waitvm(int n) {
  __builtin_amdgcn_sched_barrier(0);
  if (n <= 0)      asm volatile("s_waitcnt vmcnt(0)" ::: "memory");
  else             asm volatile("s_waitcnt vmcnt(2)" ::: "memory");
  __builtin_amdgcn_sched_barrier(0);
}

// ---------------- CSR build ----------------

__global__ void k_scan1(int* __restrict__ deg, int* __restrict__ ptr,
                        int* __restrict__ bsum, int n) {
  __shared__ int ws[4];
  int t = threadIdx.x, b = blockIdx.x;
  int i = b * 256 + t;
  int lane = t & 63, w = t >> 6;
  int x = 0;
  if (i < n) { x = deg[i]; deg[i] = 0; }
  #pragma unroll
  for (int d = 1; d < 64; d <<= 1) {
    int y = __shfl_up(x, d);
    if (lane >= d) x += y;
  }
  if (lane == 63) ws[w] = x;
  __syncthreads();
  if (t == 0) {
    int s = 0;
    #pragma unroll
    for (int k = 0; k < 4; ++k) { s += ws[k]; ws[k] = s; }
  }
  __syncthreads();
  int incl = x + (w ? ws[w - 1] : 0);
  if (i < n) ptr[i + 1] = incl;
  if (t == 255) bsum[b] = incl;
  if (i == 0) ptr[0] = 0;
}

__global__ void k_scan2(int* __restrict__ bsum, int nb) {
  __shared__ int ws[4];
  int t = threadIdx.x;
  int lane = t & 63, w = t >> 6;
  int v = (t < nb) ? bsum[t] : 0;
  int x = v;
  #pragma unroll
  for (int d = 1; d < 64; d <<= 1) {
    int y = __shfl_up(x, d);
    if (lane >= d) x += y;
  }
  if (lane == 63) ws[w] = x;
  __syncthreads();
  if (t == 0) {
    int s = 0;
    #pragma unroll
    for (int k = 0; k < 4; ++k) { s += ws[k]; ws[k] = s; }
  }
  __syncthreads();
  int incl = x + (w ? ws[w - 1] : 0);
  if (t < nb) bsum[t] = incl - v;
}

__global__ void k_scan3(int* __restrict__ ptr, const int* __restrict__ bsum, int n) {
  int i = blockIdx.x * 256 + threadIdx.x;
  if (i < n) ptr[i + 1] += bsum[blockIdx.x];
}

// ---------------- W pack + degree count (fused) --------------------------------
// pack: idx = s*4096 + q*1024 + col*8 + j (k = s*32+q*8+j), fp16.
// W0 -> 32 ksteps (K zero-padded to 1024), W1 -> 4, W2 -> 4 (cols pad 128).

__global__ void k_wpackdeg(const float* __restrict__ W0, const float* __restrict__ W1,
                           const float* __restrict__ W2, unsigned short* __restrict__ P,
                           int K0, const int* __restrict__ ei, int* __restrict__ deg,
                           int E) {
  int t = blockIdx.x * blockDim.x + threadIdx.x;
  if (t < 163840) {
    const float* W; int K, N, e;
    if (t < 131072)      { W = W0; K = K0;  N = 128; e = t; }
    else if (t < 147456) { W = W1; K = 128; N = 128; e = t - 131072; }
    else                 { W = W2; K = 128; N = 16;  e = t - 147456; }
    int s = e >> 12, rem = e & 4095;
    int q = rem >> 10, col = (rem >> 3) & 127, j = rem & 7;
    int k = s * 32 + q * 8 + j;
    float v = (k < K && col < N) ? W[(long)k * N + col] : 0.f;
    _Float16 h = (_Float16)v;
    P[t] = __builtin_bit_cast(unsigned short, h);
  }
  if (t < E) atomicAdd(&deg[ei[E + t]], 1);
}

// ---------------- layer-0 GEMM: 3-deep counted-vmcnt pipeline + fused scatter --
// 512 threads = 8 waves (4 row-groups x 2 col-groups); BM=64, BN=128, BK=32.
// 3-deep LDS buffers (48KB -> 3 blocks/CU, +50% TLP vs r20's 64KB/2); prologue
// issues tiles 0,1 then the CSR scatter (vm ops issued LAST -> in-order vmcnt
// retirement keeps counted waits valid); per step: vmcnt(2) [tile s landed,
// tile s+1 in flight ACROSS the barrier] -> raw s_barrier -> compute ->
// issue tile s+2 into buf (s+2)%3 (safe: its prior readers done pre-barrier).
// No vmcnt(0) drain in the main loop. Fused epilogue: fp16 out + als/ald.

__global__ __launch_bounds__(512) void k_mgemm14(
    const float* __restrict__ A, const unsigned short* __restrict__ Pb,
    unsigned short* __restrict__ outp, float* __restrict__ als,
    float* __restrict__ ald, const float* __restrict__ avs,
    const float* __restrict__ avd, int M, int K,
    const int* __restrict__ ei, const int* __restrict__ ptr,
    int* __restrict__ cur, int* __restrict__ srcs, int E) {
  __shared__ __align__(16) char lds[49152];  // A: 3x8KB | B: 3x8KB

  int t = threadIdx.x, lane = t & 63, wv = t >> 6;
  int r15 = lane & 15, q = lane >> 4;
  int wr = wv >> 1, wc = wv & 1;
  long row0 = (long)blockIdx.x * 64;

  // staging: thread -> row = t>>3 (0..63), seg = t&7 (16B of 128B row-chunk)
  int srow = t >> 3, sseg = t & 7;
  int gseg = sseg ^ (srow & 7);            // pre-swizzled source (rule 21)
  long arow = row0 + srow; if (arow >= M) arow = M - 1;
  const char* gA = (const char*)(A + arow * (long)K) + gseg * 16;
  const char* gB = (const char*)Pb + t * 16;

  f32x4 acc[4];
  #pragma unroll
  for (int nt = 0; nt < 4; ++nt) acc[nt] = (f32x4){0.f, 0.f, 0.f, 0.f};

  auto issue = [&](int s) {
    char* Ab = lds + (s % 3) * 8192;
    char* Bb = lds + 24576 + (s % 3) * 8192;
    gload16(gA + (size_t)s * 128, Ab + t * 16);
    gload16(gB + (size_t)s * 8192, Bb + t * 16);
  };
  auto compute = [&](int s) {
    const char* Ab = lds + (s % 3) * 8192;
    const char* Bb = lds + 24576 + (s % 3) * 8192;
    int row = wr * 16 + r15;
    int sw = row & 7;
    uint4v alo = *(const uint4v*)(Ab + row * 128 + ((2 * q) ^ sw) * 16);
    uint4v ahi = *(const uint4v*)(Ab + row * 128 + ((2 * q + 1) ^ sw) * 16);
    float4 lo = __builtin_bit_cast(float4, alo);
    float4 hi = __builtin_bit_cast(float4, ahi);
    uint4v au;
    au[0] = pk(lo.x, lo.y); au[1] = pk(lo.z, lo.w);
    au[2] = pk(hi.x, hi.y); au[3] = pk(hi.z, hi.w);
    half8 af = __builtin_bit_cast(half8, au);
    #pragma unroll
    for (int nt = 0; nt < 4; ++nt) {
      half8 bf = *(const half8*)(Bb + q * 2048 + (wc * 64 + nt * 16 + r15) * 16);
      acc[nt] = __builtin_amdgcn_mfma_f32_16x16x32_f16(af, bf, acc[nt], 0, 0, 0);
    }
  };

  issue(0); issue(1);                      // 4 loads/thread in flight

  // fused CSR scatter: 1024 edges per block (2 per thread). Issued AFTER the
  // tile loads -> its vm ops are the newest; vmcnt(2) below retires them and
  // tile 0 together (in-order retirement), steady state unaffected.
  {
    int e0 = blockIdx.x * 1024 + t;
    if (e0 < E) {
      int d = ei[E + e0];
      int pos = ptr[d] + atomicAdd(&cur[d], 1);
      srcs[pos] = ei[e0];
    }
    int e1 = e0 + 512;
    if (e1 < E) {
      int d = ei[E + e1];
      int pos = ptr[d] + atomicAdd(&cur[d], 1);
      srcs[pos] = ei[e1];
    }
  }

  #pragma unroll
  for (int s = 0; s < 32; ++s) {
    waitvm(s < 31 ? 2 : 0);                // tile s landed; s+1 stays in flight
    __builtin_amdgcn_s_barrier();          // collective: tile s fully in LDS
    compute(s);
    if (s + 2 < 32) issue(s + 2);          // refill buf (s+2)%3 (not s%3)
  }

  // ---- epilogue: C/D layout col=lane&15, row=(lane>>4)*4+i ----
  long rbase = row0 + wr * 16 + q * 4;
  #pragma unroll
  for (int i = 0; i < 4; ++i) {
    long r = rbase + i;
    if (r < M) {
      #pragma unroll
      for (int nt = 0; nt < 4; ++nt) {
        int col = wc * 64 + nt * 16 + r15;
        _Float16 hv = (_Float16)acc[nt][i];
        outp[r * 128 + col] = __builtin_bit_cast(unsigned short, hv);
      }
    }
  }
  #pragma unroll
  for (int nt = 0; nt < 4; ++nt) {
    int head = wc * 4 + nt;
    float cs = avs[head * 16 + r15];
    float cd = avd[head * 16 + r15];
    #pragma unroll
    for (int i = 0; i < 4; ++i) {
      float s1 = acc[nt][i] * cs;
      float s2 = acc[nt][i] * cd;
      #pragma unroll
      for (int d = 1; d < 16; d <<= 1) {
        s1 += __shfl_xor(s1, d);
        s2 += __shfl_xor(s2, d);
      }
      if (r15 == 0) {
        long r = rbase + i;
        if (r < M) { als[r * 8 + head] = s1; ald[r * 8 + head] = s2; }
      }
    }
  }
}

// ---------------- MFMA fp16 GEMM (layers 1,2): 64-VGPR dbuf (round-13) --------

template<int HH, bool AF16, bool OF16>
__global__ __launch_bounds__(512) void k_mgemm7(
    const void* __restrict__ Ap, const unsigned short* __restrict__ Pb,
    void* __restrict__ outp, float* __restrict__ als, float* __restrict__ ald,
    const float* __restrict__ avs, const float* __restrict__ avd,
    int M, int K, int nst, int ldc) {
  __shared__ __align__(16) char lds[24576];
  char* bA0 = lds;
  char* bA1 = lds + 4096;
  char* bB0 = lds + 8192;
  char* bB1 = lds + 16384;

  int t = threadIdx.x, lane = t & 63;
  int r15 = lane & 15, q = lane >> 4;
  int wv = t >> 6;
  int wr = wv >> 1, wc = wv & 1;
  long row0 = (long)blockIdx.x * 64;

  int srow = t >> 3, sseg = t & 7;
  long arow = row0 + srow; if (arow >= M) arow = M - 1;
  const float* pa32 = (const float*)Ap + arow * (long)K;
  const unsigned short* pa16 = (const unsigned short*)Ap + arow * (long)K;

  f32x4 acc[4];
  #pragma unroll
  for (int nt = 0; nt < 4; ++nt) acc[nt] = (f32x4){0.f, 0.f, 0.f, 0.f};

  uint4v rA0, rA1, rB0, rB1;
  uint2v sA0, sA1;

  auto loadA = [&](int s, uint4v& r32, uint2v& r16) {
    int k0 = s * 32 + sseg * 4;
    if constexpr (AF16) {
      r16 = (k0 < K) ? *(const uint2v*)(pa16 + k0) : (uint2v){0u, 0u};
    } else {
      r32 = (k0 < K) ? *(const uint4v*)(pa32 + k0) : (uint4v){0u, 0u, 0u, 0u};
    }
  };
  auto writeA = [&](char* buf, uint4v r32, uint2v r16) {
    char* p = buf + ((sseg >> 1) * 1024 + srow * 16 + (sseg & 1) * 8);
    if constexpr (AF16) {
      *(uint2v*)p = r16;
    } else {
      float4 f = __builtin_bit_cast(float4, r32);
      uint2v h;
      h[0] = pk(f.x, f.y);
      h[1] = pk(f.z, f.w);
      *(uint2v*)p = h;
    }
  };
  auto loadB = [&](int s, uint4v& r) {
    r = *(const uint4v*)(Pb + (size_t)s * 4096 + t * 8);
  };
  auto writeB = [&](char* buf, uint4v r) {
    *(uint4v*)(buf + t * 16) = r;
  };
  auto compute = [&](const char* bA, const char* bB) {
    half8 af = *(const half8*)(bA + q * 1024 + (wr * 16 + r15) * 16);
    #pragma unroll
    for (int nt = 0; nt < 4; ++nt) {
      half8 bf = *(const half8*)(bB + q * 2048 + (wc * 64 + nt * 16 + r15) * 16);
      acc[nt] = __builtin_amdgcn_mfma_f32_16x16x32_f16(af, bf, acc[nt], 0, 0, 0);
    }
  };

  loadA(0, rA0, sA0); loadB(0, rB0);
  if (nst > 1) { loadA(1, rA1, sA1); loadB(1, rB1); }
  writeA(bA0, rA0, sA0); writeB(bB0, rB0);
  __syncthreads();

  for (int s = 0; s < nst; s += 2) {
    if (s + 2 < nst) { loadA(s + 2, rA0, sA0); loadB(s + 2, rB0); }
    compute(bA0, bB0);
    if (s + 1 < nst) { writeA(bA1, rA1, sA1); writeB(bB1, rB1); }
    __syncthreads();
    if (s + 1 < nst) {
      if (s + 3 < nst) { loadA(s + 3, rA1, sA1); loadB(s + 3, rB1); }
      compute(bA1, bB1);
      if (s + 2 < nst) { writeA(bA0, rA0, sA0); writeB(bB0, rB0); }
      __syncthreads();
    }
  }

  long rbase = row0 + wr * 16 + q * 4;
  if constexpr (OF16) {
    unsigned short* o16 = (unsigned short*)outp;
    #pragma unroll
    for (int i = 0; i < 4; ++i) {
      long r = rbase + i;
      if (r < M) {
        #pragma unroll
        for (int nt = 0; nt < 4; ++nt) {
          int col = wc * 64 + nt * 16 + r15;
          _Float16 hv = (_Float16)acc[nt][i];
          o16[r * ldc + col] = __builtin_bit_cast(unsigned short, hv);
        }
      }
    }
  } else {
    float* o32 = (float*)outp;
    #pragma unroll
    for (int i = 0; i < 4; ++i) {
      long r = rbase + i;
      if (r < M) {
        #pragma unroll
        for (int nt = 0; nt < 4; ++nt) {
          int col = wc * 64 + nt * 16 + r15;
          if (col < ldc) o32[r * ldc + col] = acc[nt][i];
        }
      }
    }
  }
  #pragma unroll
  for (int nt = 0; nt < 4; ++nt) {
    int head = wc * 4 + nt;
    if (head < HH) {
      float cs = avs[head * 16 + r15];
      float cd = avd[head * 16 + r15];
      #pragma unroll
      for (int i = 0; i < 4; ++i) {
        float s1 = acc[nt][i] * cs;
        float s2 = acc[nt][i] * cd;
        #pragma unroll
        for (int d = 1; d < 16; d <<= 1) {
          s1 += __shfl_xor(s1, d);
          s2 += __shfl_xor(s2, d);
        }
        if (r15 == 0) {
          long r = rbase + i;
          if (r < M) { als[r * HH + head] = s1; ald[r * HH + head] = s2; }
        }
      }
    }
  }
}

// ---------------- per-dst aggregation, H=8, C=16, fp16 h, ELU ------------------
// Split-wave halves, alternate edges, 4-edge batches; no max pass.

__global__ void k_agg128h(const unsigned short* __restrict__ h,
                          const float* __restrict__ als, const float* __restrict__ ald,
                          const int* __restrict__ ptr, const int* __restrict__ srcs,
                          const float* __restrict__ bias,
                          unsigned short* __restrict__ out, int n) {
  int wid = (int)(((long)blockIdx.x * blockDim.x + threadIdx.x) >> 6);
  if (wid >= n) return;
  int lane = threadIdx.x & 63;
  int half = lane >> 5, l5 = lane & 31;
  int c0 = 4 * l5;
  int hB = l5 >> 2;
  int p0 = ptr[wid], deg = ptr[wid + 1] - p0;
  float aldB = ald[wid * 8 + hB];
  float a0 = 0.f, a1 = 0.f, a2 = 0.f, a3 = 0.f, dsum = 0.f;
  int j = half;
  for (; j + 6 < deg; j += 8) {
    int s0 = srcs[p0 + j],     s1 = srcs[p0 + j + 2];
    int s2 = srcs[p0 + j + 4], s3 = srcs[p0 + j + 6];
    float l0 = als[s0 * 8 + hB] + aldB;
    float l1 = als[s1 * 8 + hB] + aldB;
    float l2 = als[s2 * 8 + hB] + aldB;
    float l3 = als[s3 * 8 + hB] + aldB;
    uint2v h0 = *(const uint2v*)(h + (long)s0 * 128 + c0);
    uint2v h1 = *(const uint2v*)(h + (long)s1 * 128 + c0);
    uint2v h2 = *(const uint2v*)(h + (long)s2 * 128 + c0);
    uint2v h3 = *(const uint2v*)(h + (long)s3 * 128 + c0);
    l0 = l0 > 0.f ? l0 : 0.2f * l0;
    l1 = l1 > 0.f ? l1 : 0.2f * l1;
    l2 = l2 > 0.f ? l2 : 0.2f * l2;
    l3 = l3 > 0.f ? l3 : 0.2f * l3;
    float e0 = __expf(l0), e1 = __expf(l1), e2 = __expf(l2), e3 = __expf(l3);
    dsum += e0 + e1 + e2 + e3;
    a0 += e0 * f16lo(h0[0]) + e1 * f16lo(h1[0]) + e2 * f16lo(h2[0]) + e3 * f16lo(h3[0]);
    a1 += e0 * f16hi(h0[0]) + e1 * f16hi(h1[0]) + e2 * f16hi(h2[0]) + e3 * f16hi(h3[0]);
    a2 += e0 * f16lo(h0[1]) + e1 * f16lo(h1[1]) + e2 * f16lo(h2[1]) + e3 * f16lo(h3[1]);
    a3 += e0 * f16hi(h0[1]) + e1 * f16hi(h1[1]) + e2 * f16hi(h2[1]) + e3 * f16hi(h3[1]);
  }
  for (; j < deg; j += 2) {
    int s = srcs[p0 + j];
    float l = als[s * 8 + hB] + aldB;
    l = l > 0.f ? l : 0.2f * l;
    float e = __expf(l);
    uint2v hv = *(const uint2v*)(h + (long)s * 128 + c0);
    dsum += e;
    a0 += e * f16lo(hv[0]);
    a1 += e * f16hi(hv[0]);
    a2 += e * f16lo(hv[1]);
    a3 += e * f16hi(hv[1]);
  }
  a0 += __shfl_xor(a0, 32);
  a1 += __shfl_xor(a1, 32);
  a2 += __shfl_xor(a2, 32);
  a3 += __shfl_xor(a3, 32);
  dsum += __shfl_xor(dsum, 32);
  if (half == 0) {
    float inv = 1.f / (dsum + 1e-16f);
    float o0 = a0 * inv + bias[c0];
    float o1 = a1 * inv + bias[c0 + 1];
    float o2 = a2 * inv + bias[c0 + 2];
    float o3 = a3 * inv + bias[c0 + 3];
    o0 = o0 > 0.f ? o0 : (__expf(o0) - 1.f);
    o1 = o1 > 0.f ? o1 : (__expf(o1) - 1.f);
    o2 = o2 > 0.f ? o2 : (__expf(o2) - 1.f);
    o3 = o3 > 0.f ? o3 : (__expf(o3) - 1.f);
    uint2v po;
    po[0] = __builtin_bit_cast(unsigned int, __builtin_amdgcn_cvt_pkrtz(o0, o1));
    po[1] = __builtin_bit_cast(unsigned int, __builtin_amdgcn_cvt_pkrtz(o2, o3));
    *(uint2v*)(out + (long)wid * 128 + c0) = po;
  }
}

// ---------------- per-dst aggregation, H=1, C=16, fp32, no max, 4-batch --------

__global__ void k_agg16(const float* __restrict__ h, const float* __restrict__ als,
                        const float* __restrict__ ald, const int* __restrict__ ptr,
                        const int* __restrict__ srcs, const float* __restrict__ bias,
                        float* __restrict__ out, int n, int lda) {
  int wid = (int)(((long)blockIdx.x * blockDim.x + threadIdx.x) >> 6);
  if (wid >= n) return;
  int lane = threadIdx.x & 63;
  int p0 = ptr[wid], deg = ptr[wid + 1] - p0;
  float aldv = ald[wid];
  int g = lane >> 4, c = lane & 15;
  float acc = 0.f, dsum = 0.f;
  int j = g;
  for (; j + 12 < deg; j += 16) {
    int s0 = srcs[p0 + j],     s1 = srcs[p0 + j + 4];
    int s2 = srcs[p0 + j + 8], s3 = srcs[p0 + j + 12];
    float l0 = als[s0] + aldv, l1 = als[s1] + aldv;
    float l2 = als[s2] + aldv, l3 = als[s3] + aldv;
    float h0 = h[(long)s0 * lda + c], h1 = h[(long)s1 * lda + c];
    float h2 = h[(long)s2 * lda + c], h3 = h[(long)s3 * lda + c];
    l0 = l0 > 0.f ? l0 : 0.2f * l0;
    l1 = l1 > 0.f ? l1 : 0.2f * l1;
    l2 = l2 > 0.f ? l2 : 0.2f * l2;
    l3 = l3 > 0.f ? l3 : 0.2f * l3;
    float e0 = __expf(l0), e1 = __expf(l1), e2 = __expf(l2), e3 = __expf(l3);
    dsum += e0 + e1 + e2 + e3;
    acc += e0 * h0 + e1 * h1 + e2 * h2 + e3 * h3;
  }
  for (; j < deg; j += 4) {
    int s = srcs[p0 + j];
    float l = als[s] + aldv;
    l = l > 0.f ? l : 0.2f * l;
    float e = __expf(l);
    dsum += e;
    acc += e * h[(long)s * lda + c];
  }
  #pragma unroll
  for (int d = 16; d < 64; d <<= 1) {
    acc += __shfl_xor(acc, d);
    dsum += __shfl_xor(dsum, d);
  }
  if (lane < 16)
    out[(long)wid * 16 + lane] = acc / (dsum + 1e-16f) + bias[lane];
}

// ---------------- launch ----------------

extern "C" void kernel_launch(void* const* d_in, const int* in_sizes, int n_in,
                              void* d_out, int out_size, void* d_ws, size_t ws_size,
                              hipStream_t stream) {
  const float* x  = (const float*)d_in[0];
  const int*   ei = (const int*)d_in[1];
  const float* W0 = (const float*)d_in[2];
  const float* as0= (const float*)d_in[3];
  const float* ad0= (const float*)d_in[4];
  const float* b0 = (const float*)d_in[5];
  const float* W1 = (const float*)d_in[6];
  const float* as1= (const float*)d_in[7];
  const float* ad1= (const float*)d_in[8];
  const float* b1 = (const float*)d_in[9];
  const float* W2 = (const float*)d_in[10];
  const float* as2= (const float*)d_in[11];
  const float* ad2= (const float*)d_in[12];
  const float* b2 = (const float*)d_in[13];
  float* out = (float*)d_out;

  int E = in_sizes[1] / 2;
  int n = in_sizes[0] / GENES;

  char* ws = (char*)d_ws;
  size_t off = 0;
  auto alloc = [&](size_t bytes) {
    void* p = ws + off;
    off = (off + bytes + 255) & ~(size_t)255;
    return p;
  };
  int* ptr   = (int*)alloc((size_t)(n + 1) * sizeof(int));
  int* cur   = (int*)alloc((size_t)n * sizeof(int));
  int* bsum  = (int*)alloc(512 * sizeof(int));
  int* srcs  = (int*)alloc((size_t)E * sizeof(int));
  unsigned short* Ah = (unsigned short*)alloc((size_t)n * 128 * sizeof(unsigned short));
  unsigned short* Bh = (unsigned short*)alloc((size_t)n * 128 * sizeof(unsigned short));
  float* A2  = (float*)alloc((size_t)n * 16 * sizeof(float));
  float* als = (float*)alloc((size_t)n * 8 * sizeof(float));
  float* ald = (float*)alloc((size_t)n * 8 * sizeof(float));
  unsigned short* P = (unsigned short*)alloc((size_t)163840 * sizeof(unsigned short));
  unsigned short* P0 = P;
  unsigned short* P1 = P + 131072;
  unsigned short* P2 = P + 147456;

  int eb = (E + 255) / 256;
  int nb = (n + 255) / 256;
  hipMemsetAsync(cur, 0, (size_t)n * sizeof(int), stream);
  k_wpackdeg<<<eb, 256, 0, stream>>>(W0, W1, W2, P, GENES, ei, cur, E);
  k_scan1<<<nb, 256, 0, stream>>>(cur, ptr, bsum, n);   // zeroes cur in place
  k_scan2<<<1, 256, 0, stream>>>(bsum, nb);
  k_scan3<<<nb, 256, 0, stream>>>(ptr, bsum, n);

  int mgb  = (n + 63) / 64;
  int aggb = (int)(((long)n * 64 + 255) / 256);

  // layer 0: x @ W0 -> Ah fp16 (+als/ald, +fused CSR scatter); agg -> Bh
  k_mgemm14<<<mgb, 512, 0, stream>>>(x, P0, Ah, als, ald, as0, ad0, n, GENES,
                                     ei, ptr, cur, srcs, E);
  k_agg128h<<<aggb, 256, 0, stream>>>(Ah, als, ald, ptr, srcs, b0, Bh, n);

  // layer 1: Bh @ W1 -> Ah fp16 (+als/ald), aggregate -> Bh fp16 (ELU)
  k_mgemm7<8, true, true><<<mgb, 512, 0, stream>>>(
      Bh, P1, Ah, als, ald, as1, ad1, n, 128, 4, 128);
  k_agg128h<<<aggb, 256, 0, stream>>>(Ah, als, ald, ptr, srcs, b1, Bh, n);

  // layer 2: Bh @ W2 (padded) -> A2 fp32 [n][16] (+als/ald H=1), aggregate -> out
  k_mgemm7<1, true, false><<<mgb, 512, 0, stream>>>(
      Bh, P2, A2, als, ald, as2, ad2, n, 128, 4, 16);
  k_agg16<<<aggb, 256, 0, stream>>>(A2, als, ald, ptr, srcs, b2, out, n, 16);
}

// Round 22
// 255.486 us; speedup vs baseline: 1.1037x; 1.0288x over previous
//
#include <hip/hip_runtime.h>
#include <hip/hip_bf16.h>
#include <math.h>

#define GENES 1000

typedef __attribute__((ext_vector_type(8))) _Float16 half8;
typedef __attribute__((ext_vector_type(4))) float f32x4;
typedef __attribute__((ext_vector_type(4))) unsigned int uint4v;
typedef __attribute__((ext_vector_type(2))) unsigned int uint2v;

__device__ inline float f16lo(unsigned int v) {
  return (float)__builtin_bit_cast(_Float16, (unsigned short)(v & 0xffffu));
}
__device__ inline float f16hi(unsigned int v) {
  return (float)__builtin_bit_cast(_Float16, (unsigned short)(v >> 16));
}
__device__ inline unsigned int pk(float a, float b) {
  return __builtin_bit_cast(unsigned int, __builtin_amdgcn_cvt_pkrtz(a, b));
}

// async global->LDS, 16B per lane (m104/m173); tracked only by vmcnt.
__device__ inline void gload16(const void* g, void* l) {
  __builtin_amdgcn_global_load_lds(
      (const __attribute__((address_space(1))) unsigned int*)g,
      (__attribute__((address_space(3))) unsigned int*)l, 16, 0, 0);
}

__device__ __forceinline__ void waitvm(int n) {
  __builtin_amdgcn_sched_barrier(0);
  if (n <= 0)      asm volatile("s_waitcnt vmcnt(0)" ::: "memory");
  else             asm volatile("s_waitcnt vmcnt(2)" ::: "memory");
  __builtin_amdgcn_sched_barrier(0);
}

// ---------------- CSR build ----------------

__global__ void k_scan1(int* __restrict__ deg, int* __restrict__ ptr,
                        int* __restrict__ bsum, int n) {
  __shared__ int ws[4];
  int t = threadIdx.x, b = blockIdx.x;
  int i = b * 256 + t;
  int lane = t & 63, w = t >> 6;
  int x = 0;
  if (i < n) { x = deg[i]; deg[i] = 0; }
  #pragma unroll
  for (int d = 1; d < 64; d <<= 1) {
    int y = __shfl_up(x, d);
    if (lane >= d) x += y;
  }
  if (lane == 63) ws[w] = x;
  __syncthreads();
  if (t == 0) {
    int s = 0;
    #pragma unroll
    for (int k = 0; k < 4; ++k) { s += ws[k]; ws[k] = s; }
  }
  __syncthreads();
  int incl = x + (w ? ws[w - 1] : 0);
  if (i < n) ptr[i + 1] = incl;
  if (t == 255) bsum[b] = incl;
  if (i == 0) ptr[0] = 0;
}

__global__ void k_scan2(int* __restrict__ bsum, int nb) {
  __shared__ int ws[4];
  int t = threadIdx.x;
  int lane = t & 63, w = t >> 6;
  int v = (t < nb) ? bsum[t] : 0;
  int x = v;
  #pragma unroll
  for (int d = 1; d < 64; d <<= 1) {
    int y = __shfl_up(x, d);
    if (lane >= d) x += y;
  }
  if (lane == 63) ws[w] = x;
  __syncthreads();
  if (t == 0) {
    int s = 0;
    #pragma unroll
    for (int k = 0; k < 4; ++k) { s += ws[k]; ws[k] = s; }
  }
  __syncthreads();
  int incl = x + (w ? ws[w - 1] : 0);
  if (t < nb) bsum[t] = incl - v;
}

__global__ void k_scan3(int* __restrict__ ptr, const int* __restrict__ bsum, int n) {
  int i = blockIdx.x * 256 + threadIdx.x;
  if (i < n) ptr[i + 1] += bsum[blockIdx.x];
}

// ---------------- W pack + degree count (fused) --------------------------------

__global__ void k_wpackdeg(const float* __restrict__ W0, const float* __restrict__ W1,
                           const float* __restrict__ W2, unsigned short* __restrict__ P,
                           int K0, const int* __restrict__ ei, int* __restrict__ deg,
                           int E) {
  int t = blockIdx.x * blockDim.x + threadIdx.x;
  if (t < 163840) {
    const float* W; int K, N, e;
    if (t < 131072)      { W = W0; K = K0;  N = 128; e = t; }
    else if (t < 147456) { W = W1; K = 128; N = 128; e = t - 131072; }
    else                 { W = W2; K = 128; N = 16;  e = t - 147456; }
    int s = e >> 12, rem = e & 4095;
    int q = rem >> 10, col = (rem >> 3) & 127, j = rem & 7;
    int k = s * 32 + q * 8 + j;
    float v = (k < K && col < N) ? W[(long)k * N + col] : 0.f;
    _Float16 h = (_Float16)v;
    P[t] = __builtin_bit_cast(unsigned short, h);
  }
  if (t < E) atomicAdd(&deg[ei[E + t]], 1);
}

// ---------------- layer-0 GEMM: 3-deep counted-vmcnt pipeline + fused scatter --

__global__ __launch_bounds__(512) void k_mgemm14(
    const float* __restrict__ A, const unsigned short* __restrict__ Pb,
    unsigned short* __restrict__ outp, float* __restrict__ als,
    float* __restrict__ ald, const float* __restrict__ avs,
    const float* __restrict__ avd, int M, int K,
    const int* __restrict__ ei, const int* __restrict__ ptr,
    int* __restrict__ cur, int* __restrict__ srcs, int E) {
  __shared__ __align__(16) char lds[49152];  // A: 3x8KB | B: 3x8KB

  int t = threadIdx.x, lane = t & 63, wv = t >> 6;
  int r15 = lane & 15, q = lane >> 4;
  int wr = wv >> 1, wc = wv & 1;
  long row0 = (long)blockIdx.x * 64;

  int srow = t >> 3, sseg = t & 7;
  int gseg = sseg ^ (srow & 7);            // pre-swizzled source (rule 21)
  long arow = row0 + srow; if (arow >= M) arow = M - 1;
  const char* gA = (const char*)(A + arow * (long)K) + gseg * 16;
  const char* gB = (const char*)Pb + t * 16;

  f32x4 acc[4];
  #pragma unroll
  for (int nt = 0; nt < 4; ++nt) acc[nt] = (f32x4){0.f, 0.f, 0.f, 0.f};

  auto issue = [&](int s) {
    char* Ab = lds + (s % 3) * 8192;
    char* Bb = lds + 24576 + (s % 3) * 8192;
    gload16(gA + (size_t)s * 128, Ab + t * 16);
    gload16(gB + (size_t)s * 8192, Bb + t * 16);
  };
  auto compute = [&](int s) {
    const char* Ab = lds + (s % 3) * 8192;
    const char* Bb = lds + 24576 + (s % 3) * 8192;
    int row = wr * 16 + r15;
    int sw = row & 7;
    uint4v alo = *(const uint4v*)(Ab + row * 128 + ((2 * q) ^ sw) * 16);
    uint4v ahi = *(const uint4v*)(Ab + row * 128 + ((2 * q + 1) ^ sw) * 16);
    float4 lo = __builtin_bit_cast(float4, alo);
    float4 hi = __builtin_bit_cast(float4, ahi);
    uint4v au;
    au[0] = pk(lo.x, lo.y); au[1] = pk(lo.z, lo.w);
    au[2] = pk(hi.x, hi.y); au[3] = pk(hi.z, hi.w);
    half8 af = __builtin_bit_cast(half8, au);
    #pragma unroll
    for (int nt = 0; nt < 4; ++nt) {
      half8 bf = *(const half8*)(Bb + q * 2048 + (wc * 64 + nt * 16 + r15) * 16);
      acc[nt] = __builtin_amdgcn_mfma_f32_16x16x32_f16(af, bf, acc[nt], 0, 0, 0);
    }
  };

  issue(0); issue(1);

  // fused CSR scatter (issued after tile loads; in-order vmcnt retirement)
  {
    int e0 = blockIdx.x * 1024 + t;
    if (e0 < E) {
      int d = ei[E + e0];
      int pos = ptr[d] + atomicAdd(&cur[d], 1);
      srcs[pos] = ei[e0];
    }
    int e1 = e0 + 512;
    if (e1 < E) {
      int d = ei[E + e1];
      int pos = ptr[d] + atomicAdd(&cur[d], 1);
      srcs[pos] = ei[e1];
    }
  }

  #pragma unroll
  for (int s = 0; s < 32; ++s) {
    waitvm(s < 31 ? 2 : 0);
    __builtin_amdgcn_s_barrier();
    compute(s);
    if (s + 2 < 32) issue(s + 2);
  }

  long rbase = row0 + wr * 16 + q * 4;
  #pragma unroll
  for (int i = 0; i < 4; ++i) {
    long r = rbase + i;
    if (r < M) {
      #pragma unroll
      for (int nt = 0; nt < 4; ++nt) {
        int col = wc * 64 + nt * 16 + r15;
        _Float16 hv = (_Float16)acc[nt][i];
        outp[r * 128 + col] = __builtin_bit_cast(unsigned short, hv);
      }
    }
  }
  #pragma unroll
  for (int nt = 0; nt < 4; ++nt) {
    int head = wc * 4 + nt;
    float cs = avs[head * 16 + r15];
    float cd = avd[head * 16 + r15];
    #pragma unroll
    for (int i = 0; i < 4; ++i) {
      float s1 = acc[nt][i] * cs;
      float s2 = acc[nt][i] * cd;
      #pragma unroll
      for (int d = 1; d < 16; d <<= 1) {
        s1 += __shfl_xor(s1, d);
        s2 += __shfl_xor(s2, d);
      }
      if (r15 == 0) {
        long r = rbase + i;
        if (r < M) { als[r * 8 + head] = s1; ald[r * 8 + head] = s2; }
      }
    }
  }
}

// ---------------- fused agg(H=8,ELU) -> GEMM(K=128) ---------------------------
// Block owns 64 dst rows. Phase 1: 8 waves aggregate 8 nodes each (agg128h's
// proven split-wave/4-batch loop) writing fp16 DIRECTLY into the 16KB LDS
// A-tile ([s][q][row][8] fragment layout) -- the aggregated h never touches
// global (saves the 12.8MB x2 roundtrip + 2 launches). Phase 2: one barrier,
// then 4 MFMA k-steps with B direct from L2 (32KB, hot). Row-wise GEMM =>
// each aggregated row is consumed only by its own block (fusion is legal).
// als/ald are per-layer buffers (in=layer L, out=layer L+1: no read/write race).

template<int HH, bool OF16>
__global__ __launch_bounds__(512) void k_fagg(
    const unsigned short* __restrict__ hsrc,
    const float* __restrict__ als_i, const float* __restrict__ ald_i,
    const int* __restrict__ ptr, const int* __restrict__ srcs,
    const float* __restrict__ bias, const unsigned short* __restrict__ Pb,
    void* __restrict__ outp, float* __restrict__ als_o, float* __restrict__ ald_o,
    const float* __restrict__ avs, const float* __restrict__ avd,
    int M, int ldc) {
  __shared__ __align__(16) unsigned short At[4 * 4 * 64 * 8];  // 16 KB

  int t = threadIdx.x, lane = t & 63, wv = t >> 6;
  int half = lane >> 5, l5 = lane & 31;
  long row0 = (long)blockIdx.x * 64;

  // ---- phase 1: aggregate 8 nodes per wave into the LDS A-tile ----
  int c0 = 4 * l5;
  int hB = l5 >> 2;
  int sA = c0 >> 5, qA = (c0 >> 3) & 3, jA = c0 & 7;
  #pragma unroll 1
  for (int i = 0; i < 8; ++i) {
    int rowL = wv * 8 + i;
    long node = row0 + rowL;
    char* dst = (char*)At + ((sA * 4 + qA) * 64 + rowL) * 16 + (jA ? 8 : 0);
    if (node < M) {
      int p0 = ptr[node], deg = ptr[node + 1] - p0;
      float aldB = ald_i[node * 8 + hB];
      float a0 = 0.f, a1 = 0.f, a2 = 0.f, a3 = 0.f, dsum = 0.f;
      int j = half;
      for (; j + 6 < deg; j += 8) {
        int s0 = srcs[p0 + j],     s1 = srcs[p0 + j + 2];
        int s2 = srcs[p0 + j + 4], s3 = srcs[p0 + j + 6];
        float l0 = als_i[s0 * 8 + hB] + aldB;
        float l1 = als_i[s1 * 8 + hB] + aldB;
        float l2 = als_i[s2 * 8 + hB] + aldB;
        float l3 = als_i[s3 * 8 + hB] + aldB;
        uint2v h0 = *(const uint2v*)(hsrc + (long)s0 * 128 + c0);
        uint2v h1 = *(const uint2v*)(hsrc + (long)s1 * 128 + c0);
        uint2v h2 = *(const uint2v*)(hsrc + (long)s2 * 128 + c0);
        uint2v h3 = *(const uint2v*)(hsrc + (long)s3 * 128 + c0);
        l0 = l0 > 0.f ? l0 : 0.2f * l0;
        l1 = l1 > 0.f ? l1 : 0.2f * l1;
        l2 = l2 > 0.f ? l2 : 0.2f * l2;
        l3 = l3 > 0.f ? l3 : 0.2f * l3;
        float e0 = __expf(l0), e1 = __expf(l1), e2 = __expf(l2), e3 = __expf(l3);
        dsum += e0 + e1 + e2 + e3;
        a0 += e0 * f16lo(h0[0]) + e1 * f16lo(h1[0]) + e2 * f16lo(h2[0]) + e3 * f16lo(h3[0]);
        a1 += e0 * f16hi(h0[0]) + e1 * f16hi(h1[0]) + e2 * f16hi(h2[0]) + e3 * f16hi(h3[0]);
        a2 += e0 * f16lo(h0[1]) + e1 * f16lo(h1[1]) + e2 * f16lo(h2[1]) + e3 * f16lo(h3[1]);
        a3 += e0 * f16hi(h0[1]) + e1 * f16hi(h1[1]) + e2 * f16hi(h2[1]) + e3 * f16hi(h3[1]);
      }
      for (; j < deg; j += 2) {
        int s = srcs[p0 + j];
        float l = als_i[s * 8 + hB] + aldB;
        l = l > 0.f ? l : 0.2f * l;
        float e = __expf(l);
        uint2v hv = *(const uint2v*)(hsrc + (long)s * 128 + c0);
        dsum += e;
        a0 += e * f16lo(hv[0]);
        a1 += e * f16hi(hv[0]);
        a2 += e * f16lo(hv[1]);
        a3 += e * f16hi(hv[1]);
      }
      a0 += __shfl_xor(a0, 32);
      a1 += __shfl_xor(a1, 32);
      a2 += __shfl_xor(a2, 32);
      a3 += __shfl_xor(a3, 32);
      dsum += __shfl_xor(dsum, 32);
      if (half == 0) {
        float inv = 1.f / (dsum + 1e-16f);
        float o0 = a0 * inv + bias[c0];
        float o1 = a1 * inv + bias[c0 + 1];
        float o2 = a2 * inv + bias[c0 + 2];
        float o3 = a3 * inv + bias[c0 + 3];
        o0 = o0 > 0.f ? o0 : (__expf(o0) - 1.f);
        o1 = o1 > 0.f ? o1 : (__expf(o1) - 1.f);
        o2 = o2 > 0.f ? o2 : (__expf(o2) - 1.f);
        o3 = o3 > 0.f ? o3 : (__expf(o3) - 1.f);
        uint2v pv;
        pv[0] = pk(o0, o1);
        pv[1] = pk(o2, o3);
        *(uint2v*)dst = pv;
      }
    } else if (half == 0) {
      *(uint2v*)dst = (uint2v){0u, 0u};   // clean zeros for tail rows
    }
  }
  __syncthreads();

  // ---- phase 2: 64x128 @ W -> out (B direct from L2) ----
  int r15 = lane & 15, q = lane >> 4;
  int wr = wv >> 1, wc = wv & 1;
  f32x4 acc[4];
  #pragma unroll
  for (int nt = 0; nt < 4; ++nt) acc[nt] = (f32x4){0.f, 0.f, 0.f, 0.f};
  #pragma unroll
  for (int s = 0; s < 4; ++s) {
    half8 af = *(const half8*)((const char*)At + ((s * 4 + q) * 64 + wr * 16 + r15) * 16);
    #pragma unroll
    for (int nt = 0; nt < 4; ++nt) {
      int col = wc * 64 + nt * 16 + r15;
      half8 bf = *(const half8*)((const char*)Pb + (size_t)s * 8192 + q * 2048 + col * 16);
      acc[nt] = __builtin_amdgcn_mfma_f32_16x16x32_f16(af, bf, acc[nt], 0, 0, 0);
    }
  }

  long rbase = row0 + wr * 16 + q * 4;
  if constexpr (OF16) {
    unsigned short* o16 = (unsigned short*)outp;
    #pragma unroll
    for (int i = 0; i < 4; ++i) {
      long r = rbase + i;
      if (r < M) {
        #pragma unroll
        for (int nt = 0; nt < 4; ++nt) {
          int col = wc * 64 + nt * 16 + r15;
          _Float16 hv = (_Float16)acc[nt][i];
          o16[r * ldc + col] = __builtin_bit_cast(unsigned short, hv);
        }
      }
    }
  } else {
    float* o32 = (float*)outp;
    #pragma unroll
    for (int i = 0; i < 4; ++i) {
      long r = rbase + i;
      if (r < M) {
        #pragma unroll
        for (int nt = 0; nt < 4; ++nt) {
          int col = wc * 64 + nt * 16 + r15;
          if (col < ldc) o32[r * ldc + col] = acc[nt][i];
        }
      }
    }
  }
  #pragma unroll
  for (int nt = 0; nt < 4; ++nt) {
    int head = wc * 4 + nt;
    if (head < HH) {
      float cs = avs[head * 16 + r15];
      float cd = avd[head * 16 + r15];
      #pragma unroll
      for (int i = 0; i < 4; ++i) {
        float s1 = acc[nt][i] * cs;
        float s2 = acc[nt][i] * cd;
        #pragma unroll
        for (int d = 1; d < 16; d <<= 1) {
          s1 += __shfl_xor(s1, d);
          s2 += __shfl_xor(s2, d);
        }
        if (r15 == 0) {
          long r = rbase + i;
          if (r < M) { als_o[r * HH + head] = s1; ald_o[r * HH + head] = s2; }
        }
      }
    }
  }
}

// ---------------- per-dst aggregation, H=1, C=16, fp32, no max, 4-batch --------

__global__ void k_agg16(const float* __restrict__ h, const float* __restrict__ als,
                        const float* __restrict__ ald, const int* __restrict__ ptr,
                        const int* __restrict__ srcs, const float* __restrict__ bias,
                        float* __restrict__ out, int n, int lda) {
  int wid = (int)(((long)blockIdx.x * blockDim.x + threadIdx.x) >> 6);
  if (wid >= n) return;
  int lane = threadIdx.x & 63;
  int p0 = ptr[wid], deg = ptr[wid + 1] - p0;
  float aldv = ald[wid];
  int g = lane >> 4, c = lane & 15;
  float acc = 0.f, dsum = 0.f;
  int j = g;
  for (; j + 12 < deg; j += 16) {
    int s0 = srcs[p0 + j],     s1 = srcs[p0 + j + 4];
    int s2 = srcs[p0 + j + 8], s3 = srcs[p0 + j + 12];
    float l0 = als[s0] + aldv, l1 = als[s1] + aldv;
    float l2 = als[s2] + aldv, l3 = als[s3] + aldv;
    float h0 = h[(long)s0 * lda + c], h1 = h[(long)s1 * lda + c];
    float h2 = h[(long)s2 * lda + c], h3 = h[(long)s3 * lda + c];
    l0 = l0 > 0.f ? l0 : 0.2f * l0;
    l1 = l1 > 0.f ? l1 : 0.2f * l1;
    l2 = l2 > 0.f ? l2 : 0.2f * l2;
    l3 = l3 > 0.f ? l3 : 0.2f * l3;
    float e0 = __expf(l0), e1 = __expf(l1), e2 = __expf(l2), e3 = __expf(l3);
    dsum += e0 + e1 + e2 + e3;
    acc += e0 * h0 + e1 * h1 + e2 * h2 + e3 * h3;
  }
  for (; j < deg; j += 4) {
    int s = srcs[p0 + j];
    float l = als[s] + aldv;
    l = l > 0.f ? l : 0.2f * l;
    float e = __expf(l);
    dsum += e;
    acc += e * h[(long)s * lda + c];
  }
  #pragma unroll
  for (int d = 16; d < 64; d <<= 1) {
    acc += __shfl_xor(acc, d);
    dsum += __shfl_xor(dsum, d);
  }
  if (lane < 16)
    out[(long)wid * 16 + lane] = acc / (dsum + 1e-16f) + bias[lane];
}

// ---------------- launch ----------------

extern "C" void kernel_launch(void* const* d_in, const int* in_sizes, int n_in,
                              void* d_out, int out_size, void* d_ws, size_t ws_size,
                              hipStream_t stream) {
  const float* x  = (const float*)d_in[0];
  const int*   ei = (const int*)d_in[1];
  const float* W0 = (const float*)d_in[2];
  const float* as0= (const float*)d_in[3];
  const float* ad0= (const float*)d_in[4];
  const float* b0 = (const float*)d_in[5];
  const float* W1 = (const float*)d_in[6];
  const float* as1= (const float*)d_in[7];
  const float* ad1= (const float*)d_in[8];
  const float* b1 = (const float*)d_in[9];
  const float* W2 = (const float*)d_in[10];
  const float* as2= (const float*)d_in[11];
  const float* ad2= (const float*)d_in[12];
  const float* b2 = (const float*)d_in[13];
  float* out = (float*)d_out;

  int E = in_sizes[1] / 2;
  int n = in_sizes[0] / GENES;

  char* ws = (char*)d_ws;
  size_t off = 0;
  auto alloc = [&](size_t bytes) {
    void* p = ws + off;
    off = (off + bytes + 255) & ~(size_t)255;
    return p;
  };
  int* ptr   = (int*)alloc((size_t)(n + 1) * sizeof(int));
  int* cur   = (int*)alloc((size_t)n * sizeof(int));
  int* bsum  = (int*)alloc(512 * sizeof(int));
  int* srcs  = (int*)alloc((size_t)E * sizeof(int));
  unsigned short* Ah = (unsigned short*)alloc((size_t)n * 128 * sizeof(unsigned short));
  unsigned short* Bh = (unsigned short*)alloc((size_t)n * 128 * sizeof(unsigned short));
  float* A2   = (float*)alloc((size_t)n * 16 * sizeof(float));
  float* als0 = (float*)alloc((size_t)n * 8 * sizeof(float));
  float* ald0 = (float*)alloc((size_t)n * 8 * sizeof(float));
  float* als1 = (float*)alloc((size_t)n * 8 * sizeof(float));
  float* ald1 = (float*)alloc((size_t)n * 8 * sizeof(float));
  float* als2 = (float*)alloc((size_t)n * sizeof(float));
  float* ald2 = (float*)alloc((size_t)n * sizeof(float));
  unsigned short* P = (unsigned short*)alloc((size_t)163840 * sizeof(unsigned short));
  unsigned short* P0 = P;
  unsigned short* P1 = P + 131072;
  unsigned short* P2 = P + 147456;

  int eb = (E + 255) / 256;
  int nb = (n + 255) / 256;
  hipMemsetAsync(cur, 0, (size_t)n * sizeof(int), stream);
  k_wpackdeg<<<eb, 256, 0, stream>>>(W0, W1, W2, P, GENES, ei, cur, E);
  k_scan1<<<nb, 256, 0, stream>>>(cur, ptr, bsum, n);   // zeroes cur in place
  k_scan2<<<1, 256, 0, stream>>>(bsum, nb);
  k_scan3<<<nb, 256, 0, stream>>>(ptr, bsum, n);

  int mgb  = (n + 63) / 64;
  int aggb = (int)(((long)n * 64 + 255) / 256);

  // layer 0: x @ W0 -> Ah fp16 (+als0/ald0, +fused CSR scatter)
  k_mgemm14<<<mgb, 512, 0, stream>>>(x, P0, Ah, als0, ald0, as0, ad0, n, GENES,
                                     ei, ptr, cur, srcs, E);

  // fused: agg(Ah; als0/ald0; b0; ELU) -> GEMM W1 -> Bh (+als1/ald1)
  k_fagg<8, true><<<mgb, 512, 0, stream>>>(
      Ah, als0, ald0, ptr, srcs, b0, P1, Bh, als1, ald1, as1, ad1, n, 128);

  // fused: agg(Bh; als1/ald1; b1; ELU) -> GEMM W2 -> A2 fp32 (+als2/ald2, H=1)
  k_fagg<1, false><<<mgb, 512, 0, stream>>>(
      Bh, als1, ald1, ptr, srcs, b1, P2, A2, als2, ald2, as2, ad2, n, 16);

  // final aggregation -> out
  k_agg16<<<aggb, 256, 0, stream>>>(A2, als2, ald2, ptr, srcs, b2, out, n, 16);
}

// Round 23
// 254.035 us; speedup vs baseline: 1.1100x; 1.0057x over previous
//
#include <hip/hip_runtime.h>
#include <hip/hip_bf16.h>
#include <math.h>

#define GENES 1000

typedef __attribute__((ext_vector_type(8))) _Float16 half8;
typedef __attribute__((ext_vector_type(4))) float f32x4;
typedef __attribute__((ext_vector_type(4))) unsigned int uint4v;
typedef __attribute__((ext_vector_type(2))) unsigned int uint2v;

__device__ inline float f16lo(unsigned int v) {
  return (float)__builtin_bit_cast(_Float16, (unsigned short)(v & 0xffffu));
}
__device__ inline float f16hi(unsigned int v) {
  return (float)__builtin_bit_cast(_Float16, (unsigned short)(v >> 16));
}
__device__ inline float f16v(unsigned short v) {
  return (float)__builtin_bit_cast(_Float16, v);
}
__device__ inline unsigned int pk(float a, float b) {
  return __builtin_bit_cast(unsigned int, __builtin_amdgcn_cvt_pkrtz(a, b));
}

// async global->LDS, 16B per lane (m104/m173); tracked only by vmcnt.
__device__ inline void gload16(const void* g, void* l) {
  __builtin_amdgcn_global_load_lds(
      (const __attribute__((address_space(1))) unsigned int*)g,
      (__attribute__((address_space(3))) unsigned int*)l, 16, 0, 0);
}

__device__ __forceinline__ void waitvm(int n) {
  __builtin_amdgcn_sched_barrier(0);
  if (n <= 0)      asm volatile("s_waitcnt vmcnt(0)" ::: "memory");
  else             asm volatile("s_waitcnt vmcnt(2)" ::: "memory");
  __builtin_amdgcn_sched_barrier(0);
}

// ---------------- CSR build ----------------

__global__ void k_scan1(int* __restrict__ deg, int* __restrict__ ptr,
                        int* __restrict__ bsum, int n) {
  __shared__ int ws[4];
  int t = threadIdx.x, b = blockIdx.x;
  int i = b * 256 + t;
  int lane = t & 63, w = t >> 6;
  int x = 0;
  if (i < n) { x = deg[i]; deg[i] = 0; }
  #pragma unroll
  for (int d = 1; d < 64; d <<= 1) {
    int y = __shfl_up(x, d);
    if (lane >= d) x += y;
  }
  if (lane == 63) ws[w] = x;
  __syncthreads();
  if (t == 0) {
    int s = 0;
    #pragma unroll
    for (int k = 0; k < 4; ++k) { s += ws[k]; ws[k] = s; }
  }
  __syncthreads();
  int incl = x + (w ? ws[w - 1] : 0);
  if (i < n) ptr[i + 1] = incl;
  if (t == 255) bsum[b] = incl;
  if (i == 0) ptr[0] = 0;
}

__global__ void k_scan2(int* __restrict__ bsum, int nb) {
  __shared__ int ws[4];
  int t = threadIdx.x;
  int lane = t & 63, w = t >> 6;
  int v = (t < nb) ? bsum[t] : 0;
  int x = v;
  #pragma unroll
  for (int d = 1; d < 64; d <<= 1) {
    int y = __shfl_up(x, d);
    if (lane >= d) x += y;
  }
  if (lane == 63) ws[w] = x;
  __syncthreads();
  if (t == 0) {
    int s = 0;
    #pragma unroll
    for (int k = 0; k < 4; ++k) { s += ws[k]; ws[k] = s; }
  }
  __syncthreads();
  int incl = x + (w ? ws[w - 1] : 0);
  if (t < nb) bsum[t] = incl - v;
}

__global__ void k_scan3(int* __restrict__ ptr, const int* __restrict__ bsum, int n) {
  int i = blockIdx.x * 256 + threadIdx.x;
  if (i < n) ptr[i + 1] += bsum[blockIdx.x];
}

// ---------------- W pack + degree count (fused) --------------------------------

__global__ void k_wpackdeg(const float* __restrict__ W0, const float* __restrict__ W1,
                           const float* __restrict__ W2, unsigned short* __restrict__ P,
                           int K0, const int* __restrict__ ei, int* __restrict__ deg,
                           int E) {
  int t = blockIdx.x * blockDim.x + threadIdx.x;
  if (t < 163840) {
    const float* W; int K, N, e;
    if (t < 131072)      { W = W0; K = K0;  N = 128; e = t; }
    else if (t < 147456) { W = W1; K = 128; N = 128; e = t - 131072; }
    else                 { W = W2; K = 128; N = 16;  e = t - 147456; }
    int s = e >> 12, rem = e & 4095;
    int q = rem >> 10, col = (rem >> 3) & 127, j = rem & 7;
    int k = s * 32 + q * 8 + j;
    float v = (k < K && col < N) ? W[(long)k * N + col] : 0.f;
    _Float16 h = (_Float16)v;
    P[t] = __builtin_bit_cast(unsigned short, h);
  }
  if (t < E) atomicAdd(&deg[ei[E + t]], 1);
}

// ---------------- layer-0 GEMM: 3-deep counted-vmcnt pipeline + fused scatter --

__global__ __launch_bounds__(512) void k_mgemm14(
    const float* __restrict__ A, const unsigned short* __restrict__ Pb,
    unsigned short* __restrict__ outp, float* __restrict__ als,
    float* __restrict__ ald, const float* __restrict__ avs,
    const float* __restrict__ avd, int M, int K,
    const int* __restrict__ ei, const int* __restrict__ ptr,
    int* __restrict__ cur, int* __restrict__ srcs, int E) {
  __shared__ __align__(16) char lds[49152];  // A: 3x8KB | B: 3x8KB

  int t = threadIdx.x, lane = t & 63, wv = t >> 6;
  int r15 = lane & 15, q = lane >> 4;
  int wr = wv >> 1, wc = wv & 1;
  long row0 = (long)blockIdx.x * 64;

  int srow = t >> 3, sseg = t & 7;
  int gseg = sseg ^ (srow & 7);            // pre-swizzled source (rule 21)
  long arow = row0 + srow; if (arow >= M) arow = M - 1;
  const char* gA = (const char*)(A + arow * (long)K) + gseg * 16;
  const char* gB = (const char*)Pb + t * 16;

  f32x4 acc[4];
  #pragma unroll
  for (int nt = 0; nt < 4; ++nt) acc[nt] = (f32x4){0.f, 0.f, 0.f, 0.f};

  auto issue = [&](int s) {
    char* Ab = lds + (s % 3) * 8192;
    char* Bb = lds + 24576 + (s % 3) * 8192;
    gload16(gA + (size_t)s * 128, Ab + t * 16);
    gload16(gB + (size_t)s * 8192, Bb + t * 16);
  };
  auto compute = [&](int s) {
    const char* Ab = lds + (s % 3) * 8192;
    const char* Bb = lds + 24576 + (s % 3) * 8192;
    int row = wr * 16 + r15;
    int sw = row & 7;
    uint4v alo = *(const uint4v*)(Ab + row * 128 + ((2 * q) ^ sw) * 16);
    uint4v ahi = *(const uint4v*)(Ab + row * 128 + ((2 * q + 1) ^ sw) * 16);
    float4 lo = __builtin_bit_cast(float4, alo);
    float4 hi = __builtin_bit_cast(float4, ahi);
    uint4v au;
    au[0] = pk(lo.x, lo.y); au[1] = pk(lo.z, lo.w);
    au[2] = pk(hi.x, hi.y); au[3] = pk(hi.z, hi.w);
    half8 af = __builtin_bit_cast(half8, au);
    #pragma unroll
    for (int nt = 0; nt < 4; ++nt) {
      half8 bf = *(const half8*)(Bb + q * 2048 + (wc * 64 + nt * 16 + r15) * 16);
      acc[nt] = __builtin_amdgcn_mfma_f32_16x16x32_f16(af, bf, acc[nt], 0, 0, 0);
    }
  };

  issue(0); issue(1);

  // fused CSR scatter (issued after tile loads; in-order vmcnt retirement)
  {
    int e0 = blockIdx.x * 1024 + t;
    if (e0 < E) {
      int d = ei[E + e0];
      int pos = ptr[d] + atomicAdd(&cur[d], 1);
      srcs[pos] = ei[e0];
    }
    int e1 = e0 + 512;
    if (e1 < E) {
      int d = ei[E + e1];
      int pos = ptr[d] + atomicAdd(&cur[d], 1);
      srcs[pos] = ei[e1];
    }
  }

  #pragma unroll
  for (int s = 0; s < 32; ++s) {
    waitvm(s < 31 ? 2 : 0);
    __builtin_amdgcn_s_barrier();
    compute(s);
    if (s + 2 < 32) issue(s + 2);
  }

  long rbase = row0 + wr * 16 + q * 4;
  #pragma unroll
  for (int i = 0; i < 4; ++i) {
    long r = rbase + i;
    if (r < M) {
      #pragma unroll
      for (int nt = 0; nt < 4; ++nt) {
        int col = wc * 64 + nt * 16 + r15;
        _Float16 hv = (_Float16)acc[nt][i];
        outp[r * 128 + col] = __builtin_bit_cast(unsigned short, hv);
      }
    }
  }
  #pragma unroll
  for (int nt = 0; nt < 4; ++nt) {
    int head = wc * 4 + nt;
    float cs = avs[head * 16 + r15];
    float cd = avd[head * 16 + r15];
    #pragma unroll
    for (int i = 0; i < 4; ++i) {
      float s1 = acc[nt][i] * cs;
      float s2 = acc[nt][i] * cd;
      #pragma unroll
      for (int d = 1; d < 16; d <<= 1) {
        s1 += __shfl_xor(s1, d);
        s2 += __shfl_xor(s2, d);
      }
      if (r15 == 0) {
        long r = rbase + i;
        if (r < M) { als[r * 8 + head] = s1; ald[r * 8 + head] = s2; }
      }
    }
  }
}

// ---------------- fused agg(H=8,ELU) -> GEMM(K=128) ---------------------------
// Block owns 64 dst rows: 8 waves aggregate 8 nodes each straight into the
// 16KB LDS A-tile (fragment layout), one barrier, 4 MFMA k-steps (B from L2).
// Row-wise GEMM => fusion legal; per-layer als/ald buffers avoid r/w races.

template<int HH, bool OF16>
__global__ __launch_bounds__(512) void k_fagg(
    const unsigned short* __restrict__ hsrc,
    const float* __restrict__ als_i, const float* __restrict__ ald_i,
    const int* __restrict__ ptr, const int* __restrict__ srcs,
    const float* __restrict__ bias, const unsigned short* __restrict__ Pb,
    void* __restrict__ outp, float* __restrict__ als_o, float* __restrict__ ald_o,
    const float* __restrict__ avs, const float* __restrict__ avd,
    int M, int ldc) {
  __shared__ __align__(16) unsigned short At[4 * 4 * 64 * 8];  // 16 KB

  int t = threadIdx.x, lane = t & 63, wv = t >> 6;
  int half = lane >> 5, l5 = lane & 31;
  long row0 = (long)blockIdx.x * 64;

  // ---- phase 1: aggregate 8 nodes per wave into the LDS A-tile ----
  int c0 = 4 * l5;
  int hB = l5 >> 2;
  int sA = c0 >> 5, qA = (c0 >> 3) & 3, jA = c0 & 7;
  #pragma unroll 1
  for (int i = 0; i < 8; ++i) {
    int rowL = wv * 8 + i;
    long node = row0 + rowL;
    char* dst = (char*)At + ((sA * 4 + qA) * 64 + rowL) * 16 + (jA ? 8 : 0);
    if (node < M) {
      int p0 = ptr[node], deg = ptr[node + 1] - p0;
      float aldB = ald_i[node * 8 + hB];
      float a0 = 0.f, a1 = 0.f, a2 = 0.f, a3 = 0.f, dsum = 0.f;
      int j = half;
      for (; j + 6 < deg; j += 8) {
        int s0 = srcs[p0 + j],     s1 = srcs[p0 + j + 2];
        int s2 = srcs[p0 + j + 4], s3 = srcs[p0 + j + 6];
        float l0 = als_i[s0 * 8 + hB] + aldB;
        float l1 = als_i[s1 * 8 + hB] + aldB;
        float l2 = als_i[s2 * 8 + hB] + aldB;
        float l3 = als_i[s3 * 8 + hB] + aldB;
        uint2v h0 = *(const uint2v*)(hsrc + (long)s0 * 128 + c0);
        uint2v h1 = *(const uint2v*)(hsrc + (long)s1 * 128 + c0);
        uint2v h2 = *(const uint2v*)(hsrc + (long)s2 * 128 + c0);
        uint2v h3 = *(const uint2v*)(hsrc + (long)s3 * 128 + c0);
        l0 = l0 > 0.f ? l0 : 0.2f * l0;
        l1 = l1 > 0.f ? l1 : 0.2f * l1;
        l2 = l2 > 0.f ? l2 : 0.2f * l2;
        l3 = l3 > 0.f ? l3 : 0.2f * l3;
        float e0 = __expf(l0), e1 = __expf(l1), e2 = __expf(l2), e3 = __expf(l3);
        dsum += e0 + e1 + e2 + e3;
        a0 += e0 * f16lo(h0[0]) + e1 * f16lo(h1[0]) + e2 * f16lo(h2[0]) + e3 * f16lo(h3[0]);
        a1 += e0 * f16hi(h0[0]) + e1 * f16hi(h1[0]) + e2 * f16hi(h2[0]) + e3 * f16hi(h3[0]);
        a2 += e0 * f16lo(h0[1]) + e1 * f16lo(h1[1]) + e2 * f16lo(h2[1]) + e3 * f16lo(h3[1]);
        a3 += e0 * f16hi(h0[1]) + e1 * f16hi(h1[1]) + e2 * f16hi(h2[1]) + e3 * f16hi(h3[1]);
      }
      for (; j < deg; j += 2) {
        int s = srcs[p0 + j];
        float l = als_i[s * 8 + hB] + aldB;
        l = l > 0.f ? l : 0.2f * l;
        float e = __expf(l);
        uint2v hv = *(const uint2v*)(hsrc + (long)s * 128 + c0);
        dsum += e;
        a0 += e * f16lo(hv[0]);
        a1 += e * f16hi(hv[0]);
        a2 += e * f16lo(hv[1]);
        a3 += e * f16hi(hv[1]);
      }
      a0 += __shfl_xor(a0, 32);
      a1 += __shfl_xor(a1, 32);
      a2 += __shfl_xor(a2, 32);
      a3 += __shfl_xor(a3, 32);
      dsum += __shfl_xor(dsum, 32);
      if (half == 0) {
        float inv = 1.f / (dsum + 1e-16f);
        float o0 = a0 * inv + bias[c0];
        float o1 = a1 * inv + bias[c0 + 1];
        float o2 = a2 * inv + bias[c0 + 2];
        float o3 = a3 * inv + bias[c0 + 3];
        o0 = o0 > 0.f ? o0 : (__expf(o0) - 1.f);
        o1 = o1 > 0.f ? o1 : (__expf(o1) - 1.f);
        o2 = o2 > 0.f ? o2 : (__expf(o2) - 1.f);
        o3 = o3 > 0.f ? o3 : (__expf(o3) - 1.f);
        uint2v pv;
        pv[0] = pk(o0, o1);
        pv[1] = pk(o2, o3);
        *(uint2v*)dst = pv;
      }
    } else if (half == 0) {
      *(uint2v*)dst = (uint2v){0u, 0u};
    }
  }
  __syncthreads();

  // ---- phase 2: 64x128 @ W -> out (B direct from L2) ----
  int r15 = lane & 15, q = lane >> 4;
  int wr = wv >> 1, wc = wv & 1;
  f32x4 acc[4];
  #pragma unroll
  for (int nt = 0; nt < 4; ++nt) acc[nt] = (f32x4){0.f, 0.f, 0.f, 0.f};
  #pragma unroll
  for (int s = 0; s < 4; ++s) {
    half8 af = *(const half8*)((const char*)At + ((s * 4 + q) * 64 + wr * 16 + r15) * 16);
    #pragma unroll
    for (int nt = 0; nt < 4; ++nt) {
      int col = wc * 64 + nt * 16 + r15;
      half8 bf = *(const half8*)((const char*)Pb + (size_t)s * 8192 + q * 2048 + col * 16);
      acc[nt] = __builtin_amdgcn_mfma_f32_16x16x32_f16(af, bf, acc[nt], 0, 0, 0);
    }
  }

  long rbase = row0 + wr * 16 + q * 4;
  if constexpr (OF16) {
    unsigned short* o16 = (unsigned short*)outp;
    #pragma unroll
    for (int i = 0; i < 4; ++i) {
      long r = rbase + i;
      if (r < M) {
        #pragma unroll
        for (int nt = 0; nt < 4; ++nt) {
          int col = wc * 64 + nt * 16 + r15;
          if (col < ldc) {
            _Float16 hv = (_Float16)acc[nt][i];
            o16[r * ldc + col] = __builtin_bit_cast(unsigned short, hv);
          }
        }
      }
    }
  } else {
    float* o32 = (float*)outp;
    #pragma unroll
    for (int i = 0; i < 4; ++i) {
      long r = rbase + i;
      if (r < M) {
        #pragma unroll
        for (int nt = 0; nt < 4; ++nt) {
          int col = wc * 64 + nt * 16 + r15;
          if (col < ldc) o32[r * ldc + col] = acc[nt][i];
        }
      }
    }
  }
  #pragma unroll
  for (int nt = 0; nt < 4; ++nt) {
    int head = wc * 4 + nt;
    if (head < HH) {
      float cs = avs[head * 16 + r15];
      float cd = avd[head * 16 + r15];
      #pragma unroll
      for (int i = 0; i < 4; ++i) {
        float s1 = acc[nt][i] * cs;
        float s2 = acc[nt][i] * cd;
        #pragma unroll
        for (int d = 1; d < 16; d <<= 1) {
          s1 += __shfl_xor(s1, d);
          s2 += __shfl_xor(s2, d);
        }
        if (r15 == 0) {
          long r = rbase + i;
          if (r < M) { als_o[r * HH + head] = s1; ald_o[r * HH + head] = s2; }
        }
      }
    }
  }
}

// ---------------- per-dst aggregation, H=1, C=16, fp16 h, no max, 4-batch ------

__global__ void k_agg16h(const unsigned short* __restrict__ h,
                         const float* __restrict__ als, const float* __restrict__ ald,
                         const int* __restrict__ ptr, const int* __restrict__ srcs,
                         const float* __restrict__ bias,
                         float* __restrict__ out, int n) {
  int wid = (int)(((long)blockIdx.x * blockDim.x + threadIdx.x) >> 6);
  if (wid >= n) return;
  int lane = threadIdx.x & 63;
  int p0 = ptr[wid], deg = ptr[wid + 1] - p0;
  float aldv = ald[wid];
  int g = lane >> 4, c = lane & 15;
  float acc = 0.f, dsum = 0.f;
  int j = g;
  for (; j + 12 < deg; j += 16) {
    int s0 = srcs[p0 + j],     s1 = srcs[p0 + j + 4];
    int s2 = srcs[p0 + j + 8], s3 = srcs[p0 + j + 12];
    float l0 = als[s0] + aldv, l1 = als[s1] + aldv;
    float l2 = als[s2] + aldv, l3 = als[s3] + aldv;
    float h0 = f16v(h[(long)s0 * 16 + c]), h1 = f16v(h[(long)s1 * 16 + c]);
    float h2 = f16v(h[(long)s2 * 16 + c]), h3 = f16v(h[(long)s3 * 16 + c]);
    l0 = l0 > 0.f ? l0 : 0.2f * l0;
    l1 = l1 > 0.f ? l1 : 0.2f * l1;
    l2 = l2 > 0.f ? l2 : 0.2f * l2;
    l3 = l3 > 0.f ? l3 : 0.2f * l3;
    float e0 = __expf(l0), e1 = __expf(l1), e2 = __expf(l2), e3 = __expf(l3);
    dsum += e0 + e1 + e2 + e3;
    acc += e0 * h0 + e1 * h1 + e2 * h2 + e3 * h3;
  }
  for (; j < deg; j += 4) {
    int s = srcs[p0 + j];
    float l = als[s] + aldv;
    l = l > 0.f ? l : 0.2f * l;
    float e = __expf(l);
    dsum += e;
    acc += e * f16v(h[(long)s * 16 + c]);
  }
  #pragma unroll
  for (int d = 16; d < 64; d <<= 1) {
    acc += __shfl_xor(acc, d);
    dsum += __shfl_xor(dsum, d);
  }
  if (lane < 16)
    out[(long)wid * 16 + lane] = acc / (dsum + 1e-16f) + bias[lane];
}

// ---------------- launch ----------------

extern "C" void kernel_launch(void* const* d_in, const int* in_sizes, int n_in,
                              void* d_out, int out_size, void* d_ws, size_t ws_size,
                              hipStream_t stream) {
  const float* x  = (const float*)d_in[0];
  const int*   ei = (const int*)d_in[1];
  const float* W0 = (const float*)d_in[2];
  const float* as0= (const float*)d_in[3];
  const float* ad0= (const float*)d_in[4];
  const float* b0 = (const float*)d_in[5];
  const float* W1 = (const float*)d_in[6];
  const float* as1= (const float*)d_in[7];
  const float* ad1= (const float*)d_in[8];
  const float* b1 = (const float*)d_in[9];
  const float* W2 = (const float*)d_in[10];
  const float* as2= (const float*)d_in[11];
  const float* ad2= (const float*)d_in[12];
  const float* b2 = (const float*)d_in[13];
  float* out = (float*)d_out;

  int E = in_sizes[1] / 2;
  int n = in_sizes[0] / GENES;

  char* ws = (char*)d_ws;
  size_t off = 0;
  auto alloc = [&](size_t bytes) {
    void* p = ws + off;
    off = (off + bytes + 255) & ~(size_t)255;
    return p;
  };
  int* ptr   = (int*)alloc((size_t)(n + 1) * sizeof(int));
  int* cur   = (int*)alloc((size_t)n * sizeof(int));
  int* bsum  = (int*)alloc(512 * sizeof(int));
  int* srcs  = (int*)alloc((size_t)E * sizeof(int));
  unsigned short* Ah = (unsigned short*)alloc((size_t)n * 128 * sizeof(unsigned short));
  unsigned short* Bh = (unsigned short*)alloc((size_t)n * 128 * sizeof(unsigned short));
  unsigned short* A2h = (unsigned short*)alloc((size_t)n * 16 * sizeof(unsigned short));
  float* als0 = (float*)alloc((size_t)n * 8 * sizeof(float));
  float* ald0 = (float*)alloc((size_t)n * 8 * sizeof(float));
  float* als1 = (float*)alloc((size_t)n * 8 * sizeof(float));
  float* ald1 = (float*)alloc((size_t)n * 8 * sizeof(float));
  float* als2 = (float*)alloc((size_t)n * sizeof(float));
  float* ald2 = (float*)alloc((size_t)n * sizeof(float));
  unsigned short* P = (unsigned short*)alloc((size_t)163840 * sizeof(unsigned short));
  unsigned short* P0 = P;
  unsigned short* P1 = P + 131072;
  unsigned short* P2 = P + 147456;

  int eb = (E + 255) / 256;
  int nb = (n + 255) / 256;
  hipMemsetAsync(cur, 0, (size_t)n * sizeof(int), stream);
  k_wpackdeg<<<eb, 256, 0, stream>>>(W0, W1, W2, P, GENES, ei, cur, E);
  k_scan1<<<nb, 256, 0, stream>>>(cur, ptr, bsum, n);   // zeroes cur in place
  k_scan2<<<1, 256, 0, stream>>>(bsum, nb);
  k_scan3<<<nb, 256, 0, stream>>>(ptr, bsum, n);

  int mgb  = (n + 63) / 64;
  int aggb = (int)(((long)n * 64 + 255) / 256);

  // layer 0: x @ W0 -> Ah fp16 (+als0/ald0, +fused CSR scatter)
  k_mgemm14<<<mgb, 512, 0, stream>>>(x, P0, Ah, als0, ald0, as0, ad0, n, GENES,
                                     ei, ptr, cur, srcs, E);

  // fused: agg(Ah; als0/ald0; b0; ELU) -> GEMM W1 -> Bh fp16 (+als1/ald1)
  k_fagg<8, true><<<mgb, 512, 0, stream>>>(
      Ah, als0, ald0, ptr, srcs, b0, P1, Bh, als1, ald1, as1, ad1, n, 128);

  // fused: agg(Bh; als1/ald1; b1; ELU) -> GEMM W2 -> A2h fp16 (+als2/ald2, H=1)
  k_fagg<1, true><<<mgb, 512, 0, stream>>>(
      Bh, als1, ald1, ptr, srcs, b1, P2, A2h, als2, ald2, as2, ad2, n, 16);

  // final aggregation (fp16 h) -> out fp32
  k_agg16h<<<aggb, 256, 0, stream>>>(A2h, als2, ald2, ptr, srcs, b2, out, n);
}